// Round 12
// baseline (953.433 us; speedup 1.0000x reference)
//
#include <hip/hip_runtime.h>

typedef unsigned short u16;
typedef __attribute__((ext_vector_type(4))) u16 u16x4;
typedef __attribute__((ext_vector_type(8))) u16 u16x8;
typedef __attribute__((ext_vector_type(8))) short s16x8;
typedef __attribute__((ext_vector_type(4))) float f32x4;

#define E_CNT 72192
#define BN_CNT 1536
// edges per graph = 48*47
#define EPG 2256

__device__ __forceinline__ float b2f(u16 u) {
    union { unsigned int i; float f; } x; x.i = ((unsigned int)u) << 16; return x.f;
}
__device__ __forceinline__ u16 f2b(float f) {
    union { float f; unsigned int i; } x; x.f = f;
    unsigned int r = x.i + 0x7fffu + ((x.i >> 16) & 1u);
    return (u16)(r >> 16);
}
__device__ __forceinline__ float siluf(float x) { return x / (1.f + expf(-x)); }

// async global->LDS, 16B per lane (linear dest). (guide §5 / m97)
__device__ __forceinline__ void gll16(const void* g, void* l) {
    __builtin_amdgcn_global_load_lds(
        (const __attribute__((address_space(1))) void*)g,
        (__attribute__((address_space(3))) void*)l, 16, 0, 0);
}

// ---------------- wave (64-lane) LayerNorm, eps 1e-6, no affine -------------
__device__ __forceinline__ float wave_ln64(float x) {
    float s = x;
    #pragma unroll
    for (int off = 1; off < 64; off <<= 1) s += __shfl_xor(s, off);
    float mean = s * 0.015625f;
    float d = x - mean;
    float v2 = d * d;
    #pragma unroll
    for (int off = 1; off < 64; off <<= 1) v2 += __shfl_xor(v2, off);
    return d * rsqrtf(v2 * 0.015625f + 1e-6f);
}

// ---------------- block(256)-wide LayerNorm over 256 dims -------------------
__device__ __forceinline__ float block_ln256(float x) {
    __shared__ float tmp[4];
    int t = threadIdx.x;
    float s = x;
    #pragma unroll
    for (int off = 1; off < 64; off <<= 1) s += __shfl_xor(s, off);
    if ((t & 63) == 0) tmp[t >> 6] = s;
    __syncthreads();
    float mean = (tmp[0] + tmp[1] + tmp[2] + tmp[3]) * (1.f / 256.f);
    float d = x - mean;
    float v2 = d * d;
    #pragma unroll
    for (int off = 1; off < 64; off <<= 1) v2 += __shfl_xor(v2, off);
    __syncthreads();
    if ((t & 63) == 0) tmp[t >> 6] = v2;
    __syncthreads();
    float var = (tmp[0] + tmp[1] + tmp[2] + tmp[3]) * (1.f / 256.f);
    return d * rsqrtf(var + 1e-6f);
}

// ---------------- generic bf16 MFMA GEMM, 64x64 tile ------------------------
template<int ACT, int OUTBF>
__global__ __launch_bounds__(256) void k_gemm(
    const u16* __restrict__ A, const u16* __restrict__ Bt,
    const float* __restrict__ bias, void* __restrict__ C,
    int M, int N, int K)
{
    __shared__ u16 As[64][40];
    __shared__ u16 Bs[64][40];
    int bn0 = blockIdx.x * 64, bm0 = blockIdx.y * 64;
    int t = threadIdx.x;
    int lane = t & 63, wave = t >> 6;
    int wm = wave >> 1, wn = wave & 1;
    int lr = t >> 2, lc = (t & 3) * 8;
    f32x4 acc[2][2] = {};
    const u16* Ap = A + (size_t)(bm0 + lr) * K + lc;
    const u16* Bp = Bt + (size_t)(bn0 + lr) * K + lc;
    int fr = lane & 15, fk = (lane >> 4) * 8;
    for (int k0 = 0; k0 < K; k0 += 32) {
        *(u16x8*)&As[lr][lc] = *(const u16x8*)(Ap + k0);
        *(u16x8*)&Bs[lr][lc] = *(const u16x8*)(Bp + k0);
        __syncthreads();
        s16x8 a0 = *(const s16x8*)&As[wm * 32 + fr][fk];
        s16x8 a1 = *(const s16x8*)&As[wm * 32 + 16 + fr][fk];
        s16x8 b0 = *(const s16x8*)&Bs[wn * 32 + fr][fk];
        s16x8 b1 = *(const s16x8*)&Bs[wn * 32 + 16 + fr][fk];
        acc[0][0] = __builtin_amdgcn_mfma_f32_16x16x32_bf16(a0, b0, acc[0][0], 0, 0, 0);
        acc[0][1] = __builtin_amdgcn_mfma_f32_16x16x32_bf16(a0, b1, acc[0][1], 0, 0, 0);
        acc[1][0] = __builtin_amdgcn_mfma_f32_16x16x32_bf16(a1, b0, acc[1][0], 0, 0, 0);
        acc[1][1] = __builtin_amdgcn_mfma_f32_16x16x32_bf16(a1, b1, acc[1][1], 0, 0, 0);
        __syncthreads();
    }
    int cIn = lane & 15, r4 = (lane >> 4) * 4;
    #pragma unroll
    for (int i = 0; i < 2; i++)
    #pragma unroll
    for (int j = 0; j < 2; j++) {
        int col = bn0 + wn * 32 + j * 16 + cIn;
        float bv = bias ? bias[col] : 0.f;
        #pragma unroll
        for (int r = 0; r < 4; r++) {
            int rowg = bm0 + wm * 32 + i * 16 + r4 + r;
            float vv = acc[i][j][r] + bv;
            if (ACT == 1) vv = siluf(vv);
            if (OUTBF) ((u16*)C)[(size_t)rowg * N + col] = f2b(vv);
            else       ((float*)C)[(size_t)rowg * N + col] = vv;
        }
    }
}

// ---------------- 128x128 tile bf16 MFMA GEMM, 3-deep pipelined -------------
// (r5/r6 verified structure: counted vmcnt + both-sides chunk-XOR swizzle)
template<int ACT, int OUTBF>
__global__ __launch_bounds__(256) void k_gemm128(
    const u16* __restrict__ A, const u16* __restrict__ Bt,
    const float* __restrict__ bias, void* __restrict__ C,
    int M, int N, int K)
{
    __shared__ u16 As[3][128 * 32];
    __shared__ u16 Bs[3][128 * 32];
    const int t = threadIdx.x;
    const int lane = t & 63, wv = t >> 6;
    const int wm = wv >> 1, wn = wv & 1;
    const int nwg = gridDim.x * gridDim.y;
    const int orig = blockIdx.y * gridDim.x + blockIdx.x;
    const int q8 = nwg >> 3, r8 = nwg & 7;
    const int xcd = orig & 7, lin = orig >> 3;
    const int wgid = (xcd < r8 ? xcd * (q8 + 1) : r8 * (q8 + 1) + (xcd - r8) * q8) + lin;
    const int bxs = wgid % gridDim.x, bys = wgid / gridDim.x;
    const int bn0 = bxs * 128, bm0 = bys * 128;
    const int srow = t >> 2;
    const int scol = ((t & 3) ^ ((t >> 3) & 3)) * 8;
    const u16* Ap = A + (size_t)(bm0 + srow) * K + scol;
    const u16* Bp = Bt + (size_t)(bn0 + srow) * K + scol;
    const size_t rstep = (size_t)64 * K;
    const int woff = wv * 16 * 32;
    const int fr = lane & 15;
    const int fkc = (((lane >> 4) ^ ((fr >> 1) & 3)) * 8);
    f32x4 acc[4][4] = {};
    const int NT = K >> 5;

    auto STAGE = [&](int b, int ko) {
        gll16(Ap + ko, &As[b][woff]);
        gll16(Ap + ko + rstep, &As[b][woff + 64 * 32]);
        gll16(Bp + ko, &Bs[b][woff]);
        gll16(Bp + ko + rstep, &Bs[b][woff + 64 * 32]);
    };
    auto COMPUTE = [&](int b) {
        const u16* aBase = &As[b][wm * 64 * 32];
        const u16* bBase = &Bs[b][wn * 64 * 32];
        s16x8 af[4], bfr[4];
        #pragma unroll
        for (int m = 0; m < 4; m++) af[m] = *(const s16x8*)&aBase[(m * 16 + fr) * 32 + fkc];
        #pragma unroll
        for (int n = 0; n < 4; n++) bfr[n] = *(const s16x8*)&bBase[(n * 16 + fr) * 32 + fkc];
        #pragma unroll
        for (int m = 0; m < 4; m++)
        #pragma unroll
        for (int n = 0; n < 4; n++)
            acc[m][n] = __builtin_amdgcn_mfma_f32_16x16x32_bf16(af[m], bfr[n], acc[m][n], 0, 0, 0);
    };

    STAGE(0, 0);
    if (NT > 1) STAGE(1, 32);
    int cur = 0;
    for (int tt = 0; tt < NT; tt++) {
        if (tt + 2 < NT) STAGE((cur + 2) % 3, (tt + 2) * 32);
        __builtin_amdgcn_sched_barrier(0);
        int ahead = NT - 1 - tt; if (ahead > 2) ahead = 2;
        if (ahead == 2)      asm volatile("s_waitcnt vmcnt(8)" ::: "memory");
        else if (ahead == 1) asm volatile("s_waitcnt vmcnt(4)" ::: "memory");
        else                 asm volatile("s_waitcnt vmcnt(0)" ::: "memory");
        __builtin_amdgcn_sched_barrier(0);
        __builtin_amdgcn_s_barrier();
        COMPUTE(cur);
        __builtin_amdgcn_s_barrier();
        __builtin_amdgcn_sched_barrier(0);
        cur = (cur + 1) % 3;
    }

    const int cIn = lane & 15, r4 = (lane >> 4) * 4;
    #pragma unroll
    for (int n = 0; n < 4; n++) {
        int col = bn0 + wn * 64 + n * 16 + cIn;
        float bv = bias ? bias[col] : 0.f;
        #pragma unroll
        for (int m = 0; m < 4; m++) {
            #pragma unroll
            for (int r = 0; r < 4; r++) {
                int rowg = bm0 + wm * 64 + m * 16 + r4 + r;
                float vv = acc[m][n][r] + bv;
                if (ACT == 1) vv = siluf(vv);
                if (OUTBF) ((u16*)C)[(size_t)rowg * N + col] = f2b(vv);
                else       ((float*)C)[(size_t)rowg * N + col] = vv;
            }
        }
    }
}

// ---------------- 128x128 GEMM with FUSED silu(f32 A) -----------------------
// Same verified ring-3 / barrier structure as k_gemm128; A is read as f32
// directly from global (per-lane swizzled addresses), silu+bf16-converted in
// registers, ds_write_b128 into the linear LDS slot right before the tile's
// barrier (T14 split: loads issued one full iteration ahead). B stays gll16.
// Uniform 6 VM ops per tile-step (A-loads clamped at K-32 so the tail issues
// real addresses) -> single constant vmcnt(12) = 2 steps x 6 ops.
// Requires M%128==0, N%128==0, K%32==0, (K/32) even.
struct AReg { f32x4 a, b, c, d; };

template<int OUTBF>
__global__ __launch_bounds__(256) void k_gemm128_fs(
    const float* __restrict__ A32, const u16* __restrict__ Bt,
    const float* __restrict__ bias, void* __restrict__ C,
    int M, int N, int K)
{
    __shared__ u16 As[3][128 * 32];
    __shared__ u16 Bs[3][128 * 32];
    const int t = threadIdx.x;
    const int lane = t & 63, wv = t >> 6;
    const int wm = wv >> 1, wn = wv & 1;
    const int nwg = gridDim.x * gridDim.y;
    const int orig = blockIdx.y * gridDim.x + blockIdx.x;
    const int q8 = nwg >> 3, r8 = nwg & 7;
    const int xcd = orig & 7, lin = orig >> 3;
    const int wgid = (xcd < r8 ? xcd * (q8 + 1) : r8 * (q8 + 1) + (xcd - r8) * q8) + lin;
    const int bxs = wgid % gridDim.x, bys = wgid / gridDim.x;
    const int bn0 = bxs * 128, bm0 = bys * 128;
    const int srow = t >> 2;
    const int scol = ((t & 3) ^ ((t >> 3) & 3)) * 8;
    const float* Ap = A32 + (size_t)(bm0 + srow) * K + scol;
    const u16* Bp = Bt + (size_t)(bn0 + srow) * K + scol;
    const size_t rstep = (size_t)64 * K;
    const int woff = wv * 16 * 32;           // u16 units
    const int dA = wv * 512 + lane * 8;      // this thread's linear A slot (u16)
    const int fr = lane & 15;
    const int fkc = (((lane >> 4) ^ ((fr >> 1) & 3)) * 8);
    f32x4 acc[4][4] = {};
    const int NT = K >> 5;
    const int koMax = K - 32;

    auto LOADA = [&](AReg& r, int ko) {
        int k = ko > koMax ? koMax : ko;     // clamp: tail issues real addrs
        r.a = *(const f32x4*)(Ap + k);
        r.b = *(const f32x4*)(Ap + k + 4);
        r.c = *(const f32x4*)(Ap + k + rstep);
        r.d = *(const f32x4*)(Ap + k + rstep + 4);
    };
    auto WRITEA = [&](int b, const AReg& r) {
        u16x8 w0, w1;
        #pragma unroll
        for (int j = 0; j < 4; j++) {
            w0[j] = f2b(siluf(r.a[j]));  w0[4 + j] = f2b(siluf(r.b[j]));
            w1[j] = f2b(siluf(r.c[j]));  w1[4 + j] = f2b(siluf(r.d[j]));
        }
        *(u16x8*)&As[b][dA] = w0;
        *(u16x8*)&As[b][2048 + dA] = w1;
    };
    auto STAGEB = [&](int b, int ko) {
        int k = ko > koMax ? koMax : ko;
        gll16(Bp + k, &Bs[b][woff]);
        gll16(Bp + k + rstep, &Bs[b][woff + 2048]);
    };
    auto COMPUTE = [&](int b) {
        const u16* aBase = &As[b][wm * 64 * 32];
        const u16* bBase = &Bs[b][wn * 64 * 32];
        s16x8 af[4], bfr[4];
        #pragma unroll
        for (int m = 0; m < 4; m++) af[m] = *(const s16x8*)&aBase[(m * 16 + fr) * 32 + fkc];
        #pragma unroll
        for (int n = 0; n < 4; n++) bfr[n] = *(const s16x8*)&bBase[(n * 16 + fr) * 32 + fkc];
        #pragma unroll
        for (int m = 0; m < 4; m++)
        #pragma unroll
        for (int n = 0; n < 4; n++)
            acc[m][n] = __builtin_amdgcn_mfma_f32_16x16x32_bf16(af[m], bfr[n], acc[m][n], 0, 0, 0);
    };

    AReg rE, rO;
    // prologue: A(0)->rE, B(0)->buf0, A(1)->rO, B(1)->buf1
    LOADA(rE, 0);  STAGEB(0, 0);
    LOADA(rO, 32); STAGEB(1, 32);
    int cur = 0;
    #pragma unroll 1
    for (int tt = 0; tt < NT; tt += 2) {
        // ---- tile tt (even): consumes rE ----
        WRITEA(cur, rE);                     // compiler waits rE's loads
        __builtin_amdgcn_sched_barrier(0);
        LOADA(rE, (tt + 2) * 32);            // A for tile tt+2
        STAGEB((cur + 2) % 3, (tt + 2) * 32);
        __builtin_amdgcn_sched_barrier(0);
        asm volatile("s_waitcnt vmcnt(12)" ::: "memory");   // B(tt) landed
        asm volatile("s_waitcnt lgkmcnt(0)" ::: "memory");  // my A writes visible
        __builtin_amdgcn_sched_barrier(0);
        __builtin_amdgcn_s_barrier();
        COMPUTE(cur);
        __builtin_amdgcn_s_barrier();
        __builtin_amdgcn_sched_barrier(0);
        cur = (cur + 1) % 3;
        // ---- tile tt+1 (odd): consumes rO ----
        WRITEA(cur, rO);
        __builtin_amdgcn_sched_barrier(0);
        LOADA(rO, (tt + 3) * 32);
        STAGEB((cur + 2) % 3, (tt + 3) * 32);
        __builtin_amdgcn_sched_barrier(0);
        asm volatile("s_waitcnt vmcnt(12)" ::: "memory");
        asm volatile("s_waitcnt lgkmcnt(0)" ::: "memory");
        __builtin_amdgcn_sched_barrier(0);
        __builtin_amdgcn_s_barrier();
        COMPUTE(cur);
        __builtin_amdgcn_s_barrier();
        __builtin_amdgcn_sched_barrier(0);
        cur = (cur + 1) % 3;
    }

    const int cIn = lane & 15, r4 = (lane >> 4) * 4;
    #pragma unroll
    for (int n = 0; n < 4; n++) {
        int col = bn0 + wn * 64 + n * 16 + cIn;
        float bv = bias ? bias[col] : 0.f;
        #pragma unroll
        for (int m = 0; m < 4; m++) {
            #pragma unroll
            for (int r = 0; r < 4; r++) {
                int rowg = bm0 + wm * 64 + m * 16 + r4 + r;
                float vv = acc[m][n][r] + bv;
                if (OUTBF) ((u16*)C)[(size_t)rowg * N + col] = f2b(vv);
                else       ((float*)C)[(size_t)rowg * N + col] = vv;
            }
        }
    }
}

// ---------------- batched weight prep: LDS-tiled transposes + bias copies ---
struct ConvJob { const float* W; u16* Wt; int ldw, k0, n0, K, tile_start, tiles_k; };
struct CopyJob { const float* src; float* dst; int n; };
struct BatchArgs { ConvJob cj[17]; CopyJob cp[5]; int conv_blocks; };

__global__ __launch_bounds__(256) void k_prep(BatchArgs a)
{
    __shared__ float ls[64][65];
    int b = blockIdx.x;
    int t = threadIdx.x;
    if (b < a.conv_blocks) {
        int j = 0;
        #pragma unroll 1
        while (j + 1 < 17 && a.cj[j + 1].tile_start <= b) ++j;
        const ConvJob J = a.cj[j];
        int local = b - J.tile_start;
        int tk = local % J.tiles_k, tn = local / J.tiles_k;
        int k0 = tk * 64, n0 = tn * 64;
        int cn = t & 63, rk = t >> 6;
        #pragma unroll
        for (int p = 0; p < 16; p++) {
            int kk = p * 4 + rk;
            ls[kk][cn] = J.W[(size_t)(J.k0 + k0 + kk) * J.ldw + J.n0 + n0 + cn];
        }
        __syncthreads();
        int ck = t & 63, rn = t >> 6;
        #pragma unroll
        for (int p = 0; p < 16; p++) {
            int nn = p * 4 + rn;
            J.Wt[(size_t)(n0 + nn) * J.K + k0 + ck] = f2b(ls[ck][nn]);
        }
    } else {
        int c = b - a.conv_blocks;
        const CopyJob C = a.cp[c];
        for (int i = t; i < C.n; i += 256) C.dst[i] = C.src[i];
    }
}

// ---------------- silu -> bf16 (vectorized, grid-stride) --------------------
__global__ void k_silu_bf(const float* __restrict__ in, u16* __restrict__ out, int n4)
{
    int i = blockIdx.x * 256 + threadIdx.x;
    int stride = gridDim.x * 256;
    for (; i < n4; i += stride) {
        f32x4 v = *(const f32x4*)(in + (size_t)i * 4);
        u16x4 o;
        #pragma unroll
        for (int j = 0; j < 4; j++) o[j] = f2b(siluf(v[j]));
        *(u16x4*)(out + (size_t)i * 4) = o;
    }
}

// ---------------- edge preprocessing (64 edges per block) -------------------
__global__ __launch_bounds__(256) void k_edge_pre(
    const float* __restrict__ pos, const float* __restrict__ edge_attr,
    const int* __restrict__ ei, const float* __restrict__ W_ee,
    const float* __restrict__ b_ee, const float* __restrict__ coors_scale,
    const u16* __restrict__ etf,
    u16* __restrict__ ea_mod, float* __restrict__ dist, float* __restrict__ cdiff)
{
    __shared__ float Ws[65][64];
    int t = threadIdx.x;
    for (int i = t; i < 65 * 64; i += 256) Ws[i >> 6][i & 63] = W_ee[i];
    __syncthreads();
    int l = t & 63;
    float bee = b_ee[l];
    float cscale = coors_scale[0];
    for (int g = 0; g < 16; g++) {
        int e = blockIdx.x * 64 + g * 4 + (t >> 6);
        int row = ei[e], col = ei[E_CNT + e];
        float d0 = pos[row * 3 + 0] - pos[col * 3 + 0];
        float d1 = pos[row * 3 + 1] - pos[col * 3 + 1];
        float d2 = pos[row * 3 + 2] - pos[col * 3 + 2];
        float ssq = d0 * d0 + d1 * d1 + d2 * d2;
        float dst = sqrtf(ssq + 1e-12f);
        float nrm = sqrtf(ssq);
        float cs = cscale / fmaxf(nrm, 1e-8f);
        if (l == 0) {
            dist[e] = dst;
            cdiff[e * 3 + 0] = d0 * cs; cdiff[e * 3 + 1] = d1 * cs; cdiff[e * 3 + 2] = d2 * cs;
        }
        float attr = edge_attr[(size_t)e * 64 + l];
        float acc = dst * Ws[0][l];
        for (int f = 0; f < 64; f++) acc += __shfl(attr, f) * Ws[1 + f][l];
        acc += bee;
        float y = wave_ln64(acc);
        const u16* ep = etf + (size_t)e * 896;
        float m = y * (1.f + b2f(ep[64 + l])) + b2f(ep[l]);
        ea_mod[(size_t)e * 64 + l] = f2b(m);
    }
}

// ---------------- node: hh = modulate(ln(h), sh_msa, sc_msa) -> bf16 --------
__global__ __launch_bounds__(256) void k_node_hh(
    const float* __restrict__ h, const float* __restrict__ nt, u16* __restrict__ hh)
{
    int n = blockIdx.x, c = threadIdx.x;
    float x = h[(size_t)n * 256 + c];
    float y = block_ln256(x);
    float m = y * (1.f + nt[(size_t)n * 1536 + 256 + c]) + nt[(size_t)n * 1536 + c];
    hh[(size_t)n * 256 + c] = f2b(m);
}

// ---------------- fused per-node: alpha + softmax + aggregation -------------
// qkv: [BN,768] f32 (q|k|v); e01: [E,512] bf16 (e0|e1)
__global__ __launch_bounds__(256) void k_agg(
    const float* __restrict__ qkv, const u16* __restrict__ e01,
    float* __restrict__ hnode, u16* __restrict__ hnode_bf)
{
    int n = blockIdx.x;
    int b = n / 48, i = n % 48;
    int t = threadIdx.x;
    __shared__ float qs[8][33];
    __shared__ float att[47][8];
    __shared__ float mxs[8], dens[8];
    __shared__ int elist[47], slist[47];
    qs[t >> 5][t & 31] = qkv[(size_t)n * 768 + t];
    if (t < 47) {
        int s = t + (t >= i ? 1 : 0);
        slist[t] = s;
        elist[t] = b * EPG + s * 47 + (i < s ? i : i - 1);
    }
    __syncthreads();
    for (int idx = t; idx < 376; idx += 256) {
        int j = idx >> 3, hh = idx & 7;
        int src = b * 48 + slist[j];
        int e = elist[j];
        const float* kp = qkv + (size_t)src * 768 + 256 + hh * 32;
        const u16* ep = e01 + (size_t)e * 512 + hh * 32;
        float p = 0.f;
        #pragma unroll
        for (int d = 0; d < 32; d++) p += qs[hh][d] * kp[d] * b2f(ep[d]);
        att[j][hh] = p * 0.17677669529663687f; // 1/sqrt(32)
    }
    __syncthreads();
    if (t < 8) {
        float m = -1e30f;
        for (int j = 0; j < 47; j++) m = fmaxf(m, att[j][t]);
        float den = 0.f;
        for (int j = 0; j < 47; j++) den += expf(att[j][t] - m);
        mxs[t] = m; dens[t] = den + 1e-16f;
    }
    __syncthreads();
    for (int idx = t; idx < 376; idx += 256) {
        int j = idx >> 3, hh = idx & 7;
        att[j][hh] = expf(att[j][hh] - mxs[hh]) / dens[hh];
    }
    __syncthreads();
    int c = t, hh = t >> 5;
    float acc = 0.f;
    for (int j = 0; j < 47; j++) {
        int src = b * 48 + slist[j];
        int e = elist[j];
        acc += att[j][hh] * qkv[(size_t)src * 768 + 512 + c] * b2f(e01[(size_t)e * 512 + 256 + c]);
    }
    hnode[(size_t)n * 256 + c] = acc;
    hnode_bf[(size_t)n * 256 + c] = f2b(acc);
}

// ---------------- node: residual + LN + modulate(mlp) * mask ----------------
__global__ __launch_bounds__(256) void k_node_mod(
    const float* __restrict__ h, const float* __restrict__ hnode_raw,
    const float* __restrict__ nt, const float* __restrict__ mask,
    float* __restrict__ hmod, u16* __restrict__ hmod_bf)
{
    int n = blockIdx.x, c = threadIdx.x;
    float x = h[(size_t)n * 256 + c] + nt[(size_t)n * 1536 + 512 + c] * hnode_raw[(size_t)n * 256 + c];
    float y = block_ln256(x);
    float m = (y * (1.f + nt[(size_t)n * 1536 + 1024 + c]) + nt[(size_t)n * 1536 + 768 + c]) * mask[n];
    hmod[(size_t)n * 256 + c] = m;
    hmod_bf[(size_t)n * 256 + c] = f2b(m);
}

// ---------------- node output ------------------------------------------------
__global__ void k_hout(const float* __restrict__ hmod, const float* __restrict__ ff2,
                       const float* __restrict__ nt, const float* __restrict__ mask,
                       float* __restrict__ out, u16* __restrict__ hout_bf)
{
    int i = blockIdx.x * 256 + threadIdx.x;
    if (i >= BN_CNT * 256) return;
    int n = i >> 8, c = i & 255;
    float v = (hmod[i] + nt[(size_t)n * 1536 + 1280 + c] * ff2[i]) * mask[n];
    out[i] = v;
    hout_bf[i] = f2b(v);
}

// ---------------- edge: h_e = edge_attr + g*h_edge; LN; modulate ------------
__global__ __launch_bounds__(256) void k_edge_mod(
    const float* __restrict__ Q1, const float* __restrict__ b_n2e,
    const float* __restrict__ edge_attr, const int* __restrict__ ei,
    const u16* __restrict__ etf, float* __restrict__ hemod, u16* __restrict__ hemod_bf)
{
    int e = blockIdx.x * 4 + (threadIdx.x >> 6);
    int l = threadIdx.x & 63;
    int row = ei[e], col = ei[E_CNT + e];
    float hedge = Q1[(size_t)row * 64 + l] + Q1[(size_t)col * 64 + l] + b_n2e[l];
    const u16* ep = etf + (size_t)e * 896;
    float x = edge_attr[(size_t)e * 64 + l] + b2f(ep[128 + l]) * hedge;
    float y = wave_ln64(x);
    float m = y * (1.f + b2f(ep[256 + l])) + b2f(ep[192 + l]);
    hemod[(size_t)e * 64 + l] = m;
    hemod_bf[(size_t)e * 64 + l] = f2b(m);
}

// ---------------- edge output ------------------------------------------------
__global__ void k_edge_out(const float* __restrict__ hemod, const float* __restrict__ ff4,
                           const u16* __restrict__ etf,
                           float* __restrict__ out2, u16* __restrict__ heout_bf)
{
    size_t i = (size_t)blockIdx.x * 256 + threadIdx.x;
    if (i >= (size_t)E_CNT * 64) return;
    int e = (int)(i >> 6), c = (int)(i & 63);
    float v = hemod[i] + b2f(etf[(size_t)e * 896 + 320 + c]) * ff4[i];
    out2[i] = v;
    heout_bf[i] = f2b(v);
}

// ---------------- CondEquiUpdate: assemble invariant input, LN, modulate ----
// p12: [BN,512] f32 (P1|P2)
__global__ __launch_bounds__(256) void k_inv_pre(
    const float* __restrict__ p12,
    const u16* __restrict__ P3, const float* __restrict__ dist,
    const float* __restrict__ W_ui, const float* __restrict__ b_ui,
    const int* __restrict__ ei, const u16* __restrict__ etf, u16* __restrict__ invmod)
{
    int e = blockIdx.x, c = threadIdx.x;
    int row = ei[e], col = ei[E_CNT + e];
    float x = p12[(size_t)row * 512 + c] + p12[(size_t)col * 512 + 256 + c]
            + b2f(P3[(size_t)e * 256 + c]) + dist[e] * W_ui[576 * 256 + c] + b_ui[c];
    float y = block_ln256(x);
    const u16* ep = etf + (size_t)e * 896;
    float m = y * (1.f + b2f(ep[640 + c])) + b2f(ep[384 + c]);
    invmod[(size_t)e * 256 + c] = f2b(m);
}

// ---------------- final per-edge scalar: tanh( silu(y) . W_uc2 ) ------------
__global__ __launch_bounds__(256) void k_inv(const u16* __restrict__ uc1,
                                             const float* __restrict__ W_uc2,
                                             float* __restrict__ inv)
{
    int e = blockIdx.x * 4 + (threadIdx.x >> 6);
    int l = threadIdx.x & 63;
    u16x4 v = *(const u16x4*)(uc1 + (size_t)e * 256 + l * 4);
    const float* w = W_uc2 + l * 4;
    float s = b2f(v[0]) * w[0] + b2f(v[1]) * w[1] + b2f(v[2]) * w[2] + b2f(v[3]) * w[3];
    #pragma unroll
    for (int off = 1; off < 64; off <<= 1) s += __shfl_xor(s, off);
    if (l == 0) inv[e] = tanhf(s);
}

// ---------------- pos update: deterministic contiguous segment sum ----------
__global__ void k_pos(const float* __restrict__ pos, const float* __restrict__ cdiff,
                      const float* __restrict__ inv, float* __restrict__ out3)
{
    int n = blockIdx.x * 256 + threadIdx.x;
    if (n >= BN_CNT) return;
    int b = n / 48, s = n % 48;
    int e0 = b * EPG + s * 47;
    float a0 = 0.f, a1 = 0.f, a2 = 0.f;
    for (int j = 0; j < 47; j++) {
        float f = inv[e0 + j];
        a0 += cdiff[(size_t)(e0 + j) * 3 + 0] * f;
        a1 += cdiff[(size_t)(e0 + j) * 3 + 1] * f;
        a2 += cdiff[(size_t)(e0 + j) * 3 + 2] * f;
    }
    out3[n * 3 + 0] = pos[n * 3 + 0] + a0;
    out3[n * 3 + 1] = pos[n * 3 + 1] + a1;
    out3[n * 3 + 2] = pos[n * 3 + 2] + a2;
}

extern "C" void kernel_launch(void* const* d_in, const int* in_sizes, int n_in,
                              void* d_out, int out_size, void* d_ws, size_t ws_size,
                              hipStream_t stream)
{
    (void)in_sizes; (void)n_in; (void)out_size; (void)ws_size;
    const float* pos       = (const float*)d_in[0];
    const float* h         = (const float*)d_in[1];
    const float* edge_attr = (const float*)d_in[2];
    const float* node_mask = (const float*)d_in[3];
    const float* nte       = (const float*)d_in[4];
    const float* ete       = (const float*)d_in[5];
    const int*   ei        = (const int*)d_in[6];
    const float* W_ee = (const float*)d_in[7];  const float* b_ee = (const float*)d_in[8];
    const float* W_nt = (const float*)d_in[9];  const float* b_nt = (const float*)d_in[10];
    const float* W_et = (const float*)d_in[11]; const float* b_et = (const float*)d_in[12];
    const float* Wq  = (const float*)d_in[13];  const float* bq  = (const float*)d_in[14];
    const float* Wk  = (const float*)d_in[15];  const float* bk  = (const float*)d_in[16];
    const float* Wv  = (const float*)d_in[17];  const float* bv  = (const float*)d_in[18];
    const float* We0 = (const float*)d_in[19];  const float* We1 = (const float*)d_in[20];
    const float* W_n2e = (const float*)d_in[21]; const float* b_n2e = (const float*)d_in[22];
    const float* W_ff1 = (const float*)d_in[23]; const float* b_ff1 = (const float*)d_in[24];
    const float* W_ff2 = (const float*)d_in[25]; const float* b_ff2 = (const float*)d_in[26];
    const float* W_ff3 = (const float*)d_in[27]; const float* b_ff3 = (const float*)d_in[28];
    const float* W_ff4 = (const float*)d_in[29]; const float* b_ff4 = (const float*)d_in[30];
    const float* coors_scale = (const float*)d_in[31];
    const float* W_ut = (const float*)d_in[32]; const float* b_ut = (const float*)d_in[33];
    const float* W_ui = (const float*)d_in[34]; const float* b_ui = (const float*)d_in[35];
    const float* W_uc1 = (const float*)d_in[36]; const float* b_uc1 = (const float*)d_in[37];
    const float* W_uc2 = (const float*)d_in[38];

    const size_t E = E_CNT;
    char* ws = (char*)d_ws;
    size_t off = 0;
    auto AL = [&](size_t b) { size_t o = off; off += (b + 255) & ~(size_t)255; return o; };

    // weights (bf16, transposed [N,K])
    size_t o_wtcat  = AL(896 * 1024 * 2);
    size_t o_wtnt   = AL(1536 * 1024 * 2);
    size_t o_wtqkv  = AL(768 * 256 * 2);
    size_t o_wte01  = AL(512 * 64 * 2);
    size_t o_wtn2e  = AL(64 * 256 * 2);
    size_t o_wtff1  = AL(512 * 256 * 2), o_wtff2 = AL(256 * 512 * 2);
    size_t o_wtff3  = AL(128 * 64 * 2),  o_wtff4 = AL(64 * 128 * 2);
    size_t o_wtuiab = AL(512 * 256 * 2);
    size_t o_wtuic  = AL(256 * 64 * 2),  o_wtuc1 = AL(256 * 256 * 2);
    size_t o_bias896 = AL(896 * 4);
    size_t o_bias768 = AL(768 * 4);
    // big regions (lifetime-based aliasing)
    size_t o_reg1 = AL(E * 1024 * 2);          // P3/invmod/uc1o region
    size_t o_etf  = AL(E * 896 * 2);           // persistent
    size_t o_ntes = AL(1536 * 1024 * 2);
    size_t o_ntf  = AL((size_t)1536 * 1536 * 4);
    size_t o_eamod = AL(E * 64 * 2);
    size_t o_dist = AL(E * 4), o_cdiff = AL(E * 12);
    size_t o_qkv  = AL(1536 * 768 * 4);
    size_t o_reg3 = AL(E * 512 * 2);           // e01 -> later ffem/ff4o/heoutbf
    size_t o_hnode = AL(1536 * 256 * 4), o_hnodebf = AL(1536 * 256 * 2);
    size_t o_q1 = AL(1536 * 64 * 4);
    size_t o_hh = AL(1536 * 256 * 2);
    size_t o_hmod = AL(1536 * 256 * 4), o_hmodbf = AL(1536 * 256 * 2);
    size_t o_ff1 = AL(1536 * 512 * 2), o_ff2 = AL(1536 * 256 * 4);
    size_t o_houtbf = AL(1536 * 256 * 2);
    size_t o_hemod = AL(E * 64 * 4), o_hemodbf = AL(E * 64 * 2);
    size_t o_p12 = AL(1536 * 512 * 4);
    size_t o_inv = AL(E * 4);
    // aliases
    size_t o_p3 = o_reg1;
    size_t o_invmod = o_reg1 + E * 256 * 2;
    size_t o_uc1o = o_reg1 + E * 256 * 4;
    size_t o_e01 = o_reg3;
    size_t o_ffem = o_reg3;
    size_t o_ff4o = o_reg3 + E * 128 * 2;
    size_t o_heoutbf = o_reg3 + E * 128 * 2 + E * 64 * 4;

    #define WSU(o) ((u16*)(ws + (o)))
    #define WSF(o) ((float*)(ws + (o)))

    // --- batched weight prep (17 tiled transposes + 5 bias copies) ---
    {
        BatchArgs a;
        int s = 0; int j = 0;
        auto add = [&](const float* W, u16* Wt, int ldw, int k0, int n0, int K, int NC) {
            a.cj[j++] = ConvJob{W, Wt, ldw, k0, n0, K, s, K / 64};
            s += (K / 64) * (NC / 64);
        };
        add(W_et, WSU(o_wtcat), 384, 0, 0, 1024, 384);
        add(W_ut, WSU(o_wtcat) + (size_t)384 * 1024, 512, 0, 0, 1024, 512);
        add(W_nt, WSU(o_wtnt), 1536, 0, 0, 1024, 1536);
        add(Wq, WSU(o_wtqkv), 256, 0, 0, 256, 256);
        add(Wk, WSU(o_wtqkv) + (size_t)256 * 256, 256, 0, 0, 256, 256);
        add(Wv, WSU(o_wtqkv) + (size_t)512 * 256, 256, 0, 0, 256, 256);
        add(We0, WSU(o_wte01), 256, 0, 0, 64, 256);
        add(We1, WSU(o_wte01) + (size_t)256 * 64, 256, 0, 0, 64, 256);
        add(W_n2e, WSU(o_wtn2e), 64, 0, 0, 256, 64);
        add(W_ff1, WSU(o_wtff1), 512, 0, 0, 256, 512);
        add(W_ff2, WSU(o_wtff2), 256, 0, 0, 512, 256);
        add(W_ff3, WSU(o_wtff3), 128, 0, 0, 64, 128);
        add(W_ff4, WSU(o_wtff4), 64, 0, 0, 128, 64);
        add(W_ui, WSU(o_wtuiab), 256, 0, 0, 256, 256);
        add(W_ui, WSU(o_wtuiab) + (size_t)256 * 256, 256, 256, 0, 256, 256);
        add(W_ui, WSU(o_wtuic), 256, 512, 0, 64, 256);
        add(W_uc1, WSU(o_wtuc1), 256, 0, 0, 256, 256);
        a.conv_blocks = s;  // 788 tiles
        a.cp[0] = CopyJob{b_et, WSF(o_bias896), 384};
        a.cp[1] = CopyJob{b_ut, WSF(o_bias896) + 384, 512};
        a.cp[2] = CopyJob{bq, WSF(o_bias768), 256};
        a.cp[3] = CopyJob{bk, WSF(o_bias768) + 256, 256};
        a.cp[4] = CopyJob{bv, WSF(o_bias768) + 512, 256};
        k_prep<<<s + 5, 256, 0, stream>>>(a);
    }

    // --- silu -> bf16 (node time emb only; edge silu fused into et GEMM) ---
    k_silu_bf<<<1024, 256, 0, stream>>>(nte, WSU(o_ntes), 1536 * 1024 / 4);

    // --- big time-embedding GEMMs ---
    k_gemm128_fs<1><<<dim3(7, 564), 256, 0, stream>>>(
        ete, WSU(o_wtcat), WSF(o_bias896), WSU(o_etf), E_CNT, 896, 1024);
    k_gemm128<0, 0><<<dim3(12, 12), 256, 0, stream>>>(
        WSU(o_ntes), WSU(o_wtnt), b_nt, WSF(o_ntf), 1536, 1536, 1024);

    // --- edge preprocess ---
    k_edge_pre<<<1128, 256, 0, stream>>>(pos, edge_attr, ei, W_ee, b_ee, coors_scale,
                                         WSU(o_etf), WSU(o_eamod), WSF(o_dist), WSF(o_cdiff));

    // --- node attention path ---
    k_node_hh<<<1536, 256, 0, stream>>>(h, WSF(o_ntf), WSU(o_hh));
    k_gemm<0, 0><<<dim3(12, 24), 256, 0, stream>>>(WSU(o_hh), WSU(o_wtqkv), WSF(o_bias768), WSF(o_qkv), 1536, 768, 256);
    k_gemm128<0, 1><<<dim3(4, 564), 256, 0, stream>>>(WSU(o_eamod), WSU(o_wte01), nullptr, WSU(o_e01), E_CNT, 512, 64);
    k_agg<<<1536, 256, 0, stream>>>(WSF(o_qkv), WSU(o_e01), WSF(o_hnode), WSU(o_hnodebf));

    // --- Q1 = h_node_raw @ W_n2e ---
    k_gemm<0, 0><<<dim3(1, 24), 256, 0, stream>>>(WSU(o_hnodebf), WSU(o_wtn2e), nullptr, WSF(o_q1), 1536, 64, 256);

    // --- node FFN + output ---
    k_node_mod<<<1536, 256, 0, stream>>>(h, WSF(o_hnode), WSF(o_ntf), node_mask, WSF(o_hmod), WSU(o_hmodbf));
    k_gemm<1, 1><<<dim3(8, 24), 256, 0, stream>>>(WSU(o_hmodbf), WSU(o_wtff1), b_ff1, WSU(o_ff1), 1536, 512, 256);
    k_gemm<0, 0><<<dim3(4, 24), 256, 0, stream>>>(WSU(o_ff1), WSU(o_wtff2), b_ff2, WSF(o_ff2), 1536, 256, 512);
    k_hout<<<1536, 256, 0, stream>>>(WSF(o_hmod), WSF(o_ff2), WSF(o_ntf), node_mask, (float*)d_out, WSU(o_houtbf));

    // --- edge FFN + output ---
    k_edge_mod<<<18048, 256, 0, stream>>>(WSF(o_q1), b_n2e, edge_attr, ei, WSU(o_etf), WSF(o_hemod), WSU(o_hemodbf));
    k_gemm128<1, 1><<<dim3(1, 564), 256, 0, stream>>>(WSU(o_hemodbf), WSU(o_wtff3), b_ff3, WSU(o_ffem), E_CNT, 128, 64);
    k_gemm<0, 0><<<dim3(1, 1128), 256, 0, stream>>>(WSU(o_ffem), WSU(o_wtff4), b_ff4, WSF(o_ff4o), E_CNT, 64, 128);
    k_edge_out<<<18048, 256, 0, stream>>>(WSF(o_hemod), WSF(o_ff4o), WSU(o_etf),
                                          (float*)d_out + 393216, WSU(o_heoutbf));

    // --- CondEquiUpdate ---
    k_gemm<0, 0><<<dim3(8, 24), 256, 0, stream>>>(WSU(o_houtbf), WSU(o_wtuiab), nullptr, WSF(o_p12), 1536, 512, 256);
    k_gemm128<0, 1><<<dim3(2, 564), 256, 0, stream>>>(WSU(o_heoutbf), WSU(o_wtuic), nullptr, WSU(o_p3), E_CNT, 256, 64);
    k_inv_pre<<<E_CNT, 256, 0, stream>>>(WSF(o_p12), WSU(o_p3), WSF(o_dist),
                                         W_ui, b_ui, ei, WSU(o_etf), WSU(o_invmod));
    k_gemm128<1, 1><<<dim3(2, 564), 256, 0, stream>>>(WSU(o_invmod), WSU(o_wtuc1), b_uc1, WSU(o_uc1o), E_CNT, 256, 256);
    k_inv<<<18048, 256, 0, stream>>>(WSU(o_uc1o), W_uc2, WSF(o_inv));
    k_pos<<<6, 256, 0, stream>>>(pos, WSF(o_cdiff), WSF(o_inv), (float*)d_out + 393216 + E_CNT * 64);

    #undef WSU
    #undef WSF
}

// Round 13
// 745.209 us; speedup vs baseline: 1.2794x; 1.2794x over previous
//
#include <hip/hip_runtime.h>

typedef unsigned short u16;
typedef __attribute__((ext_vector_type(4))) u16 u16x4;
typedef __attribute__((ext_vector_type(8))) u16 u16x8;
typedef __attribute__((ext_vector_type(8))) short s16x8;
typedef __attribute__((ext_vector_type(4))) float f32x4;

#define E_CNT 72192
#define BN_CNT 1536
// edges per graph = 48*47
#define EPG 2256

__device__ __forceinline__ float b2f(u16 u) {
    union { unsigned int i; float f; } x; x.i = ((unsigned int)u) << 16; return x.f;
}
__device__ __forceinline__ u16 f2b(float f) {
    union { float f; unsigned int i; } x; x.f = f;
    unsigned int r = x.i + 0x7fffu + ((x.i >> 16) & 1u);
    return (u16)(r >> 16);
}
__device__ __forceinline__ float siluf(float x) { return x / (1.f + expf(-x)); }

// async global->LDS, 16B per lane (linear dest). (guide §5 / m97)
__device__ __forceinline__ void gll16(const void* g, void* l) {
    __builtin_amdgcn_global_load_lds(
        (const __attribute__((address_space(1))) void*)g,
        (__attribute__((address_space(3))) void*)l, 16, 0, 0);
}

// ---------------- wave (64-lane) LayerNorm, eps 1e-6, no affine -------------
__device__ __forceinline__ float wave_ln64(float x) {
    float s = x;
    #pragma unroll
    for (int off = 1; off < 64; off <<= 1) s += __shfl_xor(s, off);
    float mean = s * 0.015625f;
    float d = x - mean;
    float v2 = d * d;
    #pragma unroll
    for (int off = 1; off < 64; off <<= 1) v2 += __shfl_xor(v2, off);
    return d * rsqrtf(v2 * 0.015625f + 1e-6f);
}

// ---------------- block(256)-wide LayerNorm over 256 dims -------------------
__device__ __forceinline__ float block_ln256(float x) {
    __shared__ float tmp[4];
    int t = threadIdx.x;
    float s = x;
    #pragma unroll
    for (int off = 1; off < 64; off <<= 1) s += __shfl_xor(s, off);
    if ((t & 63) == 0) tmp[t >> 6] = s;
    __syncthreads();
    float mean = (tmp[0] + tmp[1] + tmp[2] + tmp[3]) * (1.f / 256.f);
    float d = x - mean;
    float v2 = d * d;
    #pragma unroll
    for (int off = 1; off < 64; off <<= 1) v2 += __shfl_xor(v2, off);
    __syncthreads();
    if ((t & 63) == 0) tmp[t >> 6] = v2;
    __syncthreads();
    float var = (tmp[0] + tmp[1] + tmp[2] + tmp[3]) * (1.f / 256.f);
    return d * rsqrtf(var + 1e-6f);
}

// ---------------- generic bf16 MFMA GEMM, 64x64 tile ------------------------
template<int ACT, int OUTBF>
__global__ __launch_bounds__(256) void k_gemm(
    const u16* __restrict__ A, const u16* __restrict__ Bt,
    const float* __restrict__ bias, void* __restrict__ C,
    int M, int N, int K)
{
    __shared__ u16 As[64][40];
    __shared__ u16 Bs[64][40];
    int bn0 = blockIdx.x * 64, bm0 = blockIdx.y * 64;
    int t = threadIdx.x;
    int lane = t & 63, wave = t >> 6;
    int wm = wave >> 1, wn = wave & 1;
    int lr = t >> 2, lc = (t & 3) * 8;
    f32x4 acc[2][2] = {};
    const u16* Ap = A + (size_t)(bm0 + lr) * K + lc;
    const u16* Bp = Bt + (size_t)(bn0 + lr) * K + lc;
    int fr = lane & 15, fk = (lane >> 4) * 8;
    for (int k0 = 0; k0 < K; k0 += 32) {
        *(u16x8*)&As[lr][lc] = *(const u16x8*)(Ap + k0);
        *(u16x8*)&Bs[lr][lc] = *(const u16x8*)(Bp + k0);
        __syncthreads();
        s16x8 a0 = *(const s16x8*)&As[wm * 32 + fr][fk];
        s16x8 a1 = *(const s16x8*)&As[wm * 32 + 16 + fr][fk];
        s16x8 b0 = *(const s16x8*)&Bs[wn * 32 + fr][fk];
        s16x8 b1 = *(const s16x8*)&Bs[wn * 32 + 16 + fr][fk];
        acc[0][0] = __builtin_amdgcn_mfma_f32_16x16x32_bf16(a0, b0, acc[0][0], 0, 0, 0);
        acc[0][1] = __builtin_amdgcn_mfma_f32_16x16x32_bf16(a0, b1, acc[0][1], 0, 0, 0);
        acc[1][0] = __builtin_amdgcn_mfma_f32_16x16x32_bf16(a1, b0, acc[1][0], 0, 0, 0);
        acc[1][1] = __builtin_amdgcn_mfma_f32_16x16x32_bf16(a1, b1, acc[1][1], 0, 0, 0);
        __syncthreads();
    }
    int cIn = lane & 15, r4 = (lane >> 4) * 4;
    #pragma unroll
    for (int i = 0; i < 2; i++)
    #pragma unroll
    for (int j = 0; j < 2; j++) {
        int col = bn0 + wn * 32 + j * 16 + cIn;
        float bv = bias ? bias[col] : 0.f;
        #pragma unroll
        for (int r = 0; r < 4; r++) {
            int rowg = bm0 + wm * 32 + i * 16 + r4 + r;
            float vv = acc[i][j][r] + bv;
            if (ACT == 1) vv = siluf(vv);
            if (OUTBF) ((u16*)C)[(size_t)rowg * N + col] = f2b(vv);
            else       ((float*)C)[(size_t)rowg * N + col] = vv;
        }
    }
}

// ---------------- 128x128 tile bf16 MFMA GEMM, 3-deep pipelined -------------
// (r5/r6 verified structure: counted vmcnt + both-sides chunk-XOR swizzle,
// bank conflicts = 0, best measured config for the E-row GEMMs)
template<int ACT, int OUTBF>
__global__ __launch_bounds__(256) void k_gemm128(
    const u16* __restrict__ A, const u16* __restrict__ Bt,
    const float* __restrict__ bias, void* __restrict__ C,
    int M, int N, int K)
{
    __shared__ u16 As[3][128 * 32];
    __shared__ u16 Bs[3][128 * 32];
    const int t = threadIdx.x;
    const int lane = t & 63, wv = t >> 6;
    const int wm = wv >> 1, wn = wv & 1;
    const int nwg = gridDim.x * gridDim.y;
    const int orig = blockIdx.y * gridDim.x + blockIdx.x;
    const int q8 = nwg >> 3, r8 = nwg & 7;
    const int xcd = orig & 7, lin = orig >> 3;
    const int wgid = (xcd < r8 ? xcd * (q8 + 1) : r8 * (q8 + 1) + (xcd - r8) * q8) + lin;
    const int bxs = wgid % gridDim.x, bys = wgid / gridDim.x;
    const int bn0 = bxs * 128, bm0 = bys * 128;
    const int srow = t >> 2;
    const int scol = ((t & 3) ^ ((t >> 3) & 3)) * 8;
    const u16* Ap = A + (size_t)(bm0 + srow) * K + scol;
    const u16* Bp = Bt + (size_t)(bn0 + srow) * K + scol;
    const size_t rstep = (size_t)64 * K;
    const int woff = wv * 16 * 32;
    const int fr = lane & 15;
    const int fkc = (((lane >> 4) ^ ((fr >> 1) & 3)) * 8);
    f32x4 acc[4][4] = {};
    const int NT = K >> 5;

    auto STAGE = [&](int b, int ko) {
        gll16(Ap + ko, &As[b][woff]);
        gll16(Ap + ko + rstep, &As[b][woff + 64 * 32]);
        gll16(Bp + ko, &Bs[b][woff]);
        gll16(Bp + ko + rstep, &Bs[b][woff + 64 * 32]);
    };
    auto COMPUTE = [&](int b) {
        const u16* aBase = &As[b][wm * 64 * 32];
        const u16* bBase = &Bs[b][wn * 64 * 32];
        s16x8 af[4], bfr[4];
        #pragma unroll
        for (int m = 0; m < 4; m++) af[m] = *(const s16x8*)&aBase[(m * 16 + fr) * 32 + fkc];
        #pragma unroll
        for (int n = 0; n < 4; n++) bfr[n] = *(const s16x8*)&bBase[(n * 16 + fr) * 32 + fkc];
        #pragma unroll
        for (int m = 0; m < 4; m++)
        #pragma unroll
        for (int n = 0; n < 4; n++)
            acc[m][n] = __builtin_amdgcn_mfma_f32_16x16x32_bf16(af[m], bfr[n], acc[m][n], 0, 0, 0);
    };

    STAGE(0, 0);
    if (NT > 1) STAGE(1, 32);
    int cur = 0;
    for (int tt = 0; tt < NT; tt++) {
        if (tt + 2 < NT) STAGE((cur + 2) % 3, (tt + 2) * 32);
        __builtin_amdgcn_sched_barrier(0);
        int ahead = NT - 1 - tt; if (ahead > 2) ahead = 2;
        if (ahead == 2)      asm volatile("s_waitcnt vmcnt(8)" ::: "memory");
        else if (ahead == 1) asm volatile("s_waitcnt vmcnt(4)" ::: "memory");
        else                 asm volatile("s_waitcnt vmcnt(0)" ::: "memory");
        __builtin_amdgcn_sched_barrier(0);
        __builtin_amdgcn_s_barrier();
        COMPUTE(cur);
        __builtin_amdgcn_s_barrier();
        __builtin_amdgcn_sched_barrier(0);
        cur = (cur + 1) % 3;
    }

    const int cIn = lane & 15, r4 = (lane >> 4) * 4;
    #pragma unroll
    for (int n = 0; n < 4; n++) {
        int col = bn0 + wn * 64 + n * 16 + cIn;
        float bv = bias ? bias[col] : 0.f;
        #pragma unroll
        for (int m = 0; m < 4; m++) {
            #pragma unroll
            for (int r = 0; r < 4; r++) {
                int rowg = bm0 + wm * 64 + m * 16 + r4 + r;
                float vv = acc[m][n][r] + bv;
                if (ACT == 1) vv = siluf(vv);
                if (OUTBF) ((u16*)C)[(size_t)rowg * N + col] = f2b(vv);
                else       ((float*)C)[(size_t)rowg * N + col] = vv;
            }
        }
    }
}

// ---------------- batched weight prep: LDS-tiled transposes + bias copies ---
struct ConvJob { const float* W; u16* Wt; int ldw, k0, n0, K, tile_start, tiles_k; };
struct CopyJob { const float* src; float* dst; int n; };
struct BatchArgs { ConvJob cj[17]; CopyJob cp[5]; int conv_blocks; };

__global__ __launch_bounds__(256) void k_prep(BatchArgs a)
{
    __shared__ float ls[64][65];
    int b = blockIdx.x;
    int t = threadIdx.x;
    if (b < a.conv_blocks) {
        int j = 0;
        #pragma unroll 1
        while (j + 1 < 17 && a.cj[j + 1].tile_start <= b) ++j;
        const ConvJob J = a.cj[j];
        int local = b - J.tile_start;
        int tk = local % J.tiles_k, tn = local / J.tiles_k;
        int k0 = tk * 64, n0 = tn * 64;
        int cn = t & 63, rk = t >> 6;
        #pragma unroll
        for (int p = 0; p < 16; p++) {
            int kk = p * 4 + rk;
            ls[kk][cn] = J.W[(size_t)(J.k0 + k0 + kk) * J.ldw + J.n0 + n0 + cn];
        }
        __syncthreads();
        int ck = t & 63, rn = t >> 6;
        #pragma unroll
        for (int p = 0; p < 16; p++) {
            int nn = p * 4 + rn;
            J.Wt[(size_t)(n0 + nn) * J.K + k0 + ck] = f2b(ls[ck][nn]);
        }
    } else {
        int c = b - a.conv_blocks;
        const CopyJob C = a.cp[c];
        for (int i = t; i < C.n; i += 256) C.dst[i] = C.src[i];
    }
}

// ---------------- silu -> bf16 (vectorized, grid-stride) --------------------
__global__ void k_silu_bf(const float* __restrict__ in, u16* __restrict__ out, int n4)
{
    int i = blockIdx.x * 256 + threadIdx.x;
    int stride = gridDim.x * 256;
    for (; i < n4; i += stride) {
        f32x4 v = *(const f32x4*)(in + (size_t)i * 4);
        u16x4 o;
        #pragma unroll
        for (int j = 0; j < 4; j++) o[j] = f2b(siluf(v[j]));
        *(u16x4*)(out + (size_t)i * 4) = o;
    }
}

// ---------------- edge preprocessing (64 edges per block) -------------------
__global__ __launch_bounds__(256) void k_edge_pre(
    const float* __restrict__ pos, const float* __restrict__ edge_attr,
    const int* __restrict__ ei, const float* __restrict__ W_ee,
    const float* __restrict__ b_ee, const float* __restrict__ coors_scale,
    const u16* __restrict__ etf,
    u16* __restrict__ ea_mod, float* __restrict__ dist, float* __restrict__ cdiff)
{
    __shared__ float Ws[65][64];
    int t = threadIdx.x;
    for (int i = t; i < 65 * 64; i += 256) Ws[i >> 6][i & 63] = W_ee[i];
    __syncthreads();
    int l = t & 63;
    float bee = b_ee[l];
    float cscale = coors_scale[0];
    for (int g = 0; g < 16; g++) {
        int e = blockIdx.x * 64 + g * 4 + (t >> 6);
        int row = ei[e], col = ei[E_CNT + e];
        float d0 = pos[row * 3 + 0] - pos[col * 3 + 0];
        float d1 = pos[row * 3 + 1] - pos[col * 3 + 1];
        float d2 = pos[row * 3 + 2] - pos[col * 3 + 2];
        float ssq = d0 * d0 + d1 * d1 + d2 * d2;
        float dst = sqrtf(ssq + 1e-12f);
        float nrm = sqrtf(ssq);
        float cs = cscale / fmaxf(nrm, 1e-8f);
        if (l == 0) {
            dist[e] = dst;
            cdiff[e * 3 + 0] = d0 * cs; cdiff[e * 3 + 1] = d1 * cs; cdiff[e * 3 + 2] = d2 * cs;
        }
        float attr = edge_attr[(size_t)e * 64 + l];
        float acc = dst * Ws[0][l];
        for (int f = 0; f < 64; f++) acc += __shfl(attr, f) * Ws[1 + f][l];
        acc += bee;
        float y = wave_ln64(acc);
        const u16* ep = etf + (size_t)e * 896;
        float m = y * (1.f + b2f(ep[64 + l])) + b2f(ep[l]);
        ea_mod[(size_t)e * 64 + l] = f2b(m);
    }
}

// ---------------- node: hh = modulate(ln(h), sh_msa, sc_msa) -> bf16 --------
__global__ __launch_bounds__(256) void k_node_hh(
    const float* __restrict__ h, const float* __restrict__ nt, u16* __restrict__ hh)
{
    int n = blockIdx.x, c = threadIdx.x;
    float x = h[(size_t)n * 256 + c];
    float y = block_ln256(x);
    float m = y * (1.f + nt[(size_t)n * 1536 + 256 + c]) + nt[(size_t)n * 1536 + c];
    hh[(size_t)n * 256 + c] = f2b(m);
}

// ---------------- fused per-node: alpha + softmax + aggregation -------------
// qkv: [BN,768] f32 (q|k|v); e01: [E,512] bf16 (e0|e1)
__global__ __launch_bounds__(256) void k_agg(
    const float* __restrict__ qkv, const u16* __restrict__ e01,
    float* __restrict__ hnode, u16* __restrict__ hnode_bf)
{
    int n = blockIdx.x;
    int b = n / 48, i = n % 48;
    int t = threadIdx.x;
    __shared__ float qs[8][33];
    __shared__ float att[47][8];
    __shared__ float mxs[8], dens[8];
    __shared__ int elist[47], slist[47];
    qs[t >> 5][t & 31] = qkv[(size_t)n * 768 + t];
    if (t < 47) {
        int s = t + (t >= i ? 1 : 0);
        slist[t] = s;
        elist[t] = b * EPG + s * 47 + (i < s ? i : i - 1);
    }
    __syncthreads();
    for (int idx = t; idx < 376; idx += 256) {
        int j = idx >> 3, hh = idx & 7;
        int src = b * 48 + slist[j];
        int e = elist[j];
        const float* kp = qkv + (size_t)src * 768 + 256 + hh * 32;
        const u16* ep = e01 + (size_t)e * 512 + hh * 32;
        float p = 0.f;
        #pragma unroll
        for (int d = 0; d < 32; d++) p += qs[hh][d] * kp[d] * b2f(ep[d]);
        att[j][hh] = p * 0.17677669529663687f; // 1/sqrt(32)
    }
    __syncthreads();
    if (t < 8) {
        float m = -1e30f;
        for (int j = 0; j < 47; j++) m = fmaxf(m, att[j][t]);
        float den = 0.f;
        for (int j = 0; j < 47; j++) den += expf(att[j][t] - m);
        mxs[t] = m; dens[t] = den + 1e-16f;
    }
    __syncthreads();
    for (int idx = t; idx < 376; idx += 256) {
        int j = idx >> 3, hh = idx & 7;
        att[j][hh] = expf(att[j][hh] - mxs[hh]) / dens[hh];
    }
    __syncthreads();
    int c = t, hh = t >> 5;
    float acc = 0.f;
    for (int j = 0; j < 47; j++) {
        int src = b * 48 + slist[j];
        int e = elist[j];
        acc += att[j][hh] * qkv[(size_t)src * 768 + 512 + c] * b2f(e01[(size_t)e * 512 + 256 + c]);
    }
    hnode[(size_t)n * 256 + c] = acc;
    hnode_bf[(size_t)n * 256 + c] = f2b(acc);
}

// ---------------- node: residual + LN + modulate(mlp) * mask ----------------
__global__ __launch_bounds__(256) void k_node_mod(
    const float* __restrict__ h, const float* __restrict__ hnode_raw,
    const float* __restrict__ nt, const float* __restrict__ mask,
    float* __restrict__ hmod, u16* __restrict__ hmod_bf)
{
    int n = blockIdx.x, c = threadIdx.x;
    float x = h[(size_t)n * 256 + c] + nt[(size_t)n * 1536 + 512 + c] * hnode_raw[(size_t)n * 256 + c];
    float y = block_ln256(x);
    float m = (y * (1.f + nt[(size_t)n * 1536 + 1024 + c]) + nt[(size_t)n * 1536 + 768 + c]) * mask[n];
    hmod[(size_t)n * 256 + c] = m;
    hmod_bf[(size_t)n * 256 + c] = f2b(m);
}

// ---------------- node output ------------------------------------------------
__global__ void k_hout(const float* __restrict__ hmod, const float* __restrict__ ff2,
                       const float* __restrict__ nt, const float* __restrict__ mask,
                       float* __restrict__ out, u16* __restrict__ hout_bf)
{
    int i = blockIdx.x * 256 + threadIdx.x;
    if (i >= BN_CNT * 256) return;
    int n = i >> 8, c = i & 255;
    float v = (hmod[i] + nt[(size_t)n * 1536 + 1280 + c] * ff2[i]) * mask[n];
    out[i] = v;
    hout_bf[i] = f2b(v);
}

// ---------------- edge: h_e = edge_attr + g*h_edge; LN; modulate ------------
__global__ __launch_bounds__(256) void k_edge_mod(
    const float* __restrict__ Q1, const float* __restrict__ b_n2e,
    const float* __restrict__ edge_attr, const int* __restrict__ ei,
    const u16* __restrict__ etf, float* __restrict__ hemod, u16* __restrict__ hemod_bf)
{
    int e = blockIdx.x * 4 + (threadIdx.x >> 6);
    int l = threadIdx.x & 63;
    int row = ei[e], col = ei[E_CNT + e];
    float hedge = Q1[(size_t)row * 64 + l] + Q1[(size_t)col * 64 + l] + b_n2e[l];
    const u16* ep = etf + (size_t)e * 896;
    float x = edge_attr[(size_t)e * 64 + l] + b2f(ep[128 + l]) * hedge;
    float y = wave_ln64(x);
    float m = y * (1.f + b2f(ep[256 + l])) + b2f(ep[192 + l]);
    hemod[(size_t)e * 64 + l] = m;
    hemod_bf[(size_t)e * 64 + l] = f2b(m);
}

// ---------------- edge output ------------------------------------------------
__global__ void k_edge_out(const float* __restrict__ hemod, const float* __restrict__ ff4,
                           const u16* __restrict__ etf,
                           float* __restrict__ out2, u16* __restrict__ heout_bf)
{
    size_t i = (size_t)blockIdx.x * 256 + threadIdx.x;
    if (i >= (size_t)E_CNT * 64) return;
    int e = (int)(i >> 6), c = (int)(i & 63);
    float v = hemod[i] + b2f(etf[(size_t)e * 896 + 320 + c]) * ff4[i];
    out2[i] = v;
    heout_bf[i] = f2b(v);
}

// ---------------- CondEquiUpdate: assemble invariant input, LN, modulate ----
// p12: [BN,512] f32 (P1|P2)
__global__ __launch_bounds__(256) void k_inv_pre(
    const float* __restrict__ p12,
    const u16* __restrict__ P3, const float* __restrict__ dist,
    const float* __restrict__ W_ui, const float* __restrict__ b_ui,
    const int* __restrict__ ei, const u16* __restrict__ etf, u16* __restrict__ invmod)
{
    int e = blockIdx.x, c = threadIdx.x;
    int row = ei[e], col = ei[E_CNT + e];
    float x = p12[(size_t)row * 512 + c] + p12[(size_t)col * 512 + 256 + c]
            + b2f(P3[(size_t)e * 256 + c]) + dist[e] * W_ui[576 * 256 + c] + b_ui[c];
    float y = block_ln256(x);
    const u16* ep = etf + (size_t)e * 896;
    float m = y * (1.f + b2f(ep[640 + c])) + b2f(ep[384 + c]);
    invmod[(size_t)e * 256 + c] = f2b(m);
}

// ---------------- final per-edge scalar: tanh( silu(y) . W_uc2 ) ------------
__global__ __launch_bounds__(256) void k_inv(const u16* __restrict__ uc1,
                                             const float* __restrict__ W_uc2,
                                             float* __restrict__ inv)
{
    int e = blockIdx.x * 4 + (threadIdx.x >> 6);
    int l = threadIdx.x & 63;
    u16x4 v = *(const u16x4*)(uc1 + (size_t)e * 256 + l * 4);
    const float* w = W_uc2 + l * 4;
    float s = b2f(v[0]) * w[0] + b2f(v[1]) * w[1] + b2f(v[2]) * w[2] + b2f(v[3]) * w[3];
    #pragma unroll
    for (int off = 1; off < 64; off <<= 1) s += __shfl_xor(s, off);
    if (l == 0) inv[e] = tanhf(s);
}

// ---------------- pos update: deterministic contiguous segment sum ----------
__global__ void k_pos(const float* __restrict__ pos, const float* __restrict__ cdiff,
                      const float* __restrict__ inv, float* __restrict__ out3)
{
    int n = blockIdx.x * 256 + threadIdx.x;
    if (n >= BN_CNT) return;
    int b = n / 48, s = n % 48;
    int e0 = b * EPG + s * 47;
    float a0 = 0.f, a1 = 0.f, a2 = 0.f;
    for (int j = 0; j < 47; j++) {
        float f = inv[e0 + j];
        a0 += cdiff[(size_t)(e0 + j) * 3 + 0] * f;
        a1 += cdiff[(size_t)(e0 + j) * 3 + 1] * f;
        a2 += cdiff[(size_t)(e0 + j) * 3 + 2] * f;
    }
    out3[n * 3 + 0] = pos[n * 3 + 0] + a0;
    out3[n * 3 + 1] = pos[n * 3 + 1] + a1;
    out3[n * 3 + 2] = pos[n * 3 + 2] + a2;
}

extern "C" void kernel_launch(void* const* d_in, const int* in_sizes, int n_in,
                              void* d_out, int out_size, void* d_ws, size_t ws_size,
                              hipStream_t stream)
{
    (void)in_sizes; (void)n_in; (void)out_size; (void)ws_size;
    const float* pos       = (const float*)d_in[0];
    const float* h         = (const float*)d_in[1];
    const float* edge_attr = (const float*)d_in[2];
    const float* node_mask = (const float*)d_in[3];
    const float* nte       = (const float*)d_in[4];
    const float* ete       = (const float*)d_in[5];
    const int*   ei        = (const int*)d_in[6];
    const float* W_ee = (const float*)d_in[7];  const float* b_ee = (const float*)d_in[8];
    const float* W_nt = (const float*)d_in[9];  const float* b_nt = (const float*)d_in[10];
    const float* W_et = (const float*)d_in[11]; const float* b_et = (const float*)d_in[12];
    const float* Wq  = (const float*)d_in[13];  const float* bq  = (const float*)d_in[14];
    const float* Wk  = (const float*)d_in[15];  const float* bk  = (const float*)d_in[16];
    const float* Wv  = (const float*)d_in[17];  const float* bv  = (const float*)d_in[18];
    const float* We0 = (const float*)d_in[19];  const float* We1 = (const float*)d_in[20];
    const float* W_n2e = (const float*)d_in[21]; const float* b_n2e = (const float*)d_in[22];
    const float* W_ff1 = (const float*)d_in[23]; const float* b_ff1 = (const float*)d_in[24];
    const float* W_ff2 = (const float*)d_in[25]; const float* b_ff2 = (const float*)d_in[26];
    const float* W_ff3 = (const float*)d_in[27]; const float* b_ff3 = (const float*)d_in[28];
    const float* W_ff4 = (const float*)d_in[29]; const float* b_ff4 = (const float*)d_in[30];
    const float* coors_scale = (const float*)d_in[31];
    const float* W_ut = (const float*)d_in[32]; const float* b_ut = (const float*)d_in[33];
    const float* W_ui = (const float*)d_in[34]; const float* b_ui = (const float*)d_in[35];
    const float* W_uc1 = (const float*)d_in[36]; const float* b_uc1 = (const float*)d_in[37];
    const float* W_uc2 = (const float*)d_in[38];

    const size_t E = E_CNT;
    char* ws = (char*)d_ws;
    size_t off = 0;
    auto AL = [&](size_t b) { size_t o = off; off += (b + 255) & ~(size_t)255; return o; };

    // weights (bf16, transposed [N,K])
    size_t o_wtcat  = AL(896 * 1024 * 2);
    size_t o_wtnt   = AL(1536 * 1024 * 2);
    size_t o_wtqkv  = AL(768 * 256 * 2);
    size_t o_wte01  = AL(512 * 64 * 2);
    size_t o_wtn2e  = AL(64 * 256 * 2);
    size_t o_wtff1  = AL(512 * 256 * 2), o_wtff2 = AL(256 * 512 * 2);
    size_t o_wtff3  = AL(128 * 64 * 2),  o_wtff4 = AL(64 * 128 * 2);
    size_t o_wtuiab = AL(512 * 256 * 2);
    size_t o_wtuic  = AL(256 * 64 * 2),  o_wtuc1 = AL(256 * 256 * 2);
    size_t o_bias896 = AL(896 * 4);
    size_t o_bias768 = AL(768 * 4);
    // big regions (lifetime-based aliasing)
    size_t o_reg1 = AL(E * 1024 * 2);          // ete_silu -> later P3/invmod/uc1o
    size_t o_etf  = AL(E * 896 * 2);           // persistent
    size_t o_ntes = AL(1536 * 1024 * 2);
    size_t o_ntf  = AL((size_t)1536 * 1536 * 4);
    size_t o_eamod = AL(E * 64 * 2);
    size_t o_dist = AL(E * 4), o_cdiff = AL(E * 12);
    size_t o_qkv  = AL(1536 * 768 * 4);
    size_t o_reg3 = AL(E * 512 * 2);           // e01 -> later ffem/ff4o/heoutbf
    size_t o_hnode = AL(1536 * 256 * 4), o_hnodebf = AL(1536 * 256 * 2);
    size_t o_q1 = AL(1536 * 64 * 4);
    size_t o_hh = AL(1536 * 256 * 2);
    size_t o_hmod = AL(1536 * 256 * 4), o_hmodbf = AL(1536 * 256 * 2);
    size_t o_ff1 = AL(1536 * 512 * 2), o_ff2 = AL(1536 * 256 * 4);
    size_t o_houtbf = AL(1536 * 256 * 2);
    size_t o_hemod = AL(E * 64 * 4), o_hemodbf = AL(E * 64 * 2);
    size_t o_p12 = AL(1536 * 512 * 4);
    size_t o_inv = AL(E * 4);
    // aliases
    size_t o_etes = o_reg1;
    size_t o_p3 = o_reg1;
    size_t o_invmod = o_reg1 + E * 256 * 2;
    size_t o_uc1o = o_reg1 + E * 256 * 4;
    size_t o_e01 = o_reg3;
    size_t o_ffem = o_reg3;
    size_t o_ff4o = o_reg3 + E * 128 * 2;
    size_t o_heoutbf = o_reg3 + E * 128 * 2 + E * 64 * 4;

    #define WSU(o) ((u16*)(ws + (o)))
    #define WSF(o) ((float*)(ws + (o)))

    // --- batched weight prep (17 tiled transposes + 5 bias copies) ---
    {
        BatchArgs a;
        int s = 0; int j = 0;
        auto add = [&](const float* W, u16* Wt, int ldw, int k0, int n0, int K, int NC) {
            a.cj[j++] = ConvJob{W, Wt, ldw, k0, n0, K, s, K / 64};
            s += (K / 64) * (NC / 64);
        };
        add(W_et, WSU(o_wtcat), 384, 0, 0, 1024, 384);
        add(W_ut, WSU(o_wtcat) + (size_t)384 * 1024, 512, 0, 0, 1024, 512);
        add(W_nt, WSU(o_wtnt), 1536, 0, 0, 1024, 1536);
        add(Wq, WSU(o_wtqkv), 256, 0, 0, 256, 256);
        add(Wk, WSU(o_wtqkv) + (size_t)256 * 256, 256, 0, 0, 256, 256);
        add(Wv, WSU(o_wtqkv) + (size_t)512 * 256, 256, 0, 0, 256, 256);
        add(We0, WSU(o_wte01), 256, 0, 0, 64, 256);
        add(We1, WSU(o_wte01) + (size_t)256 * 64, 256, 0, 0, 64, 256);
        add(W_n2e, WSU(o_wtn2e), 64, 0, 0, 256, 64);
        add(W_ff1, WSU(o_wtff1), 512, 0, 0, 256, 512);
        add(W_ff2, WSU(o_wtff2), 256, 0, 0, 512, 256);
        add(W_ff3, WSU(o_wtff3), 128, 0, 0, 64, 128);
        add(W_ff4, WSU(o_wtff4), 64, 0, 0, 128, 64);
        add(W_ui, WSU(o_wtuiab), 256, 0, 0, 256, 256);
        add(W_ui, WSU(o_wtuiab) + (size_t)256 * 256, 256, 256, 0, 256, 256);
        add(W_ui, WSU(o_wtuic), 256, 512, 0, 64, 256);
        add(W_uc1, WSU(o_wtuc1), 256, 0, 0, 256, 256);
        a.conv_blocks = s;  // 788 tiles
        a.cp[0] = CopyJob{b_et, WSF(o_bias896), 384};
        a.cp[1] = CopyJob{b_ut, WSF(o_bias896) + 384, 512};
        a.cp[2] = CopyJob{bq, WSF(o_bias768), 256};
        a.cp[3] = CopyJob{bk, WSF(o_bias768) + 256, 256};
        a.cp[4] = CopyJob{bv, WSF(o_bias768) + 512, 256};
        k_prep<<<s + 5, 256, 0, stream>>>(a);
    }

    // --- silu -> bf16 ---
    k_silu_bf<<<2048, 256, 0, stream>>>(ete, WSU(o_etes), (int)(E * 1024 / 4));
    k_silu_bf<<<1024, 256, 0, stream>>>(nte, WSU(o_ntes), 1536 * 1024 / 4);

    // --- big time-embedding GEMMs ---
    k_gemm128<0, 1><<<dim3(7, 564), 256, 0, stream>>>(WSU(o_etes), WSU(o_wtcat), WSF(o_bias896), WSU(o_etf), E_CNT, 896, 1024);
    k_gemm128<0, 0><<<dim3(12, 12), 256, 0, stream>>>(WSU(o_ntes), WSU(o_wtnt), b_nt, WSF(o_ntf), 1536, 1536, 1024);

    // --- edge preprocess ---
    k_edge_pre<<<1128, 256, 0, stream>>>(pos, edge_attr, ei, W_ee, b_ee, coors_scale,
                                         WSU(o_etf), WSU(o_eamod), WSF(o_dist), WSF(o_cdiff));

    // --- node attention path ---
    k_node_hh<<<1536, 256, 0, stream>>>(h, WSF(o_ntf), WSU(o_hh));
    k_gemm<0, 0><<<dim3(12, 24), 256, 0, stream>>>(WSU(o_hh), WSU(o_wtqkv), WSF(o_bias768), WSF(o_qkv), 1536, 768, 256);
    k_gemm128<0, 1><<<dim3(4, 564), 256, 0, stream>>>(WSU(o_eamod), WSU(o_wte01), nullptr, WSU(o_e01), E_CNT, 512, 64);
    k_agg<<<1536, 256, 0, stream>>>(WSF(o_qkv), WSU(o_e01), WSF(o_hnode), WSU(o_hnodebf));

    // --- Q1 = h_node_raw @ W_n2e ---
    k_gemm<0, 0><<<dim3(1, 24), 256, 0, stream>>>(WSU(o_hnodebf), WSU(o_wtn2e), nullptr, WSF(o_q1), 1536, 64, 256);

    // --- node FFN + output ---
    k_node_mod<<<1536, 256, 0, stream>>>(h, WSF(o_hnode), WSF(o_ntf), node_mask, WSF(o_hmod), WSU(o_hmodbf));
    k_gemm<1, 1><<<dim3(8, 24), 256, 0, stream>>>(WSU(o_hmodbf), WSU(o_wtff1), b_ff1, WSU(o_ff1), 1536, 512, 256);
    k_gemm<0, 0><<<dim3(4, 24), 256, 0, stream>>>(WSU(o_ff1), WSU(o_wtff2), b_ff2, WSF(o_ff2), 1536, 256, 512);
    k_hout<<<1536, 256, 0, stream>>>(WSF(o_hmod), WSF(o_ff2), WSF(o_ntf), node_mask, (float*)d_out, WSU(o_houtbf));

    // --- edge FFN + output ---
    k_edge_mod<<<18048, 256, 0, stream>>>(WSF(o_q1), b_n2e, edge_attr, ei, WSU(o_etf), WSF(o_hemod), WSU(o_hemodbf));
    k_gemm128<1, 1><<<dim3(1, 564), 256, 0, stream>>>(WSU(o_hemodbf), WSU(o_wtff3), b_ff3, WSU(o_ffem), E_CNT, 128, 64);
    k_gemm<0, 0><<<dim3(1, 1128), 256, 0, stream>>>(WSU(o_ffem), WSU(o_wtff4), b_ff4, WSF(o_ff4o), E_CNT, 64, 128);
    k_edge_out<<<18048, 256, 0, stream>>>(WSF(o_hemod), WSF(o_ff4o), WSU(o_etf),
                                          (float*)d_out + 393216, WSU(o_heoutbf));

    // --- CondEquiUpdate ---
    k_gemm<0, 0><<<dim3(8, 24), 256, 0, stream>>>(WSU(o_houtbf), WSU(o_wtuiab), nullptr, WSF(o_p12), 1536, 512, 256);
    k_gemm128<0, 1><<<dim3(2, 564), 256, 0, stream>>>(WSU(o_heoutbf), WSU(o_wtuic), nullptr, WSU(o_p3), E_CNT, 256, 64);
    k_inv_pre<<<E_CNT, 256, 0, stream>>>(WSF(o_p12), WSU(o_p3), WSF(o_dist),
                                         W_ui, b_ui, ei, WSU(o_etf), WSU(o_invmod));
    k_gemm128<1, 1><<<dim3(2, 564), 256, 0, stream>>>(WSU(o_invmod), WSU(o_wtuc1), b_uc1, WSU(o_uc1o), E_CNT, 256, 256);
    k_inv<<<18048, 256, 0, stream>>>(WSU(o_uc1o), W_uc2, WSF(o_inv));
    k_pos<<<6, 256, 0, stream>>>(pos, WSF(o_cdiff), WSF(o_inv), (float*)d_out + 393216 + E_CNT * 64);

    #undef WSU
    #undef WSF
}

// Round 14
// 744.925 us; speedup vs baseline: 1.2799x; 1.0004x over previous
//
#include <hip/hip_runtime.h>

typedef unsigned short u16;
typedef __attribute__((ext_vector_type(4))) u16 u16x4;
typedef __attribute__((ext_vector_type(8))) u16 u16x8;
typedef __attribute__((ext_vector_type(8))) short s16x8;
typedef __attribute__((ext_vector_type(4))) float f32x4;

#define E_CNT 72192
#define BN_CNT 1536
// edges per graph = 48*47
#define EPG 2256

__device__ __forceinline__ float b2f(u16 u) {
    union { unsigned int i; float f; } x; x.i = ((unsigned int)u) << 16; return x.f;
}
__device__ __forceinline__ u16 f2b(float f) {
    union { float f; unsigned int i; } x; x.f = f;
    unsigned int r = x.i + 0x7fffu + ((x.i >> 16) & 1u);
    return (u16)(r >> 16);
}
__device__ __forceinline__ float siluf(float x) { return x / (1.f + expf(-x)); }

// async global->LDS, 16B per lane (linear dest). (guide §5 / m97)
__device__ __forceinline__ void gll16(const void* g, void* l) {
    __builtin_amdgcn_global_load_lds(
        (const __attribute__((address_space(1))) void*)g,
        (__attribute__((address_space(3))) void*)l, 16, 0, 0);
}

// ---------------- wave (64-lane) LayerNorm, eps 1e-6, no affine -------------
__device__ __forceinline__ float wave_ln64(float x) {
    float s = x;
    #pragma unroll
    for (int off = 1; off < 64; off <<= 1) s += __shfl_xor(s, off);
    float mean = s * 0.015625f;
    float d = x - mean;
    float v2 = d * d;
    #pragma unroll
    for (int off = 1; off < 64; off <<= 1) v2 += __shfl_xor(v2, off);
    return d * rsqrtf(v2 * 0.015625f + 1e-6f);
}

// ---------------- block(256)-wide LayerNorm over 256 dims -------------------
__device__ __forceinline__ float block_ln256(float x) {
    __shared__ float tmp[4];
    int t = threadIdx.x;
    float s = x;
    #pragma unroll
    for (int off = 1; off < 64; off <<= 1) s += __shfl_xor(s, off);
    if ((t & 63) == 0) tmp[t >> 6] = s;
    __syncthreads();
    float mean = (tmp[0] + tmp[1] + tmp[2] + tmp[3]) * (1.f / 256.f);
    float d = x - mean;
    float v2 = d * d;
    #pragma unroll
    for (int off = 1; off < 64; off <<= 1) v2 += __shfl_xor(v2, off);
    __syncthreads();
    if ((t & 63) == 0) tmp[t >> 6] = v2;
    __syncthreads();
    float var = (tmp[0] + tmp[1] + tmp[2] + tmp[3]) * (1.f / 256.f);
    return d * rsqrtf(var + 1e-6f);
}

// ---------------- generic bf16 MFMA GEMM, 64x64 tile ------------------------
template<int ACT, int OUTBF>
__global__ __launch_bounds__(256) void k_gemm(
    const u16* __restrict__ A, const u16* __restrict__ Bt,
    const float* __restrict__ bias, void* __restrict__ C,
    int M, int N, int K)
{
    __shared__ u16 As[64][40];
    __shared__ u16 Bs[64][40];
    int bn0 = blockIdx.x * 64, bm0 = blockIdx.y * 64;
    int t = threadIdx.x;
    int lane = t & 63, wave = t >> 6;
    int wm = wave >> 1, wn = wave & 1;
    int lr = t >> 2, lc = (t & 3) * 8;
    f32x4 acc[2][2] = {};
    const u16* Ap = A + (size_t)(bm0 + lr) * K + lc;
    const u16* Bp = Bt + (size_t)(bn0 + lr) * K + lc;
    int fr = lane & 15, fk = (lane >> 4) * 8;
    for (int k0 = 0; k0 < K; k0 += 32) {
        *(u16x8*)&As[lr][lc] = *(const u16x8*)(Ap + k0);
        *(u16x8*)&Bs[lr][lc] = *(const u16x8*)(Bp + k0);
        __syncthreads();
        s16x8 a0 = *(const s16x8*)&As[wm * 32 + fr][fk];
        s16x8 a1 = *(const s16x8*)&As[wm * 32 + 16 + fr][fk];
        s16x8 b0 = *(const s16x8*)&Bs[wn * 32 + fr][fk];
        s16x8 b1 = *(const s16x8*)&Bs[wn * 32 + 16 + fr][fk];
        acc[0][0] = __builtin_amdgcn_mfma_f32_16x16x32_bf16(a0, b0, acc[0][0], 0, 0, 0);
        acc[0][1] = __builtin_amdgcn_mfma_f32_16x16x32_bf16(a0, b1, acc[0][1], 0, 0, 0);
        acc[1][0] = __builtin_amdgcn_mfma_f32_16x16x32_bf16(a1, b0, acc[1][0], 0, 0, 0);
        acc[1][1] = __builtin_amdgcn_mfma_f32_16x16x32_bf16(a1, b1, acc[1][1], 0, 0, 0);
        __syncthreads();
    }
    int cIn = lane & 15, r4 = (lane >> 4) * 4;
    #pragma unroll
    for (int i = 0; i < 2; i++)
    #pragma unroll
    for (int j = 0; j < 2; j++) {
        int col = bn0 + wn * 32 + j * 16 + cIn;
        float bv = bias ? bias[col] : 0.f;
        #pragma unroll
        for (int r = 0; r < 4; r++) {
            int rowg = bm0 + wm * 32 + i * 16 + r4 + r;
            float vv = acc[i][j][r] + bv;
            if (ACT == 1) vv = siluf(vv);
            if (OUTBF) ((u16*)C)[(size_t)rowg * N + col] = f2b(vv);
            else       ((float*)C)[(size_t)rowg * N + col] = vv;
        }
    }
}

// ---------------- 64x64 GEMM fused with k_hout epilogue ---------------------
// C-elem x -> v = (hmod + nt_gate * x) * mask; writes f32 out + bf16 hout.
__global__ __launch_bounds__(256) void k_gemm_ff2ho(
    const u16* __restrict__ A, const u16* __restrict__ Bt,
    const float* __restrict__ bias, const float* __restrict__ hmod,
    const float* __restrict__ nt, const float* __restrict__ mask,
    float* __restrict__ out, u16* __restrict__ hout_bf, int M, int N, int K)
{
    __shared__ u16 As[64][40];
    __shared__ u16 Bs[64][40];
    int bn0 = blockIdx.x * 64, bm0 = blockIdx.y * 64;
    int t = threadIdx.x;
    int lane = t & 63, wave = t >> 6;
    int wm = wave >> 1, wn = wave & 1;
    int lr = t >> 2, lc = (t & 3) * 8;
    f32x4 acc[2][2] = {};
    const u16* Ap = A + (size_t)(bm0 + lr) * K + lc;
    const u16* Bp = Bt + (size_t)(bn0 + lr) * K + lc;
    int fr = lane & 15, fk = (lane >> 4) * 8;
    for (int k0 = 0; k0 < K; k0 += 32) {
        *(u16x8*)&As[lr][lc] = *(const u16x8*)(Ap + k0);
        *(u16x8*)&Bs[lr][lc] = *(const u16x8*)(Bp + k0);
        __syncthreads();
        s16x8 a0 = *(const s16x8*)&As[wm * 32 + fr][fk];
        s16x8 a1 = *(const s16x8*)&As[wm * 32 + 16 + fr][fk];
        s16x8 b0 = *(const s16x8*)&Bs[wn * 32 + fr][fk];
        s16x8 b1 = *(const s16x8*)&Bs[wn * 32 + 16 + fr][fk];
        acc[0][0] = __builtin_amdgcn_mfma_f32_16x16x32_bf16(a0, b0, acc[0][0], 0, 0, 0);
        acc[0][1] = __builtin_amdgcn_mfma_f32_16x16x32_bf16(a0, b1, acc[0][1], 0, 0, 0);
        acc[1][0] = __builtin_amdgcn_mfma_f32_16x16x32_bf16(a1, b0, acc[1][0], 0, 0, 0);
        acc[1][1] = __builtin_amdgcn_mfma_f32_16x16x32_bf16(a1, b1, acc[1][1], 0, 0, 0);
        __syncthreads();
    }
    int cIn = lane & 15, r4 = (lane >> 4) * 4;
    #pragma unroll
    for (int i = 0; i < 2; i++)
    #pragma unroll
    for (int j = 0; j < 2; j++) {
        int col = bn0 + wn * 32 + j * 16 + cIn;
        float bv = bias[col];
        #pragma unroll
        for (int r = 0; r < 4; r++) {
            int rowg = bm0 + wm * 32 + i * 16 + r4 + r;
            float x = acc[i][j][r] + bv;
            float v = (hmod[(size_t)rowg * 256 + col]
                     + nt[(size_t)rowg * 1536 + 1280 + col] * x) * mask[rowg];
            out[(size_t)rowg * 256 + col] = v;
            hout_bf[(size_t)rowg * 256 + col] = f2b(v);
        }
    }
}

// ---------------- 64x64 GEMM fused with k_edge_out epilogue -----------------
// C-elem x -> v = hemod + gate(etf[,320..383]) * x; writes f32 out2 + bf16.
__global__ __launch_bounds__(256) void k_gemm_ff4eo(
    const u16* __restrict__ A, const u16* __restrict__ Bt,
    const float* __restrict__ bias, const float* __restrict__ hemod,
    const u16* __restrict__ etf,
    float* __restrict__ out2, u16* __restrict__ heout_bf, int M, int N, int K)
{
    __shared__ u16 As[64][40];
    __shared__ u16 Bs[64][40];
    int bn0 = blockIdx.x * 64, bm0 = blockIdx.y * 64;
    int t = threadIdx.x;
    int lane = t & 63, wave = t >> 6;
    int wm = wave >> 1, wn = wave & 1;
    int lr = t >> 2, lc = (t & 3) * 8;
    f32x4 acc[2][2] = {};
    const u16* Ap = A + (size_t)(bm0 + lr) * K + lc;
    const u16* Bp = Bt + (size_t)(bn0 + lr) * K + lc;
    int fr = lane & 15, fk = (lane >> 4) * 8;
    for (int k0 = 0; k0 < K; k0 += 32) {
        *(u16x8*)&As[lr][lc] = *(const u16x8*)(Ap + k0);
        *(u16x8*)&Bs[lr][lc] = *(const u16x8*)(Bp + k0);
        __syncthreads();
        s16x8 a0 = *(const s16x8*)&As[wm * 32 + fr][fk];
        s16x8 a1 = *(const s16x8*)&As[wm * 32 + 16 + fr][fk];
        s16x8 b0 = *(const s16x8*)&Bs[wn * 32 + fr][fk];
        s16x8 b1 = *(const s16x8*)&Bs[wn * 32 + 16 + fr][fk];
        acc[0][0] = __builtin_amdgcn_mfma_f32_16x16x32_bf16(a0, b0, acc[0][0], 0, 0, 0);
        acc[0][1] = __builtin_amdgcn_mfma_f32_16x16x32_bf16(a0, b1, acc[0][1], 0, 0, 0);
        acc[1][0] = __builtin_amdgcn_mfma_f32_16x16x32_bf16(a1, b0, acc[1][0], 0, 0, 0);
        acc[1][1] = __builtin_amdgcn_mfma_f32_16x16x32_bf16(a1, b1, acc[1][1], 0, 0, 0);
        __syncthreads();
    }
    int cIn = lane & 15, r4 = (lane >> 4) * 4;
    #pragma unroll
    for (int i = 0; i < 2; i++)
    #pragma unroll
    for (int j = 0; j < 2; j++) {
        int col = bn0 + wn * 32 + j * 16 + cIn;
        float bv = bias[col];
        #pragma unroll
        for (int r = 0; r < 4; r++) {
            int rowg = bm0 + wm * 32 + i * 16 + r4 + r;
            float x = acc[i][j][r] + bv;
            float v = hemod[(size_t)rowg * 64 + col]
                    + b2f(etf[(size_t)rowg * 896 + 320 + col]) * x;
            out2[(size_t)rowg * 64 + col] = v;
            heout_bf[(size_t)rowg * 64 + col] = f2b(v);
        }
    }
}

// ---------------- 128x128 tile bf16 MFMA GEMM, 3-deep pipelined -------------
// (r5/r6 verified structure: counted vmcnt + both-sides chunk-XOR swizzle,
// bank conflicts = 0, best measured config for the E-row GEMMs)
template<int ACT, int OUTBF>
__global__ __launch_bounds__(256) void k_gemm128(
    const u16* __restrict__ A, const u16* __restrict__ Bt,
    const float* __restrict__ bias, void* __restrict__ C,
    int M, int N, int K)
{
    __shared__ u16 As[3][128 * 32];
    __shared__ u16 Bs[3][128 * 32];
    const int t = threadIdx.x;
    const int lane = t & 63, wv = t >> 6;
    const int wm = wv >> 1, wn = wv & 1;
    const int nwg = gridDim.x * gridDim.y;
    const int orig = blockIdx.y * gridDim.x + blockIdx.x;
    const int q8 = nwg >> 3, r8 = nwg & 7;
    const int xcd = orig & 7, lin = orig >> 3;
    const int wgid = (xcd < r8 ? xcd * (q8 + 1) : r8 * (q8 + 1) + (xcd - r8) * q8) + lin;
    const int bxs = wgid % gridDim.x, bys = wgid / gridDim.x;
    const int bn0 = bxs * 128, bm0 = bys * 128;
    const int srow = t >> 2;
    const int scol = ((t & 3) ^ ((t >> 3) & 3)) * 8;
    const u16* Ap = A + (size_t)(bm0 + srow) * K + scol;
    const u16* Bp = Bt + (size_t)(bn0 + srow) * K + scol;
    const size_t rstep = (size_t)64 * K;
    const int woff = wv * 16 * 32;
    const int fr = lane & 15;
    const int fkc = (((lane >> 4) ^ ((fr >> 1) & 3)) * 8);
    f32x4 acc[4][4] = {};
    const int NT = K >> 5;

    auto STAGE = [&](int b, int ko) {
        gll16(Ap + ko, &As[b][woff]);
        gll16(Ap + ko + rstep, &As[b][woff + 64 * 32]);
        gll16(Bp + ko, &Bs[b][woff]);
        gll16(Bp + ko + rstep, &Bs[b][woff + 64 * 32]);
    };
    auto COMPUTE = [&](int b) {
        const u16* aBase = &As[b][wm * 64 * 32];
        const u16* bBase = &Bs[b][wn * 64 * 32];
        s16x8 af[4], bfr[4];
        #pragma unroll
        for (int m = 0; m < 4; m++) af[m] = *(const s16x8*)&aBase[(m * 16 + fr) * 32 + fkc];
        #pragma unroll
        for (int n = 0; n < 4; n++) bfr[n] = *(const s16x8*)&bBase[(n * 16 + fr) * 32 + fkc];
        #pragma unroll
        for (int m = 0; m < 4; m++)
        #pragma unroll
        for (int n = 0; n < 4; n++)
            acc[m][n] = __builtin_amdgcn_mfma_f32_16x16x32_bf16(af[m], bfr[n], acc[m][n], 0, 0, 0);
    };

    STAGE(0, 0);
    if (NT > 1) STAGE(1, 32);
    int cur = 0;
    for (int tt = 0; tt < NT; tt++) {
        if (tt + 2 < NT) STAGE((cur + 2) % 3, (tt + 2) * 32);
        __builtin_amdgcn_sched_barrier(0);
        int ahead = NT - 1 - tt; if (ahead > 2) ahead = 2;
        if (ahead == 2)      asm volatile("s_waitcnt vmcnt(8)" ::: "memory");
        else if (ahead == 1) asm volatile("s_waitcnt vmcnt(4)" ::: "memory");
        else                 asm volatile("s_waitcnt vmcnt(0)" ::: "memory");
        __builtin_amdgcn_sched_barrier(0);
        __builtin_amdgcn_s_barrier();
        COMPUTE(cur);
        __builtin_amdgcn_s_barrier();
        __builtin_amdgcn_sched_barrier(0);
        cur = (cur + 1) % 3;
    }

    const int cIn = lane & 15, r4 = (lane >> 4) * 4;
    #pragma unroll
    for (int n = 0; n < 4; n++) {
        int col = bn0 + wn * 64 + n * 16 + cIn;
        float bv = bias ? bias[col] : 0.f;
        #pragma unroll
        for (int m = 0; m < 4; m++) {
            #pragma unroll
            for (int r = 0; r < 4; r++) {
                int rowg = bm0 + wm * 64 + m * 16 + r4 + r;
                float vv = acc[m][n][r] + bv;
                if (ACT == 1) vv = siluf(vv);
                if (OUTBF) ((u16*)C)[(size_t)rowg * N + col] = f2b(vv);
                else       ((float*)C)[(size_t)rowg * N + col] = vv;
            }
        }
    }
}

// ---------------- batched weight prep: LDS-tiled transposes + bias copies ---
struct ConvJob { const float* W; u16* Wt; int ldw, k0, n0, K, tile_start, tiles_k; };
struct CopyJob { const float* src; float* dst; int n; };
struct BatchArgs { ConvJob cj[17]; CopyJob cp[5]; int conv_blocks; };

__global__ __launch_bounds__(256) void k_prep(BatchArgs a)
{
    __shared__ float ls[64][65];
    int b = blockIdx.x;
    int t = threadIdx.x;
    if (b < a.conv_blocks) {
        int j = 0;
        #pragma unroll 1
        while (j + 1 < 17 && a.cj[j + 1].tile_start <= b) ++j;
        const ConvJob J = a.cj[j];
        int local = b - J.tile_start;
        int tk = local % J.tiles_k, tn = local / J.tiles_k;
        int k0 = tk * 64, n0 = tn * 64;
        int cn = t & 63, rk = t >> 6;
        #pragma unroll
        for (int p = 0; p < 16; p++) {
            int kk = p * 4 + rk;
            ls[kk][cn] = J.W[(size_t)(J.k0 + k0 + kk) * J.ldw + J.n0 + n0 + cn];
        }
        __syncthreads();
        int ck = t & 63, rn = t >> 6;
        #pragma unroll
        for (int p = 0; p < 16; p++) {
            int nn = p * 4 + rn;
            J.Wt[(size_t)(n0 + nn) * J.K + k0 + ck] = f2b(ls[ck][nn]);
        }
    } else {
        int c = b - a.conv_blocks;
        const CopyJob C = a.cp[c];
        for (int i = t; i < C.n; i += 256) C.dst[i] = C.src[i];
    }
}

// ---------------- silu -> bf16 (vectorized, grid-stride) --------------------
__global__ void k_silu_bf(const float* __restrict__ in, u16* __restrict__ out, int n4)
{
    int i = blockIdx.x * 256 + threadIdx.x;
    int stride = gridDim.x * 256;
    for (; i < n4; i += stride) {
        f32x4 v = *(const f32x4*)(in + (size_t)i * 4);
        u16x4 o;
        #pragma unroll
        for (int j = 0; j < 4; j++) o[j] = f2b(siluf(v[j]));
        *(u16x4*)(out + (size_t)i * 4) = o;
    }
}

// ---------------- edge preprocessing (64 edges per block) -------------------
__global__ __launch_bounds__(256) void k_edge_pre(
    const float* __restrict__ pos, const float* __restrict__ edge_attr,
    const int* __restrict__ ei, const float* __restrict__ W_ee,
    const float* __restrict__ b_ee, const float* __restrict__ coors_scale,
    const u16* __restrict__ etf,
    u16* __restrict__ ea_mod, float* __restrict__ dist, float* __restrict__ cdiff)
{
    __shared__ float Ws[65][64];
    int t = threadIdx.x;
    for (int i = t; i < 65 * 64; i += 256) Ws[i >> 6][i & 63] = W_ee[i];
    __syncthreads();
    int l = t & 63;
    float bee = b_ee[l];
    float cscale = coors_scale[0];
    for (int g = 0; g < 16; g++) {
        int e = blockIdx.x * 64 + g * 4 + (t >> 6);
        int row = ei[e], col = ei[E_CNT + e];
        float d0 = pos[row * 3 + 0] - pos[col * 3 + 0];
        float d1 = pos[row * 3 + 1] - pos[col * 3 + 1];
        float d2 = pos[row * 3 + 2] - pos[col * 3 + 2];
        float ssq = d0 * d0 + d1 * d1 + d2 * d2;
        float dst = sqrtf(ssq + 1e-12f);
        float nrm = sqrtf(ssq);
        float cs = cscale / fmaxf(nrm, 1e-8f);
        if (l == 0) {
            dist[e] = dst;
            cdiff[e * 3 + 0] = d0 * cs; cdiff[e * 3 + 1] = d1 * cs; cdiff[e * 3 + 2] = d2 * cs;
        }
        float attr = edge_attr[(size_t)e * 64 + l];
        float acc = dst * Ws[0][l];
        for (int f = 0; f < 64; f++) acc += __shfl(attr, f) * Ws[1 + f][l];
        acc += bee;
        float y = wave_ln64(acc);
        const u16* ep = etf + (size_t)e * 896;
        float m = y * (1.f + b2f(ep[64 + l])) + b2f(ep[l]);
        ea_mod[(size_t)e * 64 + l] = f2b(m);
    }
}

// ---------------- node: hh = modulate(ln(h), sh_msa, sc_msa) -> bf16 --------
__global__ __launch_bounds__(256) void k_node_hh(
    const float* __restrict__ h, const float* __restrict__ nt, u16* __restrict__ hh)
{
    int n = blockIdx.x, c = threadIdx.x;
    float x = h[(size_t)n * 256 + c];
    float y = block_ln256(x);
    float m = y * (1.f + nt[(size_t)n * 1536 + 256 + c]) + nt[(size_t)n * 1536 + c];
    hh[(size_t)n * 256 + c] = f2b(m);
}

// ---------------- fused per-node: alpha + softmax + aggregation -------------
// qkv: [BN,768] f32 (q|k|v); e01: [E,512] bf16 (e0|e1)
__global__ __launch_bounds__(256) void k_agg(
    const float* __restrict__ qkv, const u16* __restrict__ e01,
    float* __restrict__ hnode, u16* __restrict__ hnode_bf)
{
    int n = blockIdx.x;
    int b = n / 48, i = n % 48;
    int t = threadIdx.x;
    __shared__ float qs[8][33];
    __shared__ float att[47][8];
    __shared__ float mxs[8], dens[8];
    __shared__ int elist[47], slist[47];
    qs[t >> 5][t & 31] = qkv[(size_t)n * 768 + t];
    if (t < 47) {
        int s = t + (t >= i ? 1 : 0);
        slist[t] = s;
        elist[t] = b * EPG + s * 47 + (i < s ? i : i - 1);
    }
    __syncthreads();
    for (int idx = t; idx < 376; idx += 256) {
        int j = idx >> 3, hh = idx & 7;
        int src = b * 48 + slist[j];
        int e = elist[j];
        const float* kp = qkv + (size_t)src * 768 + 256 + hh * 32;
        const u16* ep = e01 + (size_t)e * 512 + hh * 32;
        float p = 0.f;
        #pragma unroll
        for (int d = 0; d < 32; d++) p += qs[hh][d] * kp[d] * b2f(ep[d]);
        att[j][hh] = p * 0.17677669529663687f; // 1/sqrt(32)
    }
    __syncthreads();
    if (t < 8) {
        float m = -1e30f;
        for (int j = 0; j < 47; j++) m = fmaxf(m, att[j][t]);
        float den = 0.f;
        for (int j = 0; j < 47; j++) den += expf(att[j][t] - m);
        mxs[t] = m; dens[t] = den + 1e-16f;
    }
    __syncthreads();
    for (int idx = t; idx < 376; idx += 256) {
        int j = idx >> 3, hh = idx & 7;
        att[j][hh] = expf(att[j][hh] - mxs[hh]) / dens[hh];
    }
    __syncthreads();
    int c = t, hh = t >> 5;
    float acc = 0.f;
    for (int j = 0; j < 47; j++) {
        int src = b * 48 + slist[j];
        int e = elist[j];
        acc += att[j][hh] * qkv[(size_t)src * 768 + 512 + c] * b2f(e01[(size_t)e * 512 + 256 + c]);
    }
    hnode[(size_t)n * 256 + c] = acc;
    hnode_bf[(size_t)n * 256 + c] = f2b(acc);
}

// ---------------- node: residual + LN + modulate(mlp) * mask ----------------
__global__ __launch_bounds__(256) void k_node_mod(
    const float* __restrict__ h, const float* __restrict__ hnode_raw,
    const float* __restrict__ nt, const float* __restrict__ mask,
    float* __restrict__ hmod, u16* __restrict__ hmod_bf)
{
    int n = blockIdx.x, c = threadIdx.x;
    float x = h[(size_t)n * 256 + c] + nt[(size_t)n * 1536 + 512 + c] * hnode_raw[(size_t)n * 256 + c];
    float y = block_ln256(x);
    float m = (y * (1.f + nt[(size_t)n * 1536 + 1024 + c]) + nt[(size_t)n * 1536 + 768 + c]) * mask[n];
    hmod[(size_t)n * 256 + c] = m;
    hmod_bf[(size_t)n * 256 + c] = f2b(m);
}

// ---------------- edge: h_e = edge_attr + g*h_edge; LN; modulate ------------
__global__ __launch_bounds__(256) void k_edge_mod(
    const float* __restrict__ Q1, const float* __restrict__ b_n2e,
    const float* __restrict__ edge_attr, const int* __restrict__ ei,
    const u16* __restrict__ etf, float* __restrict__ hemod, u16* __restrict__ hemod_bf)
{
    int e = blockIdx.x * 4 + (threadIdx.x >> 6);
    int l = threadIdx.x & 63;
    int row = ei[e], col = ei[E_CNT + e];
    float hedge = Q1[(size_t)row * 64 + l] + Q1[(size_t)col * 64 + l] + b_n2e[l];
    const u16* ep = etf + (size_t)e * 896;
    float x = edge_attr[(size_t)e * 64 + l] + b2f(ep[128 + l]) * hedge;
    float y = wave_ln64(x);
    float m = y * (1.f + b2f(ep[256 + l])) + b2f(ep[192 + l]);
    hemod[(size_t)e * 64 + l] = m;
    hemod_bf[(size_t)e * 64 + l] = f2b(m);
}

// ---------------- CondEquiUpdate: assemble invariant input, LN, modulate ----
// p12: [BN,512] f32 (P1|P2)
__global__ __launch_bounds__(256) void k_inv_pre(
    const float* __restrict__ p12,
    const u16* __restrict__ P3, const float* __restrict__ dist,
    const float* __restrict__ W_ui, const float* __restrict__ b_ui,
    const int* __restrict__ ei, const u16* __restrict__ etf, u16* __restrict__ invmod)
{
    int e = blockIdx.x, c = threadIdx.x;
    int row = ei[e], col = ei[E_CNT + e];
    float x = p12[(size_t)row * 512 + c] + p12[(size_t)col * 512 + 256 + c]
            + b2f(P3[(size_t)e * 256 + c]) + dist[e] * W_ui[576 * 256 + c] + b_ui[c];
    float y = block_ln256(x);
    const u16* ep = etf + (size_t)e * 896;
    float m = y * (1.f + b2f(ep[640 + c])) + b2f(ep[384 + c]);
    invmod[(size_t)e * 256 + c] = f2b(m);
}

// ---------------- final per-edge scalar: tanh( silu(y) . W_uc2 ) ------------
__global__ __launch_bounds__(256) void k_inv(const u16* __restrict__ uc1,
                                             const float* __restrict__ W_uc2,
                                             float* __restrict__ inv)
{
    int e = blockIdx.x * 4 + (threadIdx.x >> 6);
    int l = threadIdx.x & 63;
    u16x4 v = *(const u16x4*)(uc1 + (size_t)e * 256 + l * 4);
    const float* w = W_uc2 + l * 4;
    float s = b2f(v[0]) * w[0] + b2f(v[1]) * w[1] + b2f(v[2]) * w[2] + b2f(v[3]) * w[3];
    #pragma unroll
    for (int off = 1; off < 64; off <<= 1) s += __shfl_xor(s, off);
    if (l == 0) inv[e] = tanhf(s);
}

// ---------------- pos update: deterministic contiguous segment sum ----------
__global__ void k_pos(const float* __restrict__ pos, const float* __restrict__ cdiff,
                      const float* __restrict__ inv, float* __restrict__ out3)
{
    int n = blockIdx.x * 256 + threadIdx.x;
    if (n >= BN_CNT) return;
    int b = n / 48, s = n % 48;
    int e0 = b * EPG + s * 47;
    float a0 = 0.f, a1 = 0.f, a2 = 0.f;
    for (int j = 0; j < 47; j++) {
        float f = inv[e0 + j];
        a0 += cdiff[(size_t)(e0 + j) * 3 + 0] * f;
        a1 += cdiff[(size_t)(e0 + j) * 3 + 1] * f;
        a2 += cdiff[(size_t)(e0 + j) * 3 + 2] * f;
    }
    out3[n * 3 + 0] = pos[n * 3 + 0] + a0;
    out3[n * 3 + 1] = pos[n * 3 + 1] + a1;
    out3[n * 3 + 2] = pos[n * 3 + 2] + a2;
}

extern "C" void kernel_launch(void* const* d_in, const int* in_sizes, int n_in,
                              void* d_out, int out_size, void* d_ws, size_t ws_size,
                              hipStream_t stream)
{
    (void)in_sizes; (void)n_in; (void)out_size; (void)ws_size;
    const float* pos       = (const float*)d_in[0];
    const float* h         = (const float*)d_in[1];
    const float* edge_attr = (const float*)d_in[2];
    const float* node_mask = (const float*)d_in[3];
    const float* nte       = (const float*)d_in[4];
    const float* ete       = (const float*)d_in[5];
    const int*   ei        = (const int*)d_in[6];
    const float* W_ee = (const float*)d_in[7];  const float* b_ee = (const float*)d_in[8];
    const float* W_nt = (const float*)d_in[9];  const float* b_nt = (const float*)d_in[10];
    const float* W_et = (const float*)d_in[11]; const float* b_et = (const float*)d_in[12];
    const float* Wq  = (const float*)d_in[13];  const float* bq  = (const float*)d_in[14];
    const float* Wk  = (const float*)d_in[15];  const float* bk  = (const float*)d_in[16];
    const float* Wv  = (const float*)d_in[17];  const float* bv  = (const float*)d_in[18];
    const float* We0 = (const float*)d_in[19];  const float* We1 = (const float*)d_in[20];
    const float* W_n2e = (const float*)d_in[21]; const float* b_n2e = (const float*)d_in[22];
    const float* W_ff1 = (const float*)d_in[23]; const float* b_ff1 = (const float*)d_in[24];
    const float* W_ff2 = (const float*)d_in[25]; const float* b_ff2 = (const float*)d_in[26];
    const float* W_ff3 = (const float*)d_in[27]; const float* b_ff3 = (const float*)d_in[28];
    const float* W_ff4 = (const float*)d_in[29]; const float* b_ff4 = (const float*)d_in[30];
    const float* coors_scale = (const float*)d_in[31];
    const float* W_ut = (const float*)d_in[32]; const float* b_ut = (const float*)d_in[33];
    const float* W_ui = (const float*)d_in[34]; const float* b_ui = (const float*)d_in[35];
    const float* W_uc1 = (const float*)d_in[36]; const float* b_uc1 = (const float*)d_in[37];
    const float* W_uc2 = (const float*)d_in[38];

    const size_t E = E_CNT;
    char* ws = (char*)d_ws;
    size_t off = 0;
    auto AL = [&](size_t b) { size_t o = off; off += (b + 255) & ~(size_t)255; return o; };

    // weights (bf16, transposed [N,K])
    size_t o_wtcat  = AL(896 * 1024 * 2);
    size_t o_wtnt   = AL(1536 * 1024 * 2);
    size_t o_wtqkv  = AL(768 * 256 * 2);
    size_t o_wte01  = AL(512 * 64 * 2);
    size_t o_wtn2e  = AL(64 * 256 * 2);
    size_t o_wtff1  = AL(512 * 256 * 2), o_wtff2 = AL(256 * 512 * 2);
    size_t o_wtff3  = AL(128 * 64 * 2),  o_wtff4 = AL(64 * 128 * 2);
    size_t o_wtuiab = AL(512 * 256 * 2);
    size_t o_wtuic  = AL(256 * 64 * 2),  o_wtuc1 = AL(256 * 256 * 2);
    size_t o_bias896 = AL(896 * 4);
    size_t o_bias768 = AL(768 * 4);
    // big regions (lifetime-based aliasing)
    size_t o_reg1 = AL(E * 1024 * 2);          // ete_silu -> later P3/invmod/uc1o
    size_t o_etf  = AL(E * 896 * 2);           // persistent
    size_t o_ntes = AL(1536 * 1024 * 2);
    size_t o_ntf  = AL((size_t)1536 * 1536 * 4);
    size_t o_eamod = AL(E * 64 * 2);
    size_t o_dist = AL(E * 4), o_cdiff = AL(E * 12);
    size_t o_qkv  = AL(1536 * 768 * 4);
    size_t o_reg3 = AL(E * 512 * 2);           // e01 -> later ffem/heoutbf
    size_t o_hnode = AL(1536 * 256 * 4), o_hnodebf = AL(1536 * 256 * 2);
    size_t o_q1 = AL(1536 * 64 * 4);
    size_t o_hh = AL(1536 * 256 * 2);
    size_t o_hmod = AL(1536 * 256 * 4), o_hmodbf = AL(1536 * 256 * 2);
    size_t o_ff1 = AL(1536 * 512 * 2);
    size_t o_houtbf = AL(1536 * 256 * 2);
    size_t o_hemod = AL(E * 64 * 4), o_hemodbf = AL(E * 64 * 2);
    size_t o_p12 = AL(1536 * 512 * 4);
    size_t o_inv = AL(E * 4);
    // aliases
    size_t o_etes = o_reg1;
    size_t o_p3 = o_reg1;
    size_t o_invmod = o_reg1 + E * 256 * 2;
    size_t o_uc1o = o_reg1 + E * 256 * 4;
    size_t o_e01 = o_reg3;
    size_t o_ffem = o_reg3;
    size_t o_heoutbf = o_reg3 + E * 128 * 2 + E * 64 * 4;

    #define WSU(o) ((u16*)(ws + (o)))
    #define WSF(o) ((float*)(ws + (o)))

    // --- batched weight prep (17 tiled transposes + 5 bias copies) ---
    {
        BatchArgs a;
        int s = 0; int j = 0;
        auto add = [&](const float* W, u16* Wt, int ldw, int k0, int n0, int K, int NC) {
            a.cj[j++] = ConvJob{W, Wt, ldw, k0, n0, K, s, K / 64};
            s += (K / 64) * (NC / 64);
        };
        add(W_et, WSU(o_wtcat), 384, 0, 0, 1024, 384);
        add(W_ut, WSU(o_wtcat) + (size_t)384 * 1024, 512, 0, 0, 1024, 512);
        add(W_nt, WSU(o_wtnt), 1536, 0, 0, 1024, 1536);
        add(Wq, WSU(o_wtqkv), 256, 0, 0, 256, 256);
        add(Wk, WSU(o_wtqkv) + (size_t)256 * 256, 256, 0, 0, 256, 256);
        add(Wv, WSU(o_wtqkv) + (size_t)512 * 256, 256, 0, 0, 256, 256);
        add(We0, WSU(o_wte01), 256, 0, 0, 64, 256);
        add(We1, WSU(o_wte01) + (size_t)256 * 64, 256, 0, 0, 64, 256);
        add(W_n2e, WSU(o_wtn2e), 64, 0, 0, 256, 64);
        add(W_ff1, WSU(o_wtff1), 512, 0, 0, 256, 512);
        add(W_ff2, WSU(o_wtff2), 256, 0, 0, 512, 256);
        add(W_ff3, WSU(o_wtff3), 128, 0, 0, 64, 128);
        add(W_ff4, WSU(o_wtff4), 64, 0, 0, 128, 64);
        add(W_ui, WSU(o_wtuiab), 256, 0, 0, 256, 256);
        add(W_ui, WSU(o_wtuiab) + (size_t)256 * 256, 256, 256, 0, 256, 256);
        add(W_ui, WSU(o_wtuic), 256, 512, 0, 64, 256);
        add(W_uc1, WSU(o_wtuc1), 256, 0, 0, 256, 256);
        a.conv_blocks = s;  // 788 tiles
        a.cp[0] = CopyJob{b_et, WSF(o_bias896), 384};
        a.cp[1] = CopyJob{b_ut, WSF(o_bias896) + 384, 512};
        a.cp[2] = CopyJob{bq, WSF(o_bias768), 256};
        a.cp[3] = CopyJob{bk, WSF(o_bias768) + 256, 256};
        a.cp[4] = CopyJob{bv, WSF(o_bias768) + 512, 256};
        k_prep<<<s + 5, 256, 0, stream>>>(a);
    }

    // --- silu -> bf16 ---
    k_silu_bf<<<2048, 256, 0, stream>>>(ete, WSU(o_etes), (int)(E * 1024 / 4));
    k_silu_bf<<<1024, 256, 0, stream>>>(nte, WSU(o_ntes), 1536 * 1024 / 4);

    // --- big time-embedding GEMMs ---
    k_gemm128<0, 1><<<dim3(7, 564), 256, 0, stream>>>(WSU(o_etes), WSU(o_wtcat), WSF(o_bias896), WSU(o_etf), E_CNT, 896, 1024);
    k_gemm128<0, 0><<<dim3(12, 12), 256, 0, stream>>>(WSU(o_ntes), WSU(o_wtnt), b_nt, WSF(o_ntf), 1536, 1536, 1024);

    // --- edge preprocess ---
    k_edge_pre<<<1128, 256, 0, stream>>>(pos, edge_attr, ei, W_ee, b_ee, coors_scale,
                                         WSU(o_etf), WSU(o_eamod), WSF(o_dist), WSF(o_cdiff));

    // --- node attention path ---
    k_node_hh<<<1536, 256, 0, stream>>>(h, WSF(o_ntf), WSU(o_hh));
    k_gemm128<0, 0><<<dim3(6, 12), 256, 0, stream>>>(WSU(o_hh), WSU(o_wtqkv), WSF(o_bias768), WSF(o_qkv), 1536, 768, 256);
    k_gemm128<0, 1><<<dim3(4, 564), 256, 0, stream>>>(WSU(o_eamod), WSU(o_wte01), nullptr, WSU(o_e01), E_CNT, 512, 64);
    k_agg<<<1536, 256, 0, stream>>>(WSF(o_qkv), WSU(o_e01), WSF(o_hnode), WSU(o_hnodebf));

    // --- Q1 = h_node_raw @ W_n2e ---
    k_gemm<0, 0><<<dim3(1, 24), 256, 0, stream>>>(WSU(o_hnodebf), WSU(o_wtn2e), nullptr, WSF(o_q1), 1536, 64, 256);

    // --- node FFN + output (hout fused into ff2 epilogue) ---
    k_node_mod<<<1536, 256, 0, stream>>>(h, WSF(o_hnode), WSF(o_ntf), node_mask, WSF(o_hmod), WSU(o_hmodbf));
    k_gemm128<1, 1><<<dim3(4, 12), 256, 0, stream>>>(WSU(o_hmodbf), WSU(o_wtff1), b_ff1, WSU(o_ff1), 1536, 512, 256);
    k_gemm_ff2ho<<<dim3(4, 24), 256, 0, stream>>>(WSU(o_ff1), WSU(o_wtff2), b_ff2,
                                                  WSF(o_hmod), WSF(o_ntf), node_mask,
                                                  (float*)d_out, WSU(o_houtbf), 1536, 256, 512);

    // --- edge FFN + output (edge_out fused into ff4 epilogue) ---
    k_edge_mod<<<18048, 256, 0, stream>>>(WSF(o_q1), b_n2e, edge_attr, ei, WSU(o_etf), WSF(o_hemod), WSU(o_hemodbf));
    k_gemm128<1, 1><<<dim3(1, 564), 256, 0, stream>>>(WSU(o_hemodbf), WSU(o_wtff3), b_ff3, WSU(o_ffem), E_CNT, 128, 64);
    k_gemm_ff4eo<<<dim3(1, 1128), 256, 0, stream>>>(WSU(o_ffem), WSU(o_wtff4), b_ff4,
                                                    WSF(o_hemod), WSU(o_etf),
                                                    (float*)d_out + 393216, WSU(o_heoutbf), E_CNT, 64, 128);

    // --- CondEquiUpdate ---
    k_gemm128<0, 0><<<dim3(4, 12), 256, 0, stream>>>(WSU(o_houtbf), WSU(o_wtuiab), nullptr, WSF(o_p12), 1536, 512, 256);
    k_gemm128<0, 1><<<dim3(2, 564), 256, 0, stream>>>(WSU(o_heoutbf), WSU(o_wtuic), nullptr, WSU(o_p3), E_CNT, 256, 64);
    k_inv_pre<<<E_CNT, 256, 0, stream>>>(WSF(o_p12), WSU(o_p3), WSF(o_dist),
                                         W_ui, b_ui, ei, WSU(o_etf), WSU(o_invmod));
    k_gemm128<1, 1><<<dim3(2, 564), 256, 0, stream>>>(WSU(o_invmod), WSU(o_wtuc1), b_uc1, WSU(o_uc1o), E_CNT, 256, 256);
    k_inv<<<18048, 256, 0, stream>>>(WSU(o_uc1o), W_uc2, WSF(o_inv));
    k_pos<<<6, 256, 0, stream>>>(pos, WSF(o_cdiff), WSF(o_inv), (float*)d_out + 393216 + E_CNT * 64);

    #undef WSU
    #undef WSF
}

// Round 15
// 736.796 us; speedup vs baseline: 1.2940x; 1.0110x over previous
//
#include <hip/hip_runtime.h>

typedef unsigned short u16;
typedef __attribute__((ext_vector_type(4))) u16 u16x4;
typedef __attribute__((ext_vector_type(8))) u16 u16x8;
typedef __attribute__((ext_vector_type(8))) short s16x8;
typedef __attribute__((ext_vector_type(4))) float f32x4;

#define E_CNT 72192
#define BN_CNT 1536
// edges per graph = 48*47
#define EPG 2256

__device__ __forceinline__ float b2f(u16 u) {
    union { unsigned int i; float f; } x; x.i = ((unsigned int)u) << 16; return x.f;
}
__device__ __forceinline__ u16 f2b(float f) {
    union { float f; unsigned int i; } x; x.f = f;
    unsigned int r = x.i + 0x7fffu + ((x.i >> 16) & 1u);
    return (u16)(r >> 16);
}
__device__ __forceinline__ float siluf(float x) { return x / (1.f + expf(-x)); }

// async global->LDS, 16B per lane (linear dest). (guide §5 / m97)
__device__ __forceinline__ void gll16(const void* g, void* l) {
    __builtin_amdgcn_global_load_lds(
        (const __attribute__((address_space(1))) void*)g,
        (__attribute__((address_space(3))) void*)l, 16, 0, 0);
}

// ---------------- wave (64-lane) LayerNorm, eps 1e-6, no affine -------------
__device__ __forceinline__ float wave_ln64(float x) {
    float s = x;
    #pragma unroll
    for (int off = 1; off < 64; off <<= 1) s += __shfl_xor(s, off);
    float mean = s * 0.015625f;
    float d = x - mean;
    float v2 = d * d;
    #pragma unroll
    for (int off = 1; off < 64; off <<= 1) v2 += __shfl_xor(v2, off);
    return d * rsqrtf(v2 * 0.015625f + 1e-6f);
}

// ---------------- block(256)-wide LayerNorm over 256 dims -------------------
__device__ __forceinline__ float block_ln256(float x) {
    __shared__ float tmp[4];
    int t = threadIdx.x;
    float s = x;
    #pragma unroll
    for (int off = 1; off < 64; off <<= 1) s += __shfl_xor(s, off);
    if ((t & 63) == 0) tmp[t >> 6] = s;
    __syncthreads();
    float mean = (tmp[0] + tmp[1] + tmp[2] + tmp[3]) * (1.f / 256.f);
    float d = x - mean;
    float v2 = d * d;
    #pragma unroll
    for (int off = 1; off < 64; off <<= 1) v2 += __shfl_xor(v2, off);
    __syncthreads();
    if ((t & 63) == 0) tmp[t >> 6] = v2;
    __syncthreads();
    float var = (tmp[0] + tmp[1] + tmp[2] + tmp[3]) * (1.f / 256.f);
    return d * rsqrtf(var + 1e-6f);
}

// ---------------- generic bf16 MFMA GEMM, 64x64 tile ------------------------
template<int ACT, int OUTBF>
__global__ __launch_bounds__(256) void k_gemm(
    const u16* __restrict__ A, const u16* __restrict__ Bt,
    const float* __restrict__ bias, void* __restrict__ C,
    int M, int N, int K)
{
    __shared__ u16 As[64][40];
    __shared__ u16 Bs[64][40];
    int bn0 = blockIdx.x * 64, bm0 = blockIdx.y * 64;
    int t = threadIdx.x;
    int lane = t & 63, wave = t >> 6;
    int wm = wave >> 1, wn = wave & 1;
    int lr = t >> 2, lc = (t & 3) * 8;
    f32x4 acc[2][2] = {};
    const u16* Ap = A + (size_t)(bm0 + lr) * K + lc;
    const u16* Bp = Bt + (size_t)(bn0 + lr) * K + lc;
    int fr = lane & 15, fk = (lane >> 4) * 8;
    for (int k0 = 0; k0 < K; k0 += 32) {
        *(u16x8*)&As[lr][lc] = *(const u16x8*)(Ap + k0);
        *(u16x8*)&Bs[lr][lc] = *(const u16x8*)(Bp + k0);
        __syncthreads();
        s16x8 a0 = *(const s16x8*)&As[wm * 32 + fr][fk];
        s16x8 a1 = *(const s16x8*)&As[wm * 32 + 16 + fr][fk];
        s16x8 b0 = *(const s16x8*)&Bs[wn * 32 + fr][fk];
        s16x8 b1 = *(const s16x8*)&Bs[wn * 32 + 16 + fr][fk];
        acc[0][0] = __builtin_amdgcn_mfma_f32_16x16x32_bf16(a0, b0, acc[0][0], 0, 0, 0);
        acc[0][1] = __builtin_amdgcn_mfma_f32_16x16x32_bf16(a0, b1, acc[0][1], 0, 0, 0);
        acc[1][0] = __builtin_amdgcn_mfma_f32_16x16x32_bf16(a1, b0, acc[1][0], 0, 0, 0);
        acc[1][1] = __builtin_amdgcn_mfma_f32_16x16x32_bf16(a1, b1, acc[1][1], 0, 0, 0);
        __syncthreads();
    }
    int cIn = lane & 15, r4 = (lane >> 4) * 4;
    #pragma unroll
    for (int i = 0; i < 2; i++)
    #pragma unroll
    for (int j = 0; j < 2; j++) {
        int col = bn0 + wn * 32 + j * 16 + cIn;
        float bv = bias ? bias[col] : 0.f;
        #pragma unroll
        for (int r = 0; r < 4; r++) {
            int rowg = bm0 + wm * 32 + i * 16 + r4 + r;
            float vv = acc[i][j][r] + bv;
            if (ACT == 1) vv = siluf(vv);
            if (OUTBF) ((u16*)C)[(size_t)rowg * N + col] = f2b(vv);
            else       ((float*)C)[(size_t)rowg * N + col] = vv;
        }
    }
}

// ---------------- 64x64 GEMM fused with k_hout epilogue ---------------------
__global__ __launch_bounds__(256) void k_gemm_ff2ho(
    const u16* __restrict__ A, const u16* __restrict__ Bt,
    const float* __restrict__ bias, const float* __restrict__ hmod,
    const float* __restrict__ nt, const float* __restrict__ mask,
    float* __restrict__ out, u16* __restrict__ hout_bf, int M, int N, int K)
{
    __shared__ u16 As[64][40];
    __shared__ u16 Bs[64][40];
    int bn0 = blockIdx.x * 64, bm0 = blockIdx.y * 64;
    int t = threadIdx.x;
    int lane = t & 63, wave = t >> 6;
    int wm = wave >> 1, wn = wave & 1;
    int lr = t >> 2, lc = (t & 3) * 8;
    f32x4 acc[2][2] = {};
    const u16* Ap = A + (size_t)(bm0 + lr) * K + lc;
    const u16* Bp = Bt + (size_t)(bn0 + lr) * K + lc;
    int fr = lane & 15, fk = (lane >> 4) * 8;
    for (int k0 = 0; k0 < K; k0 += 32) {
        *(u16x8*)&As[lr][lc] = *(const u16x8*)(Ap + k0);
        *(u16x8*)&Bs[lr][lc] = *(const u16x8*)(Bp + k0);
        __syncthreads();
        s16x8 a0 = *(const s16x8*)&As[wm * 32 + fr][fk];
        s16x8 a1 = *(const s16x8*)&As[wm * 32 + 16 + fr][fk];
        s16x8 b0 = *(const s16x8*)&Bs[wn * 32 + fr][fk];
        s16x8 b1 = *(const s16x8*)&Bs[wn * 32 + 16 + fr][fk];
        acc[0][0] = __builtin_amdgcn_mfma_f32_16x16x32_bf16(a0, b0, acc[0][0], 0, 0, 0);
        acc[0][1] = __builtin_amdgcn_mfma_f32_16x16x32_bf16(a0, b1, acc[0][1], 0, 0, 0);
        acc[1][0] = __builtin_amdgcn_mfma_f32_16x16x32_bf16(a1, b0, acc[1][0], 0, 0, 0);
        acc[1][1] = __builtin_amdgcn_mfma_f32_16x16x32_bf16(a1, b1, acc[1][1], 0, 0, 0);
        __syncthreads();
    }
    int cIn = lane & 15, r4 = (lane >> 4) * 4;
    #pragma unroll
    for (int i = 0; i < 2; i++)
    #pragma unroll
    for (int j = 0; j < 2; j++) {
        int col = bn0 + wn * 32 + j * 16 + cIn;
        float bv = bias[col];
        #pragma unroll
        for (int r = 0; r < 4; r++) {
            int rowg = bm0 + wm * 32 + i * 16 + r4 + r;
            float x = acc[i][j][r] + bv;
            float v = (hmod[(size_t)rowg * 256 + col]
                     + nt[(size_t)rowg * 1536 + 1280 + col] * x) * mask[rowg];
            out[(size_t)rowg * 256 + col] = v;
            hout_bf[(size_t)rowg * 256 + col] = f2b(v);
        }
    }
}

// ---------------- 64x64 GEMM fused with k_edge_out epilogue -----------------
__global__ __launch_bounds__(256) void k_gemm_ff4eo(
    const u16* __restrict__ A, const u16* __restrict__ Bt,
    const float* __restrict__ bias, const float* __restrict__ hemod,
    const u16* __restrict__ etf,
    float* __restrict__ out2, u16* __restrict__ heout_bf, int M, int N, int K)
{
    __shared__ u16 As[64][40];
    __shared__ u16 Bs[64][40];
    int bn0 = blockIdx.x * 64, bm0 = blockIdx.y * 64;
    int t = threadIdx.x;
    int lane = t & 63, wave = t >> 6;
    int wm = wave >> 1, wn = wave & 1;
    int lr = t >> 2, lc = (t & 3) * 8;
    f32x4 acc[2][2] = {};
    const u16* Ap = A + (size_t)(bm0 + lr) * K + lc;
    const u16* Bp = Bt + (size_t)(bn0 + lr) * K + lc;
    int fr = lane & 15, fk = (lane >> 4) * 8;
    for (int k0 = 0; k0 < K; k0 += 32) {
        *(u16x8*)&As[lr][lc] = *(const u16x8*)(Ap + k0);
        *(u16x8*)&Bs[lr][lc] = *(const u16x8*)(Bp + k0);
        __syncthreads();
        s16x8 a0 = *(const s16x8*)&As[wm * 32 + fr][fk];
        s16x8 a1 = *(const s16x8*)&As[wm * 32 + 16 + fr][fk];
        s16x8 b0 = *(const s16x8*)&Bs[wn * 32 + fr][fk];
        s16x8 b1 = *(const s16x8*)&Bs[wn * 32 + 16 + fr][fk];
        acc[0][0] = __builtin_amdgcn_mfma_f32_16x16x32_bf16(a0, b0, acc[0][0], 0, 0, 0);
        acc[0][1] = __builtin_amdgcn_mfma_f32_16x16x32_bf16(a0, b1, acc[0][1], 0, 0, 0);
        acc[1][0] = __builtin_amdgcn_mfma_f32_16x16x32_bf16(a1, b0, acc[1][0], 0, 0, 0);
        acc[1][1] = __builtin_amdgcn_mfma_f32_16x16x32_bf16(a1, b1, acc[1][1], 0, 0, 0);
        __syncthreads();
    }
    int cIn = lane & 15, r4 = (lane >> 4) * 4;
    #pragma unroll
    for (int i = 0; i < 2; i++)
    #pragma unroll
    for (int j = 0; j < 2; j++) {
        int col = bn0 + wn * 32 + j * 16 + cIn;
        float bv = bias[col];
        #pragma unroll
        for (int r = 0; r < 4; r++) {
            int rowg = bm0 + wm * 32 + i * 16 + r4 + r;
            float x = acc[i][j][r] + bv;
            float v = hemod[(size_t)rowg * 64 + col]
                    + b2f(etf[(size_t)rowg * 896 + 320 + col]) * x;
            out2[(size_t)rowg * 64 + col] = v;
            heout_bf[(size_t)rowg * 64 + col] = f2b(v);
        }
    }
}

// ---------------- 128x128 tile bf16 MFMA GEMM, 3-deep pipelined -------------
// (r5/r6 verified structure: counted vmcnt + both-sides chunk-XOR swizzle)
template<int ACT, int OUTBF>
__global__ __launch_bounds__(256) void k_gemm128(
    const u16* __restrict__ A, const u16* __restrict__ Bt,
    const float* __restrict__ bias, void* __restrict__ C,
    int M, int N, int K)
{
    __shared__ u16 As[3][128 * 32];
    __shared__ u16 Bs[3][128 * 32];
    const int t = threadIdx.x;
    const int lane = t & 63, wv = t >> 6;
    const int wm = wv >> 1, wn = wv & 1;
    const int nwg = gridDim.x * gridDim.y;
    const int orig = blockIdx.y * gridDim.x + blockIdx.x;
    const int q8 = nwg >> 3, r8 = nwg & 7;
    const int xcd = orig & 7, lin = orig >> 3;
    const int wgid = (xcd < r8 ? xcd * (q8 + 1) : r8 * (q8 + 1) + (xcd - r8) * q8) + lin;
    const int bxs = wgid % gridDim.x, bys = wgid / gridDim.x;
    const int bn0 = bxs * 128, bm0 = bys * 128;
    const int srow = t >> 2;
    const int scol = ((t & 3) ^ ((t >> 3) & 3)) * 8;
    const u16* Ap = A + (size_t)(bm0 + srow) * K + scol;
    const u16* Bp = Bt + (size_t)(bn0 + srow) * K + scol;
    const size_t rstep = (size_t)64 * K;
    const int woff = wv * 16 * 32;
    const int fr = lane & 15;
    const int fkc = (((lane >> 4) ^ ((fr >> 1) & 3)) * 8);
    f32x4 acc[4][4] = {};
    const int NT = K >> 5;

    auto STAGE = [&](int b, int ko) {
        gll16(Ap + ko, &As[b][woff]);
        gll16(Ap + ko + rstep, &As[b][woff + 64 * 32]);
        gll16(Bp + ko, &Bs[b][woff]);
        gll16(Bp + ko + rstep, &Bs[b][woff + 64 * 32]);
    };
    auto COMPUTE = [&](int b) {
        const u16* aBase = &As[b][wm * 64 * 32];
        const u16* bBase = &Bs[b][wn * 64 * 32];
        s16x8 af[4], bfr[4];
        #pragma unroll
        for (int m = 0; m < 4; m++) af[m] = *(const s16x8*)&aBase[(m * 16 + fr) * 32 + fkc];
        #pragma unroll
        for (int n = 0; n < 4; n++) bfr[n] = *(const s16x8*)&bBase[(n * 16 + fr) * 32 + fkc];
        #pragma unroll
        for (int m = 0; m < 4; m++)
        #pragma unroll
        for (int n = 0; n < 4; n++)
            acc[m][n] = __builtin_amdgcn_mfma_f32_16x16x32_bf16(af[m], bfr[n], acc[m][n], 0, 0, 0);
    };

    STAGE(0, 0);
    if (NT > 1) STAGE(1, 32);
    int cur = 0;
    for (int tt = 0; tt < NT; tt++) {
        if (tt + 2 < NT) STAGE((cur + 2) % 3, (tt + 2) * 32);
        __builtin_amdgcn_sched_barrier(0);
        int ahead = NT - 1 - tt; if (ahead > 2) ahead = 2;
        if (ahead == 2)      asm volatile("s_waitcnt vmcnt(8)" ::: "memory");
        else if (ahead == 1) asm volatile("s_waitcnt vmcnt(4)" ::: "memory");
        else                 asm volatile("s_waitcnt vmcnt(0)" ::: "memory");
        __builtin_amdgcn_sched_barrier(0);
        __builtin_amdgcn_s_barrier();
        COMPUTE(cur);
        __builtin_amdgcn_s_barrier();
        __builtin_amdgcn_sched_barrier(0);
        cur = (cur + 1) % 3;
    }

    const int cIn = lane & 15, r4 = (lane >> 4) * 4;
    #pragma unroll
    for (int n = 0; n < 4; n++) {
        int col = bn0 + wn * 64 + n * 16 + cIn;
        float bv = bias ? bias[col] : 0.f;
        #pragma unroll
        for (int m = 0; m < 4; m++) {
            #pragma unroll
            for (int r = 0; r < 4; r++) {
                int rowg = bm0 + wm * 64 + m * 16 + r4 + r;
                float vv = acc[m][n][r] + bv;
                if (ACT == 1) vv = siluf(vv);
                if (OUTBF) ((u16*)C)[(size_t)rowg * N + col] = f2b(vv);
                else       ((float*)C)[(size_t)rowg * N + col] = vv;
            }
        }
    }
}

// ---------------- DUAL 128x128 GEMM: two independent jobs, one dispatch -----
// Identical verified ring-3 body; job selected by block id (block-uniform).
// act/outbf runtime flags (epilogue-only branches). Lets a small GEMM ride
// concurrently inside a big one (same-stream kernels can never overlap).
struct GJob {
    const u16* A; const u16* Bt; const float* bias; void* C;
    int M, N, K, gx, nwg, act, outbf;
};

__global__ __launch_bounds__(256) void k_gemm128_dual(GJob ja, GJob jb)
{
    const bool first = (int)blockIdx.x < ja.nwg;
    const GJob J = first ? ja : jb;
    const int orig = first ? blockIdx.x : blockIdx.x - ja.nwg;
    __shared__ u16 As[3][128 * 32];
    __shared__ u16 Bs[3][128 * 32];
    const int t = threadIdx.x;
    const int lane = t & 63, wv = t >> 6;
    const int wm = wv >> 1, wn = wv & 1;
    const int K = J.K;
    const int q8 = J.nwg >> 3, r8 = J.nwg & 7;
    const int xcd = orig & 7, lin = orig >> 3;
    const int wgid = (xcd < r8 ? xcd * (q8 + 1) : r8 * (q8 + 1) + (xcd - r8) * q8) + lin;
    const int bxs = wgid % J.gx, bys = wgid / J.gx;
    const int bn0 = bxs * 128, bm0 = bys * 128;
    const int srow = t >> 2;
    const int scol = ((t & 3) ^ ((t >> 3) & 3)) * 8;
    const u16* Ap = J.A + (size_t)(bm0 + srow) * K + scol;
    const u16* Bp = J.Bt + (size_t)(bn0 + srow) * K + scol;
    const size_t rstep = (size_t)64 * K;
    const int woff = wv * 16 * 32;
    const int fr = lane & 15;
    const int fkc = (((lane >> 4) ^ ((fr >> 1) & 3)) * 8);
    f32x4 acc[4][4] = {};
    const int NT = K >> 5;

    auto STAGE = [&](int b, int ko) {
        gll16(Ap + ko, &As[b][woff]);
        gll16(Ap + ko + rstep, &As[b][woff + 64 * 32]);
        gll16(Bp + ko, &Bs[b][woff]);
        gll16(Bp + ko + rstep, &Bs[b][woff + 64 * 32]);
    };
    auto COMPUTE = [&](int b) {
        const u16* aBase = &As[b][wm * 64 * 32];
        const u16* bBase = &Bs[b][wn * 64 * 32];
        s16x8 af[4], bfr[4];
        #pragma unroll
        for (int m = 0; m < 4; m++) af[m] = *(const s16x8*)&aBase[(m * 16 + fr) * 32 + fkc];
        #pragma unroll
        for (int n = 0; n < 4; n++) bfr[n] = *(const s16x8*)&bBase[(n * 16 + fr) * 32 + fkc];
        #pragma unroll
        for (int m = 0; m < 4; m++)
        #pragma unroll
        for (int n = 0; n < 4; n++)
            acc[m][n] = __builtin_amdgcn_mfma_f32_16x16x32_bf16(af[m], bfr[n], acc[m][n], 0, 0, 0);
    };

    STAGE(0, 0);
    if (NT > 1) STAGE(1, 32);
    int cur = 0;
    for (int tt = 0; tt < NT; tt++) {
        if (tt + 2 < NT) STAGE((cur + 2) % 3, (tt + 2) * 32);
        __builtin_amdgcn_sched_barrier(0);
        int ahead = NT - 1 - tt; if (ahead > 2) ahead = 2;
        if (ahead == 2)      asm volatile("s_waitcnt vmcnt(8)" ::: "memory");
        else if (ahead == 1) asm volatile("s_waitcnt vmcnt(4)" ::: "memory");
        else                 asm volatile("s_waitcnt vmcnt(0)" ::: "memory");
        __builtin_amdgcn_sched_barrier(0);
        __builtin_amdgcn_s_barrier();
        COMPUTE(cur);
        __builtin_amdgcn_s_barrier();
        __builtin_amdgcn_sched_barrier(0);
        cur = (cur + 1) % 3;
    }

    const int cIn = lane & 15, r4 = (lane >> 4) * 4;
    #pragma unroll
    for (int n = 0; n < 4; n++) {
        int col = bn0 + wn * 64 + n * 16 + cIn;
        float bv = J.bias ? J.bias[col] : 0.f;
        #pragma unroll
        for (int m = 0; m < 4; m++) {
            #pragma unroll
            for (int r = 0; r < 4; r++) {
                int rowg = bm0 + wm * 64 + m * 16 + r4 + r;
                float vv = acc[m][n][r] + bv;
                if (J.act) vv = siluf(vv);
                if (J.outbf) ((u16*)J.C)[(size_t)rowg * J.N + col] = f2b(vv);
                else         ((float*)J.C)[(size_t)rowg * J.N + col] = vv;
            }
        }
    }
}

// ---------------- batched weight prep: LDS-tiled transposes + bias copies ---
struct ConvJob { const float* W; u16* Wt; int ldw, k0, n0, K, tile_start, tiles_k; };
struct CopyJob { const float* src; float* dst; int n; };
struct BatchArgs { ConvJob cj[17]; CopyJob cp[5]; int conv_blocks; };

__global__ __launch_bounds__(256) void k_prep(BatchArgs a)
{
    __shared__ float ls[64][65];
    int b = blockIdx.x;
    int t = threadIdx.x;
    if (b < a.conv_blocks) {
        int j = 0;
        #pragma unroll 1
        while (j + 1 < 17 && a.cj[j + 1].tile_start <= b) ++j;
        const ConvJob J = a.cj[j];
        int local = b - J.tile_start;
        int tk = local % J.tiles_k, tn = local / J.tiles_k;
        int k0 = tk * 64, n0 = tn * 64;
        int cn = t & 63, rk = t >> 6;
        #pragma unroll
        for (int p = 0; p < 16; p++) {
            int kk = p * 4 + rk;
            ls[kk][cn] = J.W[(size_t)(J.k0 + k0 + kk) * J.ldw + J.n0 + n0 + cn];
        }
        __syncthreads();
        int ck = t & 63, rn = t >> 6;
        #pragma unroll
        for (int p = 0; p < 16; p++) {
            int nn = p * 4 + rn;
            J.Wt[(size_t)(n0 + nn) * J.K + k0 + ck] = f2b(ls[ck][nn]);
        }
    } else {
        int c = b - a.conv_blocks;
        const CopyJob C = a.cp[c];
        for (int i = t; i < C.n; i += 256) C.dst[i] = C.src[i];
    }
}

// ---------------- silu -> bf16 (vectorized, grid-stride) --------------------
__global__ void k_silu_bf(const float* __restrict__ in, u16* __restrict__ out, int n4)
{
    int i = blockIdx.x * 256 + threadIdx.x;
    int stride = gridDim.x * 256;
    for (; i < n4; i += stride) {
        f32x4 v = *(const f32x4*)(in + (size_t)i * 4);
        u16x4 o;
        #pragma unroll
        for (int j = 0; j < 4; j++) o[j] = f2b(siluf(v[j]));
        *(u16x4*)(out + (size_t)i * 4) = o;
    }
}

// ---------------- edge preprocessing (64 edges per block) -------------------
__global__ __launch_bounds__(256) void k_edge_pre(
    const float* __restrict__ pos, const float* __restrict__ edge_attr,
    const int* __restrict__ ei, const float* __restrict__ W_ee,
    const float* __restrict__ b_ee, const float* __restrict__ coors_scale,
    const u16* __restrict__ etf,
    u16* __restrict__ ea_mod, float* __restrict__ dist, float* __restrict__ cdiff)
{
    __shared__ float Ws[65][64];
    int t = threadIdx.x;
    for (int i = t; i < 65 * 64; i += 256) Ws[i >> 6][i & 63] = W_ee[i];
    __syncthreads();
    int l = t & 63;
    float bee = b_ee[l];
    float cscale = coors_scale[0];
    for (int g = 0; g < 16; g++) {
        int e = blockIdx.x * 64 + g * 4 + (t >> 6);
        int row = ei[e], col = ei[E_CNT + e];
        float d0 = pos[row * 3 + 0] - pos[col * 3 + 0];
        float d1 = pos[row * 3 + 1] - pos[col * 3 + 1];
        float d2 = pos[row * 3 + 2] - pos[col * 3 + 2];
        float ssq = d0 * d0 + d1 * d1 + d2 * d2;
        float dst = sqrtf(ssq + 1e-12f);
        float nrm = sqrtf(ssq);
        float cs = cscale / fmaxf(nrm, 1e-8f);
        if (l == 0) {
            dist[e] = dst;
            cdiff[e * 3 + 0] = d0 * cs; cdiff[e * 3 + 1] = d1 * cs; cdiff[e * 3 + 2] = d2 * cs;
        }
        float attr = edge_attr[(size_t)e * 64 + l];
        float acc = dst * Ws[0][l];
        for (int f = 0; f < 64; f++) acc += __shfl(attr, f) * Ws[1 + f][l];
        acc += bee;
        float y = wave_ln64(acc);
        const u16* ep = etf + (size_t)e * 896;
        float m = y * (1.f + b2f(ep[64 + l])) + b2f(ep[l]);
        ea_mod[(size_t)e * 64 + l] = f2b(m);
    }
}

// ---------------- node: hh = modulate(ln(h), sh_msa, sc_msa) -> bf16 --------
__global__ __launch_bounds__(256) void k_node_hh(
    const float* __restrict__ h, const float* __restrict__ nt, u16* __restrict__ hh)
{
    int n = blockIdx.x, c = threadIdx.x;
    float x = h[(size_t)n * 256 + c];
    float y = block_ln256(x);
    float m = y * (1.f + nt[(size_t)n * 1536 + 256 + c]) + nt[(size_t)n * 1536 + c];
    hh[(size_t)n * 256 + c] = f2b(m);
}

// ---------------- fused per-node: alpha + softmax + aggregation -------------
// qkv: [BN,768] f32 (q|k|v); e01: [E,512] bf16 (e0|e1)
__global__ __launch_bounds__(256) void k_agg(
    const float* __restrict__ qkv, const u16* __restrict__ e01,
    float* __restrict__ hnode, u16* __restrict__ hnode_bf)
{
    int n = blockIdx.x;
    int b = n / 48, i = n % 48;
    int t = threadIdx.x;
    __shared__ float qs[8][33];
    __shared__ float att[47][8];
    __shared__ float mxs[8], dens[8];
    __shared__ int elist[47], slist[47];
    qs[t >> 5][t & 31] = qkv[(size_t)n * 768 + t];
    if (t < 47) {
        int s = t + (t >= i ? 1 : 0);
        slist[t] = s;
        elist[t] = b * EPG + s * 47 + (i < s ? i : i - 1);
    }
    __syncthreads();
    for (int idx = t; idx < 376; idx += 256) {
        int j = idx >> 3, hh = idx & 7;
        int src = b * 48 + slist[j];
        int e = elist[j];
        const float* kp = qkv + (size_t)src * 768 + 256 + hh * 32;
        const u16* ep = e01 + (size_t)e * 512 + hh * 32;
        float p = 0.f;
        #pragma unroll
        for (int d = 0; d < 32; d++) p += qs[hh][d] * kp[d] * b2f(ep[d]);
        att[j][hh] = p * 0.17677669529663687f; // 1/sqrt(32)
    }
    __syncthreads();
    if (t < 8) {
        float m = -1e30f;
        for (int j = 0; j < 47; j++) m = fmaxf(m, att[j][t]);
        float den = 0.f;
        for (int j = 0; j < 47; j++) den += expf(att[j][t] - m);
        mxs[t] = m; dens[t] = den + 1e-16f;
    }
    __syncthreads();
    for (int idx = t; idx < 376; idx += 256) {
        int j = idx >> 3, hh = idx & 7;
        att[j][hh] = expf(att[j][hh] - mxs[hh]) / dens[hh];
    }
    __syncthreads();
    int c = t, hh = t >> 5;
    float acc = 0.f;
    for (int j = 0; j < 47; j++) {
        int src = b * 48 + slist[j];
        int e = elist[j];
        acc += att[j][hh] * qkv[(size_t)src * 768 + 512 + c] * b2f(e01[(size_t)e * 512 + 256 + c]);
    }
    hnode[(size_t)n * 256 + c] = acc;
    hnode_bf[(size_t)n * 256 + c] = f2b(acc);
}

// ---------------- node: residual + LN + modulate(mlp) * mask ----------------
__global__ __launch_bounds__(256) void k_node_mod(
    const float* __restrict__ h, const float* __restrict__ hnode_raw,
    const float* __restrict__ nt, const float* __restrict__ mask,
    float* __restrict__ hmod, u16* __restrict__ hmod_bf)
{
    int n = blockIdx.x, c = threadIdx.x;
    float x = h[(size_t)n * 256 + c] + nt[(size_t)n * 1536 + 512 + c] * hnode_raw[(size_t)n * 256 + c];
    float y = block_ln256(x);
    float m = (y * (1.f + nt[(size_t)n * 1536 + 1024 + c]) + nt[(size_t)n * 1536 + 768 + c]) * mask[n];
    hmod[(size_t)n * 256 + c] = m;
    hmod_bf[(size_t)n * 256 + c] = f2b(m);
}

// ---------------- edge: h_e = edge_attr + g*h_edge; LN; modulate ------------
__global__ __launch_bounds__(256) void k_edge_mod(
    const float* __restrict__ Q1, const float* __restrict__ b_n2e,
    const float* __restrict__ edge_attr, const int* __restrict__ ei,
    const u16* __restrict__ etf, float* __restrict__ hemod, u16* __restrict__ hemod_bf)
{
    int e = blockIdx.x * 4 + (threadIdx.x >> 6);
    int l = threadIdx.x & 63;
    int row = ei[e], col = ei[E_CNT + e];
    float hedge = Q1[(size_t)row * 64 + l] + Q1[(size_t)col * 64 + l] + b_n2e[l];
    const u16* ep = etf + (size_t)e * 896;
    float x = edge_attr[(size_t)e * 64 + l] + b2f(ep[128 + l]) * hedge;
    float y = wave_ln64(x);
    float m = y * (1.f + b2f(ep[256 + l])) + b2f(ep[192 + l]);
    hemod[(size_t)e * 64 + l] = m;
    hemod_bf[(size_t)e * 64 + l] = f2b(m);
}

// ---------------- CondEquiUpdate: assemble invariant input, LN, modulate ----
// p12: [BN,512] f32 (P1|P2)
__global__ __launch_bounds__(256) void k_inv_pre(
    const float* __restrict__ p12,
    const u16* __restrict__ P3, const float* __restrict__ dist,
    const float* __restrict__ W_ui, const float* __restrict__ b_ui,
    const int* __restrict__ ei, const u16* __restrict__ etf, u16* __restrict__ invmod)
{
    int e = blockIdx.x, c = threadIdx.x;
    int row = ei[e], col = ei[E_CNT + e];
    float x = p12[(size_t)row * 512 + c] + p12[(size_t)col * 512 + 256 + c]
            + b2f(P3[(size_t)e * 256 + c]) + dist[e] * W_ui[576 * 256 + c] + b_ui[c];
    float y = block_ln256(x);
    const u16* ep = etf + (size_t)e * 896;
    float m = y * (1.f + b2f(ep[640 + c])) + b2f(ep[384 + c]);
    invmod[(size_t)e * 256 + c] = f2b(m);
}

// ---------------- final per-edge scalar: tanh( silu(y) . W_uc2 ) ------------
__global__ __launch_bounds__(256) void k_inv(const u16* __restrict__ uc1,
                                             const float* __restrict__ W_uc2,
                                             float* __restrict__ inv)
{
    int e = blockIdx.x * 4 + (threadIdx.x >> 6);
    int l = threadIdx.x & 63;
    u16x4 v = *(const u16x4*)(uc1 + (size_t)e * 256 + l * 4);
    const float* w = W_uc2 + l * 4;
    float s = b2f(v[0]) * w[0] + b2f(v[1]) * w[1] + b2f(v[2]) * w[2] + b2f(v[3]) * w[3];
    #pragma unroll
    for (int off = 1; off < 64; off <<= 1) s += __shfl_xor(s, off);
    if (l == 0) inv[e] = tanhf(s);
}

// ---------------- pos update: deterministic contiguous segment sum ----------
__global__ void k_pos(const float* __restrict__ pos, const float* __restrict__ cdiff,
                      const float* __restrict__ inv, float* __restrict__ out3)
{
    int n = blockIdx.x * 256 + threadIdx.x;
    if (n >= BN_CNT) return;
    int b = n / 48, s = n % 48;
    int e0 = b * EPG + s * 47;
    float a0 = 0.f, a1 = 0.f, a2 = 0.f;
    for (int j = 0; j < 47; j++) {
        float f = inv[e0 + j];
        a0 += cdiff[(size_t)(e0 + j) * 3 + 0] * f;
        a1 += cdiff[(size_t)(e0 + j) * 3 + 1] * f;
        a2 += cdiff[(size_t)(e0 + j) * 3 + 2] * f;
    }
    out3[n * 3 + 0] = pos[n * 3 + 0] + a0;
    out3[n * 3 + 1] = pos[n * 3 + 1] + a1;
    out3[n * 3 + 2] = pos[n * 3 + 2] + a2;
}

extern "C" void kernel_launch(void* const* d_in, const int* in_sizes, int n_in,
                              void* d_out, int out_size, void* d_ws, size_t ws_size,
                              hipStream_t stream)
{
    (void)in_sizes; (void)n_in; (void)out_size; (void)ws_size;
    const float* pos       = (const float*)d_in[0];
    const float* h         = (const float*)d_in[1];
    const float* edge_attr = (const float*)d_in[2];
    const float* node_mask = (const float*)d_in[3];
    const float* nte       = (const float*)d_in[4];
    const float* ete       = (const float*)d_in[5];
    const int*   ei        = (const int*)d_in[6];
    const float* W_ee = (const float*)d_in[7];  const float* b_ee = (const float*)d_in[8];
    const float* W_nt = (const float*)d_in[9];  const float* b_nt = (const float*)d_in[10];
    const float* W_et = (const float*)d_in[11]; const float* b_et = (const float*)d_in[12];
    const float* Wq  = (const float*)d_in[13];  const float* bq  = (const float*)d_in[14];
    const float* Wk  = (const float*)d_in[15];  const float* bk  = (const float*)d_in[16];
    const float* Wv  = (const float*)d_in[17];  const float* bv  = (const float*)d_in[18];
    const float* We0 = (const float*)d_in[19];  const float* We1 = (const float*)d_in[20];
    const float* W_n2e = (const float*)d_in[21]; const float* b_n2e = (const float*)d_in[22];
    const float* W_ff1 = (const float*)d_in[23]; const float* b_ff1 = (const float*)d_in[24];
    const float* W_ff2 = (const float*)d_in[25]; const float* b_ff2 = (const float*)d_in[26];
    const float* W_ff3 = (const float*)d_in[27]; const float* b_ff3 = (const float*)d_in[28];
    const float* W_ff4 = (const float*)d_in[29]; const float* b_ff4 = (const float*)d_in[30];
    const float* coors_scale = (const float*)d_in[31];
    const float* W_ut = (const float*)d_in[32]; const float* b_ut = (const float*)d_in[33];
    const float* W_ui = (const float*)d_in[34]; const float* b_ui = (const float*)d_in[35];
    const float* W_uc1 = (const float*)d_in[36]; const float* b_uc1 = (const float*)d_in[37];
    const float* W_uc2 = (const float*)d_in[38];

    const size_t E = E_CNT;
    char* ws = (char*)d_ws;
    size_t off = 0;
    auto AL = [&](size_t b) { size_t o = off; off += (b + 255) & ~(size_t)255; return o; };

    // weights (bf16, transposed [N,K])
    size_t o_wtcat  = AL(896 * 1024 * 2);
    size_t o_wtnt   = AL(1536 * 1024 * 2);
    size_t o_wtqkv  = AL(768 * 256 * 2);
    size_t o_wte01  = AL(512 * 64 * 2);
    size_t o_wtn2e  = AL(64 * 256 * 2);
    size_t o_wtff1  = AL(512 * 256 * 2), o_wtff2 = AL(256 * 512 * 2);
    size_t o_wtff3  = AL(128 * 64 * 2),  o_wtff4 = AL(64 * 128 * 2);
    size_t o_wtuiab = AL(512 * 256 * 2);
    size_t o_wtuic  = AL(256 * 64 * 2),  o_wtuc1 = AL(256 * 256 * 2);
    size_t o_bias896 = AL(896 * 4);
    size_t o_bias768 = AL(768 * 4);
    // big regions (lifetime-based aliasing)
    size_t o_reg1 = AL(E * 1024 * 2);          // ete_silu -> later P3/invmod/uc1o
    size_t o_etf  = AL(E * 896 * 2);           // persistent
    size_t o_ntes = AL(1536 * 1024 * 2);
    size_t o_ntf  = AL((size_t)1536 * 1536 * 4);
    size_t o_eamod = AL(E * 64 * 2);
    size_t o_dist = AL(E * 4), o_cdiff = AL(E * 12);
    size_t o_qkv  = AL(1536 * 768 * 4);
    size_t o_reg3 = AL(E * 512 * 2);           // e01 -> later ffem/heoutbf
    size_t o_hnode = AL(1536 * 256 * 4), o_hnodebf = AL(1536 * 256 * 2);
    size_t o_q1 = AL(1536 * 64 * 4);
    size_t o_hh = AL(1536 * 256 * 2);
    size_t o_hmod = AL(1536 * 256 * 4), o_hmodbf = AL(1536 * 256 * 2);
    size_t o_ff1 = AL(1536 * 512 * 2);
    size_t o_houtbf = AL(1536 * 256 * 2);
    size_t o_hemod = AL(E * 64 * 4), o_hemodbf = AL(E * 64 * 2);
    size_t o_p12 = AL(1536 * 512 * 4);
    size_t o_inv = AL(E * 4);
    // aliases
    size_t o_etes = o_reg1;
    size_t o_p3 = o_reg1;
    size_t o_invmod = o_reg1 + E * 256 * 2;
    size_t o_uc1o = o_reg1 + E * 256 * 4;
    size_t o_e01 = o_reg3;
    size_t o_ffem = o_reg3;
    size_t o_heoutbf = o_reg3 + E * 128 * 2 + E * 64 * 4;

    #define WSU(o) ((u16*)(ws + (o)))
    #define WSF(o) ((float*)(ws + (o)))

    // --- batched weight prep (17 tiled transposes + 5 bias copies) ---
    {
        BatchArgs a;
        int s = 0; int j = 0;
        auto add = [&](const float* W, u16* Wt, int ldw, int k0, int n0, int K, int NC) {
            a.cj[j++] = ConvJob{W, Wt, ldw, k0, n0, K, s, K / 64};
            s += (K / 64) * (NC / 64);
        };
        add(W_et, WSU(o_wtcat), 384, 0, 0, 1024, 384);
        add(W_ut, WSU(o_wtcat) + (size_t)384 * 1024, 512, 0, 0, 1024, 512);
        add(W_nt, WSU(o_wtnt), 1536, 0, 0, 1024, 1536);
        add(Wq, WSU(o_wtqkv), 256, 0, 0, 256, 256);
        add(Wk, WSU(o_wtqkv) + (size_t)256 * 256, 256, 0, 0, 256, 256);
        add(Wv, WSU(o_wtqkv) + (size_t)512 * 256, 256, 0, 0, 256, 256);
        add(We0, WSU(o_wte01), 256, 0, 0, 64, 256);
        add(We1, WSU(o_wte01) + (size_t)256 * 64, 256, 0, 0, 64, 256);
        add(W_n2e, WSU(o_wtn2e), 64, 0, 0, 256, 64);
        add(W_ff1, WSU(o_wtff1), 512, 0, 0, 256, 512);
        add(W_ff2, WSU(o_wtff2), 256, 0, 0, 512, 256);
        add(W_ff3, WSU(o_wtff3), 128, 0, 0, 64, 128);
        add(W_ff4, WSU(o_wtff4), 64, 0, 0, 128, 64);
        add(W_ui, WSU(o_wtuiab), 256, 0, 0, 256, 256);
        add(W_ui, WSU(o_wtuiab) + (size_t)256 * 256, 256, 256, 0, 256, 256);
        add(W_ui, WSU(o_wtuic), 256, 512, 0, 64, 256);
        add(W_uc1, WSU(o_wtuc1), 256, 0, 0, 256, 256);
        a.conv_blocks = s;  // 788 tiles
        a.cp[0] = CopyJob{b_et, WSF(o_bias896), 384};
        a.cp[1] = CopyJob{b_ut, WSF(o_bias896) + 384, 512};
        a.cp[2] = CopyJob{bq, WSF(o_bias768), 256};
        a.cp[3] = CopyJob{bk, WSF(o_bias768) + 256, 256};
        a.cp[4] = CopyJob{bv, WSF(o_bias768) + 512, 256};
        k_prep<<<s + 5, 256, 0, stream>>>(a);
    }

    // --- silu -> bf16 ---
    k_silu_bf<<<2048, 256, 0, stream>>>(ete, WSU(o_etes), (int)(E * 1024 / 4));
    k_silu_bf<<<1024, 256, 0, stream>>>(nte, WSU(o_ntes), 1536 * 1024 / 4);

    // --- big time-embedding GEMMs: et || nt in ONE dispatch ---
    {
        GJob ja{WSU(o_etes), WSU(o_wtcat), WSF(o_bias896), WSU(o_etf),
                E_CNT, 896, 1024, 7, 3948, 0, 1};
        GJob jb{WSU(o_ntes), WSU(o_wtnt), b_nt, WSF(o_ntf),
                1536, 1536, 1024, 12, 144, 0, 0};
        k_gemm128_dual<<<3948 + 144, 256, 0, stream>>>(ja, jb);
    }

    // --- edge/node preprocess ---
    k_edge_pre<<<1128, 256, 0, stream>>>(pos, edge_attr, ei, W_ee, b_ee, coors_scale,
                                         WSU(o_etf), WSU(o_eamod), WSF(o_dist), WSF(o_cdiff));
    k_node_hh<<<1536, 256, 0, stream>>>(h, WSF(o_ntf), WSU(o_hh));

    // --- attention inputs: e01 || qkv in ONE dispatch ---
    {
        GJob ja{WSU(o_eamod), WSU(o_wte01), nullptr, WSU(o_e01),
                E_CNT, 512, 64, 4, 2256, 0, 1};
        GJob jb{WSU(o_hh), WSU(o_wtqkv), WSF(o_bias768), WSF(o_qkv),
                1536, 768, 256, 6, 72, 0, 0};
        k_gemm128_dual<<<2256 + 72, 256, 0, stream>>>(ja, jb);
    }
    k_agg<<<1536, 256, 0, stream>>>(WSF(o_qkv), WSU(o_e01), WSF(o_hnode), WSU(o_hnodebf));

    // --- Q1 = h_node_raw @ W_n2e ---
    k_gemm<0, 0><<<dim3(1, 24), 256, 0, stream>>>(WSU(o_hnodebf), WSU(o_wtn2e), nullptr, WSF(o_q1), 1536, 64, 256);

    // --- mod kernels (both FFN inputs ready before the dual) ---
    k_node_mod<<<1536, 256, 0, stream>>>(h, WSF(o_hnode), WSF(o_ntf), node_mask, WSF(o_hmod), WSU(o_hmodbf));
    k_edge_mod<<<18048, 256, 0, stream>>>(WSF(o_q1), b_n2e, edge_attr, ei, WSU(o_etf), WSF(o_hemod), WSU(o_hemodbf));

    // --- FFN stage 1: ff3 || ff1 in ONE dispatch ---
    {
        GJob ja{WSU(o_hemodbf), WSU(o_wtff3), b_ff3, WSU(o_ffem),
                E_CNT, 128, 64, 1, 564, 1, 1};
        GJob jb{WSU(o_hmodbf), WSU(o_wtff1), b_ff1, WSU(o_ff1),
                1536, 512, 256, 4, 48, 1, 1};
        k_gemm128_dual<<<564 + 48, 256, 0, stream>>>(ja, jb);
    }

    // --- FFN stage 2 with fused output epilogues ---
    k_gemm_ff2ho<<<dim3(4, 24), 256, 0, stream>>>(WSU(o_ff1), WSU(o_wtff2), b_ff2,
                                                  WSF(o_hmod), WSF(o_ntf), node_mask,
                                                  (float*)d_out, WSU(o_houtbf), 1536, 256, 512);
    k_gemm_ff4eo<<<dim3(1, 1128), 256, 0, stream>>>(WSU(o_ffem), WSU(o_wtff4), b_ff4,
                                                    WSF(o_hemod), WSU(o_etf),
                                                    (float*)d_out + 393216, WSU(o_heoutbf), E_CNT, 64, 128);

    // --- CondEquiUpdate: p3 || p12 in ONE dispatch ---
    {
        GJob ja{WSU(o_heoutbf), WSU(o_wtuic), nullptr, WSU(o_p3),
                E_CNT, 256, 64, 2, 1128, 0, 1};
        GJob jb{WSU(o_houtbf), WSU(o_wtuiab), nullptr, WSF(o_p12),
                1536, 512, 256, 4, 48, 0, 0};
        k_gemm128_dual<<<1128 + 48, 256, 0, stream>>>(ja, jb);
    }
    k_inv_pre<<<E_CNT, 256, 0, stream>>>(WSF(o_p12), WSU(o_p3), WSF(o_dist),
                                         W_ui, b_ui, ei, WSU(o_etf), WSU(o_invmod));
    k_gemm128<1, 1><<<dim3(2, 564), 256, 0, stream>>>(WSU(o_invmod), WSU(o_wtuc1), b_uc1, WSU(o_uc1o), E_CNT, 256, 256);
    k_inv<<<18048, 256, 0, stream>>>(WSU(o_uc1o), W_uc2, WSF(o_inv));
    k_pos<<<6, 256, 0, stream>>>(pos, WSF(o_cdiff), WSF(o_inv), (float*)d_out + 393216 + E_CNT * 64);

    #undef WSU
    #undef WSF
}

// Round 16
// 689.412 us; speedup vs baseline: 1.3830x; 1.0687x over previous
//
#include <hip/hip_runtime.h>

typedef unsigned short u16;
typedef __attribute__((ext_vector_type(4))) u16 u16x4;
typedef __attribute__((ext_vector_type(8))) u16 u16x8;
typedef __attribute__((ext_vector_type(8))) short s16x8;
typedef __attribute__((ext_vector_type(4))) float f32x4;

#define E_CNT 72192
#define BN_CNT 1536
// edges per graph = 48*47
#define EPG 2256

__device__ __forceinline__ float b2f(u16 u) {
    union { unsigned int i; float f; } x; x.i = ((unsigned int)u) << 16; return x.f;
}
__device__ __forceinline__ u16 f2b(float f) {
    union { float f; unsigned int i; } x; x.f = f;
    unsigned int r = x.i + 0x7fffu + ((x.i >> 16) & 1u);
    return (u16)(r >> 16);
}
__device__ __forceinline__ float siluf(float x) { return x / (1.f + expf(-x)); }

// async global->LDS, 16B per lane (linear dest). (guide §5 / m97)
__device__ __forceinline__ void gll16(const void* g, void* l) {
    __builtin_amdgcn_global_load_lds(
        (const __attribute__((address_space(1))) void*)g,
        (__attribute__((address_space(3))) void*)l, 16, 0, 0);
}

// ---------------- wave (64-lane) LayerNorm, eps 1e-6, no affine -------------
__device__ __forceinline__ float wave_ln64(float x) {
    float s = x;
    #pragma unroll
    for (int off = 1; off < 64; off <<= 1) s += __shfl_xor(s, off);
    float mean = s * 0.015625f;
    float d = x - mean;
    float v2 = d * d;
    #pragma unroll
    for (int off = 1; off < 64; off <<= 1) v2 += __shfl_xor(v2, off);
    return d * rsqrtf(v2 * 0.015625f + 1e-6f);
}

// ---------------- block(256)-wide LayerNorm over 256 dims -------------------
__device__ __forceinline__ float block_ln256(float x) {
    __shared__ float tmp[4];
    int t = threadIdx.x;
    float s = x;
    #pragma unroll
    for (int off = 1; off < 64; off <<= 1) s += __shfl_xor(s, off);
    if ((t & 63) == 0) tmp[t >> 6] = s;
    __syncthreads();
    float mean = (tmp[0] + tmp[1] + tmp[2] + tmp[3]) * (1.f / 256.f);
    float d = x - mean;
    float v2 = d * d;
    #pragma unroll
    for (int off = 1; off < 64; off <<= 1) v2 += __shfl_xor(v2, off);
    __syncthreads();
    if ((t & 63) == 0) tmp[t >> 6] = v2;
    __syncthreads();
    float var = (tmp[0] + tmp[1] + tmp[2] + tmp[3]) * (1.f / 256.f);
    return d * rsqrtf(var + 1e-6f);
}

// ---------------- generic bf16 MFMA GEMM, 64x64 tile ------------------------
template<int ACT, int OUTBF>
__global__ __launch_bounds__(256) void k_gemm(
    const u16* __restrict__ A, const u16* __restrict__ Bt,
    const float* __restrict__ bias, void* __restrict__ C,
    int M, int N, int K)
{
    __shared__ u16 As[64][40];
    __shared__ u16 Bs[64][40];
    int bn0 = blockIdx.x * 64, bm0 = blockIdx.y * 64;
    int t = threadIdx.x;
    int lane = t & 63, wave = t >> 6;
    int wm = wave >> 1, wn = wave & 1;
    int lr = t >> 2, lc = (t & 3) * 8;
    f32x4 acc[2][2] = {};
    const u16* Ap = A + (size_t)(bm0 + lr) * K + lc;
    const u16* Bp = Bt + (size_t)(bn0 + lr) * K + lc;
    int fr = lane & 15, fk = (lane >> 4) * 8;
    for (int k0 = 0; k0 < K; k0 += 32) {
        *(u16x8*)&As[lr][lc] = *(const u16x8*)(Ap + k0);
        *(u16x8*)&Bs[lr][lc] = *(const u16x8*)(Bp + k0);
        __syncthreads();
        s16x8 a0 = *(const s16x8*)&As[wm * 32 + fr][fk];
        s16x8 a1 = *(const s16x8*)&As[wm * 32 + 16 + fr][fk];
        s16x8 b0 = *(const s16x8*)&Bs[wn * 32 + fr][fk];
        s16x8 b1 = *(const s16x8*)&Bs[wn * 32 + 16 + fr][fk];
        acc[0][0] = __builtin_amdgcn_mfma_f32_16x16x32_bf16(a0, b0, acc[0][0], 0, 0, 0);
        acc[0][1] = __builtin_amdgcn_mfma_f32_16x16x32_bf16(a0, b1, acc[0][1], 0, 0, 0);
        acc[1][0] = __builtin_amdgcn_mfma_f32_16x16x32_bf16(a1, b0, acc[1][0], 0, 0, 0);
        acc[1][1] = __builtin_amdgcn_mfma_f32_16x16x32_bf16(a1, b1, acc[1][1], 0, 0, 0);
        __syncthreads();
    }
    int cIn = lane & 15, r4 = (lane >> 4) * 4;
    #pragma unroll
    for (int i = 0; i < 2; i++)
    #pragma unroll
    for (int j = 0; j < 2; j++) {
        int col = bn0 + wn * 32 + j * 16 + cIn;
        float bv = bias ? bias[col] : 0.f;
        #pragma unroll
        for (int r = 0; r < 4; r++) {
            int rowg = bm0 + wm * 32 + i * 16 + r4 + r;
            float vv = acc[i][j][r] + bv;
            if (ACT == 1) vv = siluf(vv);
            if (OUTBF) ((u16*)C)[(size_t)rowg * N + col] = f2b(vv);
            else       ((float*)C)[(size_t)rowg * N + col] = vv;
        }
    }
}

// ---------------- 64x64 GEMM fused with k_hout epilogue ---------------------
__global__ __launch_bounds__(256) void k_gemm_ff2ho(
    const u16* __restrict__ A, const u16* __restrict__ Bt,
    const float* __restrict__ bias, const float* __restrict__ hmod,
    const float* __restrict__ nt, const float* __restrict__ mask,
    float* __restrict__ out, u16* __restrict__ hout_bf, int M, int N, int K)
{
    __shared__ u16 As[64][40];
    __shared__ u16 Bs[64][40];
    int bn0 = blockIdx.x * 64, bm0 = blockIdx.y * 64;
    int t = threadIdx.x;
    int lane = t & 63, wave = t >> 6;
    int wm = wave >> 1, wn = wave & 1;
    int lr = t >> 2, lc = (t & 3) * 8;
    f32x4 acc[2][2] = {};
    const u16* Ap = A + (size_t)(bm0 + lr) * K + lc;
    const u16* Bp = Bt + (size_t)(bn0 + lr) * K + lc;
    int fr = lane & 15, fk = (lane >> 4) * 8;
    for (int k0 = 0; k0 < K; k0 += 32) {
        *(u16x8*)&As[lr][lc] = *(const u16x8*)(Ap + k0);
        *(u16x8*)&Bs[lr][lc] = *(const u16x8*)(Bp + k0);
        __syncthreads();
        s16x8 a0 = *(const s16x8*)&As[wm * 32 + fr][fk];
        s16x8 a1 = *(const s16x8*)&As[wm * 32 + 16 + fr][fk];
        s16x8 b0 = *(const s16x8*)&Bs[wn * 32 + fr][fk];
        s16x8 b1 = *(const s16x8*)&Bs[wn * 32 + 16 + fr][fk];
        acc[0][0] = __builtin_amdgcn_mfma_f32_16x16x32_bf16(a0, b0, acc[0][0], 0, 0, 0);
        acc[0][1] = __builtin_amdgcn_mfma_f32_16x16x32_bf16(a0, b1, acc[0][1], 0, 0, 0);
        acc[1][0] = __builtin_amdgcn_mfma_f32_16x16x32_bf16(a1, b0, acc[1][0], 0, 0, 0);
        acc[1][1] = __builtin_amdgcn_mfma_f32_16x16x32_bf16(a1, b1, acc[1][1], 0, 0, 0);
        __syncthreads();
    }
    int cIn = lane & 15, r4 = (lane >> 4) * 4;
    #pragma unroll
    for (int i = 0; i < 2; i++)
    #pragma unroll
    for (int j = 0; j < 2; j++) {
        int col = bn0 + wn * 32 + j * 16 + cIn;
        float bv = bias[col];
        #pragma unroll
        for (int r = 0; r < 4; r++) {
            int rowg = bm0 + wm * 32 + i * 16 + r4 + r;
            float x = acc[i][j][r] + bv;
            float v = (hmod[(size_t)rowg * 256 + col]
                     + nt[(size_t)rowg * 1536 + 1280 + col] * x) * mask[rowg];
            out[(size_t)rowg * 256 + col] = v;
            hout_bf[(size_t)rowg * 256 + col] = f2b(v);
        }
    }
}

// ---------------- 64x64 GEMM fused with k_edge_out epilogue -----------------
__global__ __launch_bounds__(256) void k_gemm_ff4eo(
    const u16* __restrict__ A, const u16* __restrict__ Bt,
    const float* __restrict__ bias, const float* __restrict__ hemod,
    const u16* __restrict__ etf,
    float* __restrict__ out2, u16* __restrict__ heout_bf, int M, int N, int K)
{
    __shared__ u16 As[64][40];
    __shared__ u16 Bs[64][40];
    int bn0 = blockIdx.x * 64, bm0 = blockIdx.y * 64;
    int t = threadIdx.x;
    int lane = t & 63, wave = t >> 6;
    int wm = wave >> 1, wn = wave & 1;
    int lr = t >> 2, lc = (t & 3) * 8;
    f32x4 acc[2][2] = {};
    const u16* Ap = A + (size_t)(bm0 + lr) * K + lc;
    const u16* Bp = Bt + (size_t)(bn0 + lr) * K + lc;
    int fr = lane & 15, fk = (lane >> 4) * 8;
    for (int k0 = 0; k0 < K; k0 += 32) {
        *(u16x8*)&As[lr][lc] = *(const u16x8*)(Ap + k0);
        *(u16x8*)&Bs[lr][lc] = *(const u16x8*)(Bp + k0);
        __syncthreads();
        s16x8 a0 = *(const s16x8*)&As[wm * 32 + fr][fk];
        s16x8 a1 = *(const s16x8*)&As[wm * 32 + 16 + fr][fk];
        s16x8 b0 = *(const s16x8*)&Bs[wn * 32 + fr][fk];
        s16x8 b1 = *(const s16x8*)&Bs[wn * 32 + 16 + fr][fk];
        acc[0][0] = __builtin_amdgcn_mfma_f32_16x16x32_bf16(a0, b0, acc[0][0], 0, 0, 0);
        acc[0][1] = __builtin_amdgcn_mfma_f32_16x16x32_bf16(a0, b1, acc[0][1], 0, 0, 0);
        acc[1][0] = __builtin_amdgcn_mfma_f32_16x16x32_bf16(a1, b0, acc[1][0], 0, 0, 0);
        acc[1][1] = __builtin_amdgcn_mfma_f32_16x16x32_bf16(a1, b1, acc[1][1], 0, 0, 0);
        __syncthreads();
    }
    int cIn = lane & 15, r4 = (lane >> 4) * 4;
    #pragma unroll
    for (int i = 0; i < 2; i++)
    #pragma unroll
    for (int j = 0; j < 2; j++) {
        int col = bn0 + wn * 32 + j * 16 + cIn;
        float bv = bias[col];
        #pragma unroll
        for (int r = 0; r < 4; r++) {
            int rowg = bm0 + wm * 32 + i * 16 + r4 + r;
            float x = acc[i][j][r] + bv;
            float v = hemod[(size_t)rowg * 64 + col]
                    + b2f(etf[(size_t)rowg * 896 + 320 + col]) * x;
            out2[(size_t)rowg * 64 + col] = v;
            heout_bf[(size_t)rowg * 64 + col] = f2b(v);
        }
    }
}

// ---------------- 128x128 tile bf16 MFMA GEMM, 3-deep pipelined -------------
template<int ACT, int OUTBF>
__global__ __launch_bounds__(256) void k_gemm128(
    const u16* __restrict__ A, const u16* __restrict__ Bt,
    const float* __restrict__ bias, void* __restrict__ C,
    int M, int N, int K)
{
    __shared__ u16 As[3][128 * 32];
    __shared__ u16 Bs[3][128 * 32];
    const int t = threadIdx.x;
    const int lane = t & 63, wv = t >> 6;
    const int wm = wv >> 1, wn = wv & 1;
    const int nwg = gridDim.x * gridDim.y;
    const int orig = blockIdx.y * gridDim.x + blockIdx.x;
    const int q8 = nwg >> 3, r8 = nwg & 7;
    const int xcd = orig & 7, lin = orig >> 3;
    const int wgid = (xcd < r8 ? xcd * (q8 + 1) : r8 * (q8 + 1) + (xcd - r8) * q8) + lin;
    const int bxs = wgid % gridDim.x, bys = wgid / gridDim.x;
    const int bn0 = bxs * 128, bm0 = bys * 128;
    const int srow = t >> 2;
    const int scol = ((t & 3) ^ ((t >> 3) & 3)) * 8;
    const u16* Ap = A + (size_t)(bm0 + srow) * K + scol;
    const u16* Bp = Bt + (size_t)(bn0 + srow) * K + scol;
    const size_t rstep = (size_t)64 * K;
    const int woff = wv * 16 * 32;
    const int fr = lane & 15;
    const int fkc = (((lane >> 4) ^ ((fr >> 1) & 3)) * 8);
    f32x4 acc[4][4] = {};
    const int NT = K >> 5;

    auto STAGE = [&](int b, int ko) {
        gll16(Ap + ko, &As[b][woff]);
        gll16(Ap + ko + rstep, &As[b][woff + 64 * 32]);
        gll16(Bp + ko, &Bs[b][woff]);
        gll16(Bp + ko + rstep, &Bs[b][woff + 64 * 32]);
    };
    auto COMPUTE = [&](int b) {
        const u16* aBase = &As[b][wm * 64 * 32];
        const u16* bBase = &Bs[b][wn * 64 * 32];
        s16x8 af[4], bfr[4];
        #pragma unroll
        for (int m = 0; m < 4; m++) af[m] = *(const s16x8*)&aBase[(m * 16 + fr) * 32 + fkc];
        #pragma unroll
        for (int n = 0; n < 4; n++) bfr[n] = *(const s16x8*)&bBase[(n * 16 + fr) * 32 + fkc];
        #pragma unroll
        for (int m = 0; m < 4; m++)
        #pragma unroll
        for (int n = 0; n < 4; n++)
            acc[m][n] = __builtin_amdgcn_mfma_f32_16x16x32_bf16(af[m], bfr[n], acc[m][n], 0, 0, 0);
    };

    STAGE(0, 0);
    if (NT > 1) STAGE(1, 32);
    int cur = 0;
    for (int tt = 0; tt < NT; tt++) {
        if (tt + 2 < NT) STAGE((cur + 2) % 3, (tt + 2) * 32);
        __builtin_amdgcn_sched_barrier(0);
        int ahead = NT - 1 - tt; if (ahead > 2) ahead = 2;
        if (ahead == 2)      asm volatile("s_waitcnt vmcnt(8)" ::: "memory");
        else if (ahead == 1) asm volatile("s_waitcnt vmcnt(4)" ::: "memory");
        else                 asm volatile("s_waitcnt vmcnt(0)" ::: "memory");
        __builtin_amdgcn_sched_barrier(0);
        __builtin_amdgcn_s_barrier();
        COMPUTE(cur);
        __builtin_amdgcn_s_barrier();
        __builtin_amdgcn_sched_barrier(0);
        cur = (cur + 1) % 3;
    }

    const int cIn = lane & 15, r4 = (lane >> 4) * 4;
    #pragma unroll
    for (int n = 0; n < 4; n++) {
        int col = bn0 + wn * 64 + n * 16 + cIn;
        float bv = bias ? bias[col] : 0.f;
        #pragma unroll
        for (int m = 0; m < 4; m++) {
            #pragma unroll
            for (int r = 0; r < 4; r++) {
                int rowg = bm0 + wm * 64 + m * 16 + r4 + r;
                float vv = acc[m][n][r] + bv;
                if (ACT == 1) vv = siluf(vv);
                if (OUTBF) ((u16*)C)[(size_t)rowg * N + col] = f2b(vv);
                else       ((float*)C)[(size_t)rowg * N + col] = vv;
            }
        }
    }
}

// ---------------- DUAL 128x128 GEMM: two independent jobs, one dispatch -----
struct GJob {
    const u16* A; const u16* Bt; const float* bias; void* C;
    int M, N, K, gx, nwg, act, outbf;
};

__global__ __launch_bounds__(256) void k_gemm128_dual(GJob ja, GJob jb)
{
    const bool first = (int)blockIdx.x < ja.nwg;
    const GJob J = first ? ja : jb;
    const int orig = first ? blockIdx.x : blockIdx.x - ja.nwg;
    __shared__ u16 As[3][128 * 32];
    __shared__ u16 Bs[3][128 * 32];
    const int t = threadIdx.x;
    const int lane = t & 63, wv = t >> 6;
    const int wm = wv >> 1, wn = wv & 1;
    const int K = J.K;
    const int q8 = J.nwg >> 3, r8 = J.nwg & 7;
    const int xcd = orig & 7, lin = orig >> 3;
    const int wgid = (xcd < r8 ? xcd * (q8 + 1) : r8 * (q8 + 1) + (xcd - r8) * q8) + lin;
    const int bxs = wgid % J.gx, bys = wgid / J.gx;
    const int bn0 = bxs * 128, bm0 = bys * 128;
    const int srow = t >> 2;
    const int scol = ((t & 3) ^ ((t >> 3) & 3)) * 8;
    const u16* Ap = J.A + (size_t)(bm0 + srow) * K + scol;
    const u16* Bp = J.Bt + (size_t)(bn0 + srow) * K + scol;
    const size_t rstep = (size_t)64 * K;
    const int woff = wv * 16 * 32;
    const int fr = lane & 15;
    const int fkc = (((lane >> 4) ^ ((fr >> 1) & 3)) * 8);
    f32x4 acc[4][4] = {};
    const int NT = K >> 5;

    auto STAGE = [&](int b, int ko) {
        gll16(Ap + ko, &As[b][woff]);
        gll16(Ap + ko + rstep, &As[b][woff + 64 * 32]);
        gll16(Bp + ko, &Bs[b][woff]);
        gll16(Bp + ko + rstep, &Bs[b][woff + 64 * 32]);
    };
    auto COMPUTE = [&](int b) {
        const u16* aBase = &As[b][wm * 64 * 32];
        const u16* bBase = &Bs[b][wn * 64 * 32];
        s16x8 af[4], bfr[4];
        #pragma unroll
        for (int m = 0; m < 4; m++) af[m] = *(const s16x8*)&aBase[(m * 16 + fr) * 32 + fkc];
        #pragma unroll
        for (int n = 0; n < 4; n++) bfr[n] = *(const s16x8*)&bBase[(n * 16 + fr) * 32 + fkc];
        #pragma unroll
        for (int m = 0; m < 4; m++)
        #pragma unroll
        for (int n = 0; n < 4; n++)
            acc[m][n] = __builtin_amdgcn_mfma_f32_16x16x32_bf16(af[m], bfr[n], acc[m][n], 0, 0, 0);
    };

    STAGE(0, 0);
    if (NT > 1) STAGE(1, 32);
    int cur = 0;
    for (int tt = 0; tt < NT; tt++) {
        if (tt + 2 < NT) STAGE((cur + 2) % 3, (tt + 2) * 32);
        __builtin_amdgcn_sched_barrier(0);
        int ahead = NT - 1 - tt; if (ahead > 2) ahead = 2;
        if (ahead == 2)      asm volatile("s_waitcnt vmcnt(8)" ::: "memory");
        else if (ahead == 1) asm volatile("s_waitcnt vmcnt(4)" ::: "memory");
        else                 asm volatile("s_waitcnt vmcnt(0)" ::: "memory");
        __builtin_amdgcn_sched_barrier(0);
        __builtin_amdgcn_s_barrier();
        COMPUTE(cur);
        __builtin_amdgcn_s_barrier();
        __builtin_amdgcn_sched_barrier(0);
        cur = (cur + 1) % 3;
    }

    const int cIn = lane & 15, r4 = (lane >> 4) * 4;
    #pragma unroll
    for (int n = 0; n < 4; n++) {
        int col = bn0 + wn * 64 + n * 16 + cIn;
        float bv = J.bias ? J.bias[col] : 0.f;
        #pragma unroll
        for (int m = 0; m < 4; m++) {
            #pragma unroll
            for (int r = 0; r < 4; r++) {
                int rowg = bm0 + wm * 64 + m * 16 + r4 + r;
                float vv = acc[m][n][r] + bv;
                if (J.act) vv = siluf(vv);
                if (J.outbf) ((u16*)J.C)[(size_t)rowg * J.N + col] = f2b(vv);
                else         ((float*)J.C)[(size_t)rowg * J.N + col] = vv;
            }
        }
    }
}

// ---------------- batched weight prep: LDS-tiled transposes + bias copies ---
struct ConvJob { const float* W; u16* Wt; int ldw, k0, n0, K, tile_start, tiles_k; };
struct CopyJob { const float* src; float* dst; int n; };
struct BatchArgs { ConvJob cj[17]; CopyJob cp[5]; int conv_blocks; };

__global__ __launch_bounds__(256) void k_prep(BatchArgs a)
{
    __shared__ float ls[64][65];
    int b = blockIdx.x;
    int t = threadIdx.x;
    if (b < a.conv_blocks) {
        int j = 0;
        #pragma unroll 1
        while (j + 1 < 17 && a.cj[j + 1].tile_start <= b) ++j;
        const ConvJob J = a.cj[j];
        int local = b - J.tile_start;
        int tk = local % J.tiles_k, tn = local / J.tiles_k;
        int k0 = tk * 64, n0 = tn * 64;
        int cn = t & 63, rk = t >> 6;
        #pragma unroll
        for (int p = 0; p < 16; p++) {
            int kk = p * 4 + rk;
            ls[kk][cn] = J.W[(size_t)(J.k0 + k0 + kk) * J.ldw + J.n0 + n0 + cn];
        }
        __syncthreads();
        int ck = t & 63, rn = t >> 6;
        #pragma unroll
        for (int p = 0; p < 16; p++) {
            int nn = p * 4 + rn;
            J.Wt[(size_t)(n0 + nn) * J.K + k0 + ck] = f2b(ls[ck][nn]);
        }
    } else {
        int c = b - a.conv_blocks;
        const CopyJob C = a.cp[c];
        for (int i = t; i < C.n; i += 256) C.dst[i] = C.src[i];
    }
}

// ---------------- combined silu -> bf16 for two arrays (one launch) ---------
__global__ void k_silu2(const float* __restrict__ inA, u16* __restrict__ outA, int n4A,
                        const float* __restrict__ inB, u16* __restrict__ outB, int n4B)
{
    int total = n4A + n4B;
    int stride = gridDim.x * 256;
    for (int i = blockIdx.x * 256 + threadIdx.x; i < total; i += stride) {
        const float* in; u16* out; int idx;
        if (i < n4A) { in = inA; out = outA; idx = i; }
        else         { in = inB; out = outB; idx = i - n4A; }
        f32x4 v = *(const f32x4*)(in + (size_t)idx * 4);
        u16x4 o;
        #pragma unroll
        for (int j = 0; j < 4; j++) o[j] = f2b(siluf(v[j]));
        *(u16x4*)(out + (size_t)idx * 4) = o;
    }
}

// ---------------- edge preprocessing (64 edges per block) -------------------
__global__ __launch_bounds__(256) void k_edge_pre(
    const float* __restrict__ pos, const float* __restrict__ edge_attr,
    const int* __restrict__ ei, const float* __restrict__ W_ee,
    const float* __restrict__ b_ee, const float* __restrict__ coors_scale,
    const u16* __restrict__ etf,
    u16* __restrict__ ea_mod, float* __restrict__ dist, float* __restrict__ cdiff)
{
    __shared__ float Ws[65][64];
    int t = threadIdx.x;
    for (int i = t; i < 65 * 64; i += 256) Ws[i >> 6][i & 63] = W_ee[i];
    __syncthreads();
    int l = t & 63;
    float bee = b_ee[l];
    float cscale = coors_scale[0];
    for (int g = 0; g < 16; g++) {
        int e = blockIdx.x * 64 + g * 4 + (t >> 6);
        int row = ei[e], col = ei[E_CNT + e];
        float d0 = pos[row * 3 + 0] - pos[col * 3 + 0];
        float d1 = pos[row * 3 + 1] - pos[col * 3 + 1];
        float d2 = pos[row * 3 + 2] - pos[col * 3 + 2];
        float ssq = d0 * d0 + d1 * d1 + d2 * d2;
        float dst = sqrtf(ssq + 1e-12f);
        float nrm = sqrtf(ssq);
        float cs = cscale / fmaxf(nrm, 1e-8f);
        if (l == 0) {
            dist[e] = dst;
            cdiff[e * 3 + 0] = d0 * cs; cdiff[e * 3 + 1] = d1 * cs; cdiff[e * 3 + 2] = d2 * cs;
        }
        float attr = edge_attr[(size_t)e * 64 + l];
        float acc = dst * Ws[0][l];
        for (int f = 0; f < 64; f++) acc += __shfl(attr, f) * Ws[1 + f][l];
        acc += bee;
        float y = wave_ln64(acc);
        const u16* ep = etf + (size_t)e * 896;
        float m = y * (1.f + b2f(ep[64 + l])) + b2f(ep[l]);
        ea_mod[(size_t)e * 64 + l] = f2b(m);
    }
}

// ---------------- node: hh = modulate(ln(h), sh_msa, sc_msa) -> bf16 --------
__global__ __launch_bounds__(256) void k_node_hh(
    const float* __restrict__ h, const float* __restrict__ nt, u16* __restrict__ hh)
{
    int n = blockIdx.x, c = threadIdx.x;
    float x = h[(size_t)n * 256 + c];
    float y = block_ln256(x);
    float m = y * (1.f + nt[(size_t)n * 1536 + 256 + c]) + nt[(size_t)n * 1536 + c];
    hh[(size_t)n * 256 + c] = f2b(m);
}

// ---------------- fused per-node: alpha + softmax + aggregation -------------
__global__ __launch_bounds__(256) void k_agg(
    const float* __restrict__ qkv, const u16* __restrict__ e01,
    float* __restrict__ hnode, u16* __restrict__ hnode_bf)
{
    int n = blockIdx.x;
    int b = n / 48, i = n % 48;
    int t = threadIdx.x;
    __shared__ float qs[8][33];
    __shared__ float att[47][8];
    __shared__ float mxs[8], dens[8];
    __shared__ int elist[47], slist[47];
    qs[t >> 5][t & 31] = qkv[(size_t)n * 768 + t];
    if (t < 47) {
        int s = t + (t >= i ? 1 : 0);
        slist[t] = s;
        elist[t] = b * EPG + s * 47 + (i < s ? i : i - 1);
    }
    __syncthreads();
    for (int idx = t; idx < 376; idx += 256) {
        int j = idx >> 3, hh = idx & 7;
        int src = b * 48 + slist[j];
        int e = elist[j];
        const float* kp = qkv + (size_t)src * 768 + 256 + hh * 32;
        const u16* ep = e01 + (size_t)e * 512 + hh * 32;
        float p = 0.f;
        #pragma unroll
        for (int d = 0; d < 32; d++) p += qs[hh][d] * kp[d] * b2f(ep[d]);
        att[j][hh] = p * 0.17677669529663687f; // 1/sqrt(32)
    }
    __syncthreads();
    if (t < 8) {
        float m = -1e30f;
        for (int j = 0; j < 47; j++) m = fmaxf(m, att[j][t]);
        float den = 0.f;
        for (int j = 0; j < 47; j++) den += expf(att[j][t] - m);
        mxs[t] = m; dens[t] = den + 1e-16f;
    }
    __syncthreads();
    for (int idx = t; idx < 376; idx += 256) {
        int j = idx >> 3, hh = idx & 7;
        att[j][hh] = expf(att[j][hh] - mxs[hh]) / dens[hh];
    }
    __syncthreads();
    int c = t, hh = t >> 5;
    float acc = 0.f;
    for (int j = 0; j < 47; j++) {
        int src = b * 48 + slist[j];
        int e = elist[j];
        acc += att[j][hh] * qkv[(size_t)src * 768 + 512 + c] * b2f(e01[(size_t)e * 512 + 256 + c]);
    }
    hnode[(size_t)n * 256 + c] = acc;
    hnode_bf[(size_t)n * 256 + c] = f2b(acc);
}

// ---------------- node: residual + LN + modulate(mlp) * mask ----------------
__global__ __launch_bounds__(256) void k_node_mod(
    const float* __restrict__ h, const float* __restrict__ hnode_raw,
    const float* __restrict__ nt, const float* __restrict__ mask,
    float* __restrict__ hmod, u16* __restrict__ hmod_bf)
{
    int n = blockIdx.x, c = threadIdx.x;
    float x = h[(size_t)n * 256 + c] + nt[(size_t)n * 1536 + 512 + c] * hnode_raw[(size_t)n * 256 + c];
    float y = block_ln256(x);
    float m = (y * (1.f + nt[(size_t)n * 1536 + 1024 + c]) + nt[(size_t)n * 1536 + 768 + c]) * mask[n];
    hmod[(size_t)n * 256 + c] = m;
    hmod_bf[(size_t)n * 256 + c] = f2b(m);
}

// ---------------- edge: h_e = edge_attr + g*h_edge; LN; modulate (x4) -------
__global__ __launch_bounds__(256) void k_edge_mod(
    const float* __restrict__ Q1, const float* __restrict__ b_n2e,
    const float* __restrict__ edge_attr, const int* __restrict__ ei,
    const u16* __restrict__ etf, float* __restrict__ hemod, u16* __restrict__ hemod_bf)
{
    int l = threadIdx.x & 63;
    float bn2e = b_n2e[l];
    for (int g = 0; g < 4; g++) {
        int e = blockIdx.x * 16 + g * 4 + (threadIdx.x >> 6);
        int row = ei[e], col = ei[E_CNT + e];
        float hedge = Q1[(size_t)row * 64 + l] + Q1[(size_t)col * 64 + l] + bn2e;
        const u16* ep = etf + (size_t)e * 896;
        float x = edge_attr[(size_t)e * 64 + l] + b2f(ep[128 + l]) * hedge;
        float y = wave_ln64(x);
        float m = y * (1.f + b2f(ep[256 + l])) + b2f(ep[192 + l]);
        hemod[(size_t)e * 64 + l] = m;
        hemod_bf[(size_t)e * 64 + l] = f2b(m);
    }
}

// ---------------- CondEquiUpdate inv_pre: wave-per-edge, vectorized ---------
// 4 edges/block; lane l owns channels c = l*4..l*4+3; LN over 256 via
// wave shfl reduction (no barriers).
__global__ __launch_bounds__(256) void k_inv_pre4(
    const float* __restrict__ p12,
    const u16* __restrict__ P3, const float* __restrict__ dist,
    const float* __restrict__ W_ui, const float* __restrict__ b_ui,
    const int* __restrict__ ei, const u16* __restrict__ etf, u16* __restrict__ invmod)
{
    int e = blockIdx.x * 4 + (threadIdx.x >> 6);
    int l = threadIdx.x & 63;
    int c = l * 4;
    int row = ei[e], col = ei[E_CNT + e];
    f32x4 pa = *(const f32x4*)(p12 + (size_t)row * 512 + c);
    f32x4 pb = *(const f32x4*)(p12 + (size_t)col * 512 + 256 + c);
    u16x4 p3 = *(const u16x4*)(P3 + (size_t)e * 256 + c);
    f32x4 wui = *(const f32x4*)(W_ui + 576 * 256 + c);
    f32x4 bui = *(const f32x4*)(b_ui + c);
    float dd = dist[e];
    float x[4];
    float s = 0.f;
    #pragma unroll
    for (int j = 0; j < 4; j++) {
        x[j] = pa[j] + pb[j] + b2f(p3[j]) + dd * wui[j] + bui[j];
        s += x[j];
    }
    #pragma unroll
    for (int off = 1; off < 64; off <<= 1) s += __shfl_xor(s, off);
    float mean = s * (1.f / 256.f);
    float v2 = 0.f;
    #pragma unroll
    for (int j = 0; j < 4; j++) {
        float d = x[j] - mean;
        v2 += d * d;
    }
    #pragma unroll
    for (int off = 1; off < 64; off <<= 1) v2 += __shfl_xor(v2, off);
    float rs = rsqrtf(v2 * (1.f / 256.f) + 1e-6f);
    const u16* ep = etf + (size_t)e * 896;
    u16x4 sc = *(const u16x4*)(ep + 640 + c);
    u16x4 sh = *(const u16x4*)(ep + 384 + c);
    u16x4 o;
    #pragma unroll
    for (int j = 0; j < 4; j++) {
        float y = (x[j] - mean) * rs;
        o[j] = f2b(y * (1.f + b2f(sc[j])) + b2f(sh[j]));
    }
    *(u16x4*)(invmod + (size_t)e * 256 + c) = o;
}

// ---------------- final per-edge scalar: tanh( silu(y) . W_uc2 )  (x4) ------
__global__ __launch_bounds__(256) void k_inv(const u16* __restrict__ uc1,
                                             const float* __restrict__ W_uc2,
                                             float* __restrict__ inv)
{
    int l = threadIdx.x & 63;
    const float* w = W_uc2 + l * 4;
    float w0 = w[0], w1 = w[1], w2 = w[2], w3 = w[3];
    for (int g = 0; g < 4; g++) {
        int e = blockIdx.x * 16 + g * 4 + (threadIdx.x >> 6);
        u16x4 v = *(const u16x4*)(uc1 + (size_t)e * 256 + l * 4);
        float s = b2f(v[0]) * w0 + b2f(v[1]) * w1 + b2f(v[2]) * w2 + b2f(v[3]) * w3;
        #pragma unroll
        for (int off = 1; off < 64; off <<= 1) s += __shfl_xor(s, off);
        if (l == 0) inv[e] = tanhf(s);
    }
}

// ---------------- pos update: deterministic contiguous segment sum ----------
__global__ void k_pos(const float* __restrict__ pos, const float* __restrict__ cdiff,
                      const float* __restrict__ inv, float* __restrict__ out3)
{
    int n = blockIdx.x * 256 + threadIdx.x;
    if (n >= BN_CNT) return;
    int b = n / 48, s = n % 48;
    int e0 = b * EPG + s * 47;
    float a0 = 0.f, a1 = 0.f, a2 = 0.f;
    for (int j = 0; j < 47; j++) {
        float f = inv[e0 + j];
        a0 += cdiff[(size_t)(e0 + j) * 3 + 0] * f;
        a1 += cdiff[(size_t)(e0 + j) * 3 + 1] * f;
        a2 += cdiff[(size_t)(e0 + j) * 3 + 2] * f;
    }
    out3[n * 3 + 0] = pos[n * 3 + 0] + a0;
    out3[n * 3 + 1] = pos[n * 3 + 1] + a1;
    out3[n * 3 + 2] = pos[n * 3 + 2] + a2;
}

extern "C" void kernel_launch(void* const* d_in, const int* in_sizes, int n_in,
                              void* d_out, int out_size, void* d_ws, size_t ws_size,
                              hipStream_t stream)
{
    (void)in_sizes; (void)n_in; (void)out_size; (void)ws_size;
    const float* pos       = (const float*)d_in[0];
    const float* h         = (const float*)d_in[1];
    const float* edge_attr = (const float*)d_in[2];
    const float* node_mask = (const float*)d_in[3];
    const float* nte       = (const float*)d_in[4];
    const float* ete       = (const float*)d_in[5];
    const int*   ei        = (const int*)d_in[6];
    const float* W_ee = (const float*)d_in[7];  const float* b_ee = (const float*)d_in[8];
    const float* W_nt = (const float*)d_in[9];  const float* b_nt = (const float*)d_in[10];
    const float* W_et = (const float*)d_in[11]; const float* b_et = (const float*)d_in[12];
    const float* Wq  = (const float*)d_in[13];  const float* bq  = (const float*)d_in[14];
    const float* Wk  = (const float*)d_in[15];  const float* bk  = (const float*)d_in[16];
    const float* Wv  = (const float*)d_in[17];  const float* bv  = (const float*)d_in[18];
    const float* We0 = (const float*)d_in[19];  const float* We1 = (const float*)d_in[20];
    const float* W_n2e = (const float*)d_in[21]; const float* b_n2e = (const float*)d_in[22];
    const float* W_ff1 = (const float*)d_in[23]; const float* b_ff1 = (const float*)d_in[24];
    const float* W_ff2 = (const float*)d_in[25]; const float* b_ff2 = (const float*)d_in[26];
    const float* W_ff3 = (const float*)d_in[27]; const float* b_ff3 = (const float*)d_in[28];
    const float* W_ff4 = (const float*)d_in[29]; const float* b_ff4 = (const float*)d_in[30];
    const float* coors_scale = (const float*)d_in[31];
    const float* W_ut = (const float*)d_in[32]; const float* b_ut = (const float*)d_in[33];
    const float* W_ui = (const float*)d_in[34]; const float* b_ui = (const float*)d_in[35];
    const float* W_uc1 = (const float*)d_in[36]; const float* b_uc1 = (const float*)d_in[37];
    const float* W_uc2 = (const float*)d_in[38];

    const size_t E = E_CNT;
    char* ws = (char*)d_ws;
    size_t off = 0;
    auto AL = [&](size_t b) { size_t o = off; off += (b + 255) & ~(size_t)255; return o; };

    // weights (bf16, transposed [N,K])
    size_t o_wtcat  = AL(896 * 1024 * 2);
    size_t o_wtnt   = AL(1536 * 1024 * 2);
    size_t o_wtqkv  = AL(768 * 256 * 2);
    size_t o_wte01  = AL(512 * 64 * 2);
    size_t o_wtn2e  = AL(64 * 256 * 2);
    size_t o_wtff1  = AL(512 * 256 * 2), o_wtff2 = AL(256 * 512 * 2);
    size_t o_wtff3  = AL(128 * 64 * 2),  o_wtff4 = AL(64 * 128 * 2);
    size_t o_wtuiab = AL(512 * 256 * 2);
    size_t o_wtuic  = AL(256 * 64 * 2),  o_wtuc1 = AL(256 * 256 * 2);
    size_t o_bias896 = AL(896 * 4);
    size_t o_bias768 = AL(768 * 4);
    // big regions (lifetime-based aliasing)
    size_t o_reg1 = AL(E * 1024 * 2);          // ete_silu -> later P3/invmod/uc1o
    size_t o_etf  = AL(E * 896 * 2);           // persistent
    size_t o_ntes = AL(1536 * 1024 * 2);
    size_t o_ntf  = AL((size_t)1536 * 1536 * 4);
    size_t o_eamod = AL(E * 64 * 2);
    size_t o_dist = AL(E * 4), o_cdiff = AL(E * 12);
    size_t o_qkv  = AL(1536 * 768 * 4);
    size_t o_reg3 = AL(E * 512 * 2);           // e01 -> later ffem/heoutbf
    size_t o_hnode = AL(1536 * 256 * 4), o_hnodebf = AL(1536 * 256 * 2);
    size_t o_q1 = AL(1536 * 64 * 4);
    size_t o_hh = AL(1536 * 256 * 2);
    size_t o_hmod = AL(1536 * 256 * 4), o_hmodbf = AL(1536 * 256 * 2);
    size_t o_ff1 = AL(1536 * 512 * 2);
    size_t o_houtbf = AL(1536 * 256 * 2);
    size_t o_hemod = AL(E * 64 * 4), o_hemodbf = AL(E * 64 * 2);
    size_t o_p12 = AL(1536 * 512 * 4);
    size_t o_inv = AL(E * 4);
    // aliases
    size_t o_etes = o_reg1;
    size_t o_p3 = o_reg1;
    size_t o_invmod = o_reg1 + E * 256 * 2;
    size_t o_uc1o = o_reg1 + E * 256 * 4;
    size_t o_e01 = o_reg3;
    size_t o_ffem = o_reg3;
    size_t o_heoutbf = o_reg3 + E * 128 * 2 + E * 64 * 4;

    #define WSU(o) ((u16*)(ws + (o)))
    #define WSF(o) ((float*)(ws + (o)))

    // --- batched weight prep (17 tiled transposes + 5 bias copies) ---
    {
        BatchArgs a;
        int s = 0; int j = 0;
        auto add = [&](const float* W, u16* Wt, int ldw, int k0, int n0, int K, int NC) {
            a.cj[j++] = ConvJob{W, Wt, ldw, k0, n0, K, s, K / 64};
            s += (K / 64) * (NC / 64);
        };
        add(W_et, WSU(o_wtcat), 384, 0, 0, 1024, 384);
        add(W_ut, WSU(o_wtcat) + (size_t)384 * 1024, 512, 0, 0, 1024, 512);
        add(W_nt, WSU(o_wtnt), 1536, 0, 0, 1024, 1536);
        add(Wq, WSU(o_wtqkv), 256, 0, 0, 256, 256);
        add(Wk, WSU(o_wtqkv) + (size_t)256 * 256, 256, 0, 0, 256, 256);
        add(Wv, WSU(o_wtqkv) + (size_t)512 * 256, 256, 0, 0, 256, 256);
        add(We0, WSU(o_wte01), 256, 0, 0, 64, 256);
        add(We1, WSU(o_wte01) + (size_t)256 * 64, 256, 0, 0, 64, 256);
        add(W_n2e, WSU(o_wtn2e), 64, 0, 0, 256, 64);
        add(W_ff1, WSU(o_wtff1), 512, 0, 0, 256, 512);
        add(W_ff2, WSU(o_wtff2), 256, 0, 0, 512, 256);
        add(W_ff3, WSU(o_wtff3), 128, 0, 0, 64, 128);
        add(W_ff4, WSU(o_wtff4), 64, 0, 0, 128, 64);
        add(W_ui, WSU(o_wtuiab), 256, 0, 0, 256, 256);
        add(W_ui, WSU(o_wtuiab) + (size_t)256 * 256, 256, 256, 0, 256, 256);
        add(W_ui, WSU(o_wtuic), 256, 512, 0, 64, 256);
        add(W_uc1, WSU(o_wtuc1), 256, 0, 0, 256, 256);
        a.conv_blocks = s;  // 788 tiles
        a.cp[0] = CopyJob{b_et, WSF(o_bias896), 384};
        a.cp[1] = CopyJob{b_ut, WSF(o_bias896) + 384, 512};
        a.cp[2] = CopyJob{bq, WSF(o_bias768), 256};
        a.cp[3] = CopyJob{bk, WSF(o_bias768) + 256, 256};
        a.cp[4] = CopyJob{bv, WSF(o_bias768) + 512, 256};
        k_prep<<<s + 5, 256, 0, stream>>>(a);
    }

    // --- silu -> bf16 (both time embeddings, one launch) ---
    k_silu2<<<2048, 256, 0, stream>>>(ete, WSU(o_etes), (int)(E * 1024 / 4),
                                      nte, WSU(o_ntes), 1536 * 1024 / 4);

    // --- big time-embedding GEMMs: et || nt in ONE dispatch ---
    {
        GJob ja{WSU(o_etes), WSU(o_wtcat), WSF(o_bias896), WSU(o_etf),
                E_CNT, 896, 1024, 7, 3948, 0, 1};
        GJob jb{WSU(o_ntes), WSU(o_wtnt), b_nt, WSF(o_ntf),
                1536, 1536, 1024, 12, 144, 0, 0};
        k_gemm128_dual<<<3948 + 144, 256, 0, stream>>>(ja, jb);
    }

    // --- edge/node preprocess ---
    k_edge_pre<<<1128, 256, 0, stream>>>(pos, edge_attr, ei, W_ee, b_ee, coors_scale,
                                         WSU(o_etf), WSU(o_eamod), WSF(o_dist), WSF(o_cdiff));
    k_node_hh<<<1536, 256, 0, stream>>>(h, WSF(o_ntf), WSU(o_hh));

    // --- attention inputs: e01 || qkv in ONE dispatch ---
    {
        GJob ja{WSU(o_eamod), WSU(o_wte01), nullptr, WSU(o_e01),
                E_CNT, 512, 64, 4, 2256, 0, 1};
        GJob jb{WSU(o_hh), WSU(o_wtqkv), WSF(o_bias768), WSF(o_qkv),
                1536, 768, 256, 6, 72, 0, 0};
        k_gemm128_dual<<<2256 + 72, 256, 0, stream>>>(ja, jb);
    }
    k_agg<<<1536, 256, 0, stream>>>(WSF(o_qkv), WSU(o_e01), WSF(o_hnode), WSU(o_hnodebf));

    // --- Q1 = h_node_raw @ W_n2e ---
    k_gemm<0, 0><<<dim3(1, 24), 256, 0, stream>>>(WSU(o_hnodebf), WSU(o_wtn2e), nullptr, WSF(o_q1), 1536, 64, 256);

    // --- mod kernels (both FFN inputs ready before the dual) ---
    k_node_mod<<<1536, 256, 0, stream>>>(h, WSF(o_hnode), WSF(o_ntf), node_mask, WSF(o_hmod), WSU(o_hmodbf));
    k_edge_mod<<<4512, 256, 0, stream>>>(WSF(o_q1), b_n2e, edge_attr, ei, WSU(o_etf), WSF(o_hemod), WSU(o_hemodbf));

    // --- FFN stage 1: ff3 || ff1 in ONE dispatch ---
    {
        GJob ja{WSU(o_hemodbf), WSU(o_wtff3), b_ff3, WSU(o_ffem),
                E_CNT, 128, 64, 1, 564, 1, 1};
        GJob jb{WSU(o_hmodbf), WSU(o_wtff1), b_ff1, WSU(o_ff1),
                1536, 512, 256, 4, 48, 1, 1};
        k_gemm128_dual<<<564 + 48, 256, 0, stream>>>(ja, jb);
    }

    // --- FFN stage 2 with fused output epilogues ---
    k_gemm_ff2ho<<<dim3(4, 24), 256, 0, stream>>>(WSU(o_ff1), WSU(o_wtff2), b_ff2,
                                                  WSF(o_hmod), WSF(o_ntf), node_mask,
                                                  (float*)d_out, WSU(o_houtbf), 1536, 256, 512);
    k_gemm_ff4eo<<<dim3(1, 1128), 256, 0, stream>>>(WSU(o_ffem), WSU(o_wtff4), b_ff4,
                                                    WSF(o_hemod), WSU(o_etf),
                                                    (float*)d_out + 393216, WSU(o_heoutbf), E_CNT, 64, 128);

    // --- CondEquiUpdate: p3 || p12 in ONE dispatch ---
    {
        GJob ja{WSU(o_heoutbf), WSU(o_wtuic), nullptr, WSU(o_p3),
                E_CNT, 256, 64, 2, 1128, 0, 1};
        GJob jb{WSU(o_houtbf), WSU(o_wtuiab), nullptr, WSF(o_p12),
                1536, 512, 256, 4, 48, 0, 0};
        k_gemm128_dual<<<1128 + 48, 256, 0, stream>>>(ja, jb);
    }
    k_inv_pre4<<<18048, 256, 0, stream>>>(WSF(o_p12), WSU(o_p3), WSF(o_dist),
                                          W_ui, b_ui, ei, WSU(o_etf), WSU(o_invmod));
    k_gemm128<1, 1><<<dim3(2, 564), 256, 0, stream>>>(WSU(o_invmod), WSU(o_wtuc1), b_uc1, WSU(o_uc1o), E_CNT, 256, 256);
    k_inv<<<4512, 256, 0, stream>>>(WSU(o_uc1o), W_uc2, WSF(o_inv));
    k_pos<<<6, 256, 0, stream>>>(pos, WSF(o_cdiff), WSF(o_inv), (float*)d_out + 393216 + E_CNT * 64);

    #undef WSU
    #undef WSF
}

// Round 17
// 675.168 us; speedup vs baseline: 1.4121x; 1.0211x over previous
//
#include <hip/hip_runtime.h>

typedef unsigned short u16;
typedef __attribute__((ext_vector_type(4))) u16 u16x4;
typedef __attribute__((ext_vector_type(8))) u16 u16x8;
typedef __attribute__((ext_vector_type(8))) short s16x8;
typedef __attribute__((ext_vector_type(4))) float f32x4;

#define E_CNT 72192
#define BN_CNT 1536
// edges per graph = 48*47
#define EPG 2256

__device__ __forceinline__ float b2f(u16 u) {
    union { unsigned int i; float f; } x; x.i = ((unsigned int)u) << 16; return x.f;
}
__device__ __forceinline__ u16 f2b(float f) {
    union { float f; unsigned int i; } x; x.f = f;
    unsigned int r = x.i + 0x7fffu + ((x.i >> 16) & 1u);
    return (u16)(r >> 16);
}
__device__ __forceinline__ float siluf(float x) { return x / (1.f + expf(-x)); }

// async global->LDS, 16B per lane (linear dest). (guide §5 / m97)
__device__ __forceinline__ void gll16(const void* g, void* l) {
    __builtin_amdgcn_global_load_lds(
        (const __attribute__((address_space(1))) void*)g,
        (__attribute__((address_space(3))) void*)l, 16, 0, 0);
}

// ---------------- wave (64-lane) LayerNorm, eps 1e-6, no affine -------------
__device__ __forceinline__ float wave_ln64(float x) {
    float s = x;
    #pragma unroll
    for (int off = 1; off < 64; off <<= 1) s += __shfl_xor(s, off);
    float mean = s * 0.015625f;
    float d = x - mean;
    float v2 = d * d;
    #pragma unroll
    for (int off = 1; off < 64; off <<= 1) v2 += __shfl_xor(v2, off);
    return d * rsqrtf(v2 * 0.015625f + 1e-6f);
}

// ---------------- block(256)-wide LayerNorm over 256 dims -------------------
__device__ __forceinline__ float block_ln256(float x) {
    __shared__ float tmp[4];
    int t = threadIdx.x;
    float s = x;
    #pragma unroll
    for (int off = 1; off < 64; off <<= 1) s += __shfl_xor(s, off);
    if ((t & 63) == 0) tmp[t >> 6] = s;
    __syncthreads();
    float mean = (tmp[0] + tmp[1] + tmp[2] + tmp[3]) * (1.f / 256.f);
    float d = x - mean;
    float v2 = d * d;
    #pragma unroll
    for (int off = 1; off < 64; off <<= 1) v2 += __shfl_xor(v2, off);
    __syncthreads();
    if ((t & 63) == 0) tmp[t >> 6] = v2;
    __syncthreads();
    float var = (tmp[0] + tmp[1] + tmp[2] + tmp[3]) * (1.f / 256.f);
    return d * rsqrtf(var + 1e-6f);
}

// ---------------- generic bf16 MFMA GEMM, 64x64 tile ------------------------
template<int ACT, int OUTBF>
__global__ __launch_bounds__(256) void k_gemm(
    const u16* __restrict__ A, const u16* __restrict__ Bt,
    const float* __restrict__ bias, void* __restrict__ C,
    int M, int N, int K)
{
    __shared__ u16 As[64][40];
    __shared__ u16 Bs[64][40];
    int bn0 = blockIdx.x * 64, bm0 = blockIdx.y * 64;
    int t = threadIdx.x;
    int lane = t & 63, wave = t >> 6;
    int wm = wave >> 1, wn = wave & 1;
    int lr = t >> 2, lc = (t & 3) * 8;
    f32x4 acc[2][2] = {};
    const u16* Ap = A + (size_t)(bm0 + lr) * K + lc;
    const u16* Bp = Bt + (size_t)(bn0 + lr) * K + lc;
    int fr = lane & 15, fk = (lane >> 4) * 8;
    for (int k0 = 0; k0 < K; k0 += 32) {
        *(u16x8*)&As[lr][lc] = *(const u16x8*)(Ap + k0);
        *(u16x8*)&Bs[lr][lc] = *(const u16x8*)(Bp + k0);
        __syncthreads();
        s16x8 a0 = *(const s16x8*)&As[wm * 32 + fr][fk];
        s16x8 a1 = *(const s16x8*)&As[wm * 32 + 16 + fr][fk];
        s16x8 b0 = *(const s16x8*)&Bs[wn * 32 + fr][fk];
        s16x8 b1 = *(const s16x8*)&Bs[wn * 32 + 16 + fr][fk];
        acc[0][0] = __builtin_amdgcn_mfma_f32_16x16x32_bf16(a0, b0, acc[0][0], 0, 0, 0);
        acc[0][1] = __builtin_amdgcn_mfma_f32_16x16x32_bf16(a0, b1, acc[0][1], 0, 0, 0);
        acc[1][0] = __builtin_amdgcn_mfma_f32_16x16x32_bf16(a1, b0, acc[1][0], 0, 0, 0);
        acc[1][1] = __builtin_amdgcn_mfma_f32_16x16x32_bf16(a1, b1, acc[1][1], 0, 0, 0);
        __syncthreads();
    }
    int cIn = lane & 15, r4 = (lane >> 4) * 4;
    #pragma unroll
    for (int i = 0; i < 2; i++)
    #pragma unroll
    for (int j = 0; j < 2; j++) {
        int col = bn0 + wn * 32 + j * 16 + cIn;
        float bv = bias ? bias[col] : 0.f;
        #pragma unroll
        for (int r = 0; r < 4; r++) {
            int rowg = bm0 + wm * 32 + i * 16 + r4 + r;
            float vv = acc[i][j][r] + bv;
            if (ACT == 1) vv = siluf(vv);
            if (OUTBF) ((u16*)C)[(size_t)rowg * N + col] = f2b(vv);
            else       ((float*)C)[(size_t)rowg * N + col] = vv;
        }
    }
}

// ---------------- 64x64 GEMM fused with k_hout epilogue ---------------------
__global__ __launch_bounds__(256) void k_gemm_ff2ho(
    const u16* __restrict__ A, const u16* __restrict__ Bt,
    const float* __restrict__ bias, const float* __restrict__ hmod,
    const float* __restrict__ nt, const float* __restrict__ mask,
    float* __restrict__ out, u16* __restrict__ hout_bf, int M, int N, int K)
{
    __shared__ u16 As[64][40];
    __shared__ u16 Bs[64][40];
    int bn0 = blockIdx.x * 64, bm0 = blockIdx.y * 64;
    int t = threadIdx.x;
    int lane = t & 63, wave = t >> 6;
    int wm = wave >> 1, wn = wave & 1;
    int lr = t >> 2, lc = (t & 3) * 8;
    f32x4 acc[2][2] = {};
    const u16* Ap = A + (size_t)(bm0 + lr) * K + lc;
    const u16* Bp = Bt + (size_t)(bn0 + lr) * K + lc;
    int fr = lane & 15, fk = (lane >> 4) * 8;
    for (int k0 = 0; k0 < K; k0 += 32) {
        *(u16x8*)&As[lr][lc] = *(const u16x8*)(Ap + k0);
        *(u16x8*)&Bs[lr][lc] = *(const u16x8*)(Bp + k0);
        __syncthreads();
        s16x8 a0 = *(const s16x8*)&As[wm * 32 + fr][fk];
        s16x8 a1 = *(const s16x8*)&As[wm * 32 + 16 + fr][fk];
        s16x8 b0 = *(const s16x8*)&Bs[wn * 32 + fr][fk];
        s16x8 b1 = *(const s16x8*)&Bs[wn * 32 + 16 + fr][fk];
        acc[0][0] = __builtin_amdgcn_mfma_f32_16x16x32_bf16(a0, b0, acc[0][0], 0, 0, 0);
        acc[0][1] = __builtin_amdgcn_mfma_f32_16x16x32_bf16(a0, b1, acc[0][1], 0, 0, 0);
        acc[1][0] = __builtin_amdgcn_mfma_f32_16x16x32_bf16(a1, b0, acc[1][0], 0, 0, 0);
        acc[1][1] = __builtin_amdgcn_mfma_f32_16x16x32_bf16(a1, b1, acc[1][1], 0, 0, 0);
        __syncthreads();
    }
    int cIn = lane & 15, r4 = (lane >> 4) * 4;
    #pragma unroll
    for (int i = 0; i < 2; i++)
    #pragma unroll
    for (int j = 0; j < 2; j++) {
        int col = bn0 + wn * 32 + j * 16 + cIn;
        float bv = bias[col];
        #pragma unroll
        for (int r = 0; r < 4; r++) {
            int rowg = bm0 + wm * 32 + i * 16 + r4 + r;
            float x = acc[i][j][r] + bv;
            float v = (hmod[(size_t)rowg * 256 + col]
                     + nt[(size_t)rowg * 1536 + 1280 + col] * x) * mask[rowg];
            out[(size_t)rowg * 256 + col] = v;
            hout_bf[(size_t)rowg * 256 + col] = f2b(v);
        }
    }
}

// ---------------- 64x64 GEMM fused with k_edge_out epilogue -----------------
__global__ __launch_bounds__(256) void k_gemm_ff4eo(
    const u16* __restrict__ A, const u16* __restrict__ Bt,
    const float* __restrict__ bias, const float* __restrict__ hemod,
    const u16* __restrict__ etf,
    float* __restrict__ out2, u16* __restrict__ heout_bf, int M, int N, int K)
{
    __shared__ u16 As[64][40];
    __shared__ u16 Bs[64][40];
    int bn0 = blockIdx.x * 64, bm0 = blockIdx.y * 64;
    int t = threadIdx.x;
    int lane = t & 63, wave = t >> 6;
    int wm = wave >> 1, wn = wave & 1;
    int lr = t >> 2, lc = (t & 3) * 8;
    f32x4 acc[2][2] = {};
    const u16* Ap = A + (size_t)(bm0 + lr) * K + lc;
    const u16* Bp = Bt + (size_t)(bn0 + lr) * K + lc;
    int fr = lane & 15, fk = (lane >> 4) * 8;
    for (int k0 = 0; k0 < K; k0 += 32) {
        *(u16x8*)&As[lr][lc] = *(const u16x8*)(Ap + k0);
        *(u16x8*)&Bs[lr][lc] = *(const u16x8*)(Bp + k0);
        __syncthreads();
        s16x8 a0 = *(const s16x8*)&As[wm * 32 + fr][fk];
        s16x8 a1 = *(const s16x8*)&As[wm * 32 + 16 + fr][fk];
        s16x8 b0 = *(const s16x8*)&Bs[wn * 32 + fr][fk];
        s16x8 b1 = *(const s16x8*)&Bs[wn * 32 + 16 + fr][fk];
        acc[0][0] = __builtin_amdgcn_mfma_f32_16x16x32_bf16(a0, b0, acc[0][0], 0, 0, 0);
        acc[0][1] = __builtin_amdgcn_mfma_f32_16x16x32_bf16(a0, b1, acc[0][1], 0, 0, 0);
        acc[1][0] = __builtin_amdgcn_mfma_f32_16x16x32_bf16(a1, b0, acc[1][0], 0, 0, 0);
        acc[1][1] = __builtin_amdgcn_mfma_f32_16x16x32_bf16(a1, b1, acc[1][1], 0, 0, 0);
        __syncthreads();
    }
    int cIn = lane & 15, r4 = (lane >> 4) * 4;
    #pragma unroll
    for (int i = 0; i < 2; i++)
    #pragma unroll
    for (int j = 0; j < 2; j++) {
        int col = bn0 + wn * 32 + j * 16 + cIn;
        float bv = bias[col];
        #pragma unroll
        for (int r = 0; r < 4; r++) {
            int rowg = bm0 + wm * 32 + i * 16 + r4 + r;
            float x = acc[i][j][r] + bv;
            float v = hemod[(size_t)rowg * 64 + col]
                    + b2f(etf[(size_t)rowg * 896 + 320 + col]) * x;
            out2[(size_t)rowg * 64 + col] = v;
            heout_bf[(size_t)rowg * 64 + col] = f2b(v);
        }
    }
}

// ---------------- 128x128 tile bf16 MFMA GEMM, 3-deep pipelined -------------
template<int ACT, int OUTBF>
__global__ __launch_bounds__(256) void k_gemm128(
    const u16* __restrict__ A, const u16* __restrict__ Bt,
    const float* __restrict__ bias, void* __restrict__ C,
    int M, int N, int K)
{
    __shared__ u16 As[3][128 * 32];
    __shared__ u16 Bs[3][128 * 32];
    const int t = threadIdx.x;
    const int lane = t & 63, wv = t >> 6;
    const int wm = wv >> 1, wn = wv & 1;
    const int nwg = gridDim.x * gridDim.y;
    const int orig = blockIdx.y * gridDim.x + blockIdx.x;
    const int q8 = nwg >> 3, r8 = nwg & 7;
    const int xcd = orig & 7, lin = orig >> 3;
    const int wgid = (xcd < r8 ? xcd * (q8 + 1) : r8 * (q8 + 1) + (xcd - r8) * q8) + lin;
    const int bxs = wgid % gridDim.x, bys = wgid / gridDim.x;
    const int bn0 = bxs * 128, bm0 = bys * 128;
    const int srow = t >> 2;
    const int scol = ((t & 3) ^ ((t >> 3) & 3)) * 8;
    const u16* Ap = A + (size_t)(bm0 + srow) * K + scol;
    const u16* Bp = Bt + (size_t)(bn0 + srow) * K + scol;
    const size_t rstep = (size_t)64 * K;
    const int woff = wv * 16 * 32;
    const int fr = lane & 15;
    const int fkc = (((lane >> 4) ^ ((fr >> 1) & 3)) * 8);
    f32x4 acc[4][4] = {};
    const int NT = K >> 5;

    auto STAGE = [&](int b, int ko) {
        gll16(Ap + ko, &As[b][woff]);
        gll16(Ap + ko + rstep, &As[b][woff + 64 * 32]);
        gll16(Bp + ko, &Bs[b][woff]);
        gll16(Bp + ko + rstep, &Bs[b][woff + 64 * 32]);
    };
    auto COMPUTE = [&](int b) {
        const u16* aBase = &As[b][wm * 64 * 32];
        const u16* bBase = &Bs[b][wn * 64 * 32];
        s16x8 af[4], bfr[4];
        #pragma unroll
        for (int m = 0; m < 4; m++) af[m] = *(const s16x8*)&aBase[(m * 16 + fr) * 32 + fkc];
        #pragma unroll
        for (int n = 0; n < 4; n++) bfr[n] = *(const s16x8*)&bBase[(n * 16 + fr) * 32 + fkc];
        #pragma unroll
        for (int m = 0; m < 4; m++)
        #pragma unroll
        for (int n = 0; n < 4; n++)
            acc[m][n] = __builtin_amdgcn_mfma_f32_16x16x32_bf16(af[m], bfr[n], acc[m][n], 0, 0, 0);
    };

    STAGE(0, 0);
    if (NT > 1) STAGE(1, 32);
    int cur = 0;
    for (int tt = 0; tt < NT; tt++) {
        if (tt + 2 < NT) STAGE((cur + 2) % 3, (tt + 2) * 32);
        __builtin_amdgcn_sched_barrier(0);
        int ahead = NT - 1 - tt; if (ahead > 2) ahead = 2;
        if (ahead == 2)      asm volatile("s_waitcnt vmcnt(8)" ::: "memory");
        else if (ahead == 1) asm volatile("s_waitcnt vmcnt(4)" ::: "memory");
        else                 asm volatile("s_waitcnt vmcnt(0)" ::: "memory");
        __builtin_amdgcn_sched_barrier(0);
        __builtin_amdgcn_s_barrier();
        COMPUTE(cur);
        __builtin_amdgcn_s_barrier();
        __builtin_amdgcn_sched_barrier(0);
        cur = (cur + 1) % 3;
    }

    const int cIn = lane & 15, r4 = (lane >> 4) * 4;
    #pragma unroll
    for (int n = 0; n < 4; n++) {
        int col = bn0 + wn * 64 + n * 16 + cIn;
        float bv = bias ? bias[col] : 0.f;
        #pragma unroll
        for (int m = 0; m < 4; m++) {
            #pragma unroll
            for (int r = 0; r < 4; r++) {
                int rowg = bm0 + wm * 64 + m * 16 + r4 + r;
                float vv = acc[m][n][r] + bv;
                if (ACT == 1) vv = siluf(vv);
                if (OUTBF) ((u16*)C)[(size_t)rowg * N + col] = f2b(vv);
                else       ((float*)C)[(size_t)rowg * N + col] = vv;
            }
        }
    }
}

// ---------------- DUAL 128x128 GEMM: two independent jobs, one dispatch -----
struct GJob {
    const u16* A; const u16* Bt; const float* bias; void* C;
    int M, N, K, gx, nwg, act, outbf;
};

__global__ __launch_bounds__(256) void k_gemm128_dual(GJob ja, GJob jb)
{
    const bool first = (int)blockIdx.x < ja.nwg;
    const GJob J = first ? ja : jb;
    const int orig = first ? blockIdx.x : blockIdx.x - ja.nwg;
    __shared__ u16 As[3][128 * 32];
    __shared__ u16 Bs[3][128 * 32];
    const int t = threadIdx.x;
    const int lane = t & 63, wv = t >> 6;
    const int wm = wv >> 1, wn = wv & 1;
    const int K = J.K;
    const int q8 = J.nwg >> 3, r8 = J.nwg & 7;
    const int xcd = orig & 7, lin = orig >> 3;
    const int wgid = (xcd < r8 ? xcd * (q8 + 1) : r8 * (q8 + 1) + (xcd - r8) * q8) + lin;
    const int bxs = wgid % J.gx, bys = wgid / J.gx;
    const int bn0 = bxs * 128, bm0 = bys * 128;
    const int srow = t >> 2;
    const int scol = ((t & 3) ^ ((t >> 3) & 3)) * 8;
    const u16* Ap = J.A + (size_t)(bm0 + srow) * K + scol;
    const u16* Bp = J.Bt + (size_t)(bn0 + srow) * K + scol;
    const size_t rstep = (size_t)64 * K;
    const int woff = wv * 16 * 32;
    const int fr = lane & 15;
    const int fkc = (((lane >> 4) ^ ((fr >> 1) & 3)) * 8);
    f32x4 acc[4][4] = {};
    const int NT = K >> 5;

    auto STAGE = [&](int b, int ko) {
        gll16(Ap + ko, &As[b][woff]);
        gll16(Ap + ko + rstep, &As[b][woff + 64 * 32]);
        gll16(Bp + ko, &Bs[b][woff]);
        gll16(Bp + ko + rstep, &Bs[b][woff + 64 * 32]);
    };
    auto COMPUTE = [&](int b) {
        const u16* aBase = &As[b][wm * 64 * 32];
        const u16* bBase = &Bs[b][wn * 64 * 32];
        s16x8 af[4], bfr[4];
        #pragma unroll
        for (int m = 0; m < 4; m++) af[m] = *(const s16x8*)&aBase[(m * 16 + fr) * 32 + fkc];
        #pragma unroll
        for (int n = 0; n < 4; n++) bfr[n] = *(const s16x8*)&bBase[(n * 16 + fr) * 32 + fkc];
        #pragma unroll
        for (int m = 0; m < 4; m++)
        #pragma unroll
        for (int n = 0; n < 4; n++)
            acc[m][n] = __builtin_amdgcn_mfma_f32_16x16x32_bf16(af[m], bfr[n], acc[m][n], 0, 0, 0);
    };

    STAGE(0, 0);
    if (NT > 1) STAGE(1, 32);
    int cur = 0;
    for (int tt = 0; tt < NT; tt++) {
        if (tt + 2 < NT) STAGE((cur + 2) % 3, (tt + 2) * 32);
        __builtin_amdgcn_sched_barrier(0);
        int ahead = NT - 1 - tt; if (ahead > 2) ahead = 2;
        if (ahead == 2)      asm volatile("s_waitcnt vmcnt(8)" ::: "memory");
        else if (ahead == 1) asm volatile("s_waitcnt vmcnt(4)" ::: "memory");
        else                 asm volatile("s_waitcnt vmcnt(0)" ::: "memory");
        __builtin_amdgcn_sched_barrier(0);
        __builtin_amdgcn_s_barrier();
        COMPUTE(cur);
        __builtin_amdgcn_s_barrier();
        __builtin_amdgcn_sched_barrier(0);
        cur = (cur + 1) % 3;
    }

    const int cIn = lane & 15, r4 = (lane >> 4) * 4;
    #pragma unroll
    for (int n = 0; n < 4; n++) {
        int col = bn0 + wn * 64 + n * 16 + cIn;
        float bv = J.bias ? J.bias[col] : 0.f;
        #pragma unroll
        for (int m = 0; m < 4; m++) {
            #pragma unroll
            for (int r = 0; r < 4; r++) {
                int rowg = bm0 + wm * 64 + m * 16 + r4 + r;
                float vv = acc[m][n][r] + bv;
                if (J.act) vv = siluf(vv);
                if (J.outbf) ((u16*)J.C)[(size_t)rowg * J.N + col] = f2b(vv);
                else         ((float*)J.C)[(size_t)rowg * J.N + col] = vv;
            }
        }
    }
}

// ---------------- batched prep: transposes + bias copies + silu streams -----
struct ConvJob { const float* W; u16* Wt; int ldw, k0, n0, K, tile_start, tiles_k; };
struct CopyJob { const float* src; float* dst; int n; };
struct BatchArgs {
    ConvJob cj[17]; CopyJob cp[5]; int conv_blocks;
    const float* sA; u16* sOA; int n4A;
    const float* sB; u16* sOB; int n4B; int silu_blocks;
};

__global__ __launch_bounds__(256) void k_prep(BatchArgs a)
{
    __shared__ float ls[64][65];
    int b = blockIdx.x;
    int t = threadIdx.x;
    if (b < a.conv_blocks) {
        int j = 0;
        #pragma unroll 1
        while (j + 1 < 17 && a.cj[j + 1].tile_start <= b) ++j;
        const ConvJob J = a.cj[j];
        int local = b - J.tile_start;
        int tk = local % J.tiles_k, tn = local / J.tiles_k;
        int k0 = tk * 64, n0 = tn * 64;
        int cn = t & 63, rk = t >> 6;
        #pragma unroll
        for (int p = 0; p < 16; p++) {
            int kk = p * 4 + rk;
            ls[kk][cn] = J.W[(size_t)(J.k0 + k0 + kk) * J.ldw + J.n0 + n0 + cn];
        }
        __syncthreads();
        int ck = t & 63, rn = t >> 6;
        #pragma unroll
        for (int p = 0; p < 16; p++) {
            int nn = p * 4 + rn;
            J.Wt[(size_t)(n0 + nn) * J.K + k0 + ck] = f2b(ls[ck][nn]);
        }
    } else if (b < a.conv_blocks + 5) {
        int c = b - a.conv_blocks;
        const CopyJob C = a.cp[c];
        for (int i = t; i < C.n; i += 256) C.dst[i] = C.src[i];
    } else {
        int sb = b - a.conv_blocks - 5;
        int total = a.n4A + a.n4B;
        int stride = a.silu_blocks * 256;
        for (int i = sb * 256 + t; i < total; i += stride) {
            const float* in; u16* out; int idx;
            if (i < a.n4A) { in = a.sA; out = a.sOA; idx = i; }
            else           { in = a.sB; out = a.sOB; idx = i - a.n4A; }
            f32x4 v = *(const f32x4*)(in + (size_t)idx * 4);
            u16x4 o;
            #pragma unroll
            for (int j = 0; j < 4; j++) o[j] = f2b(siluf(v[j]));
            *(u16x4*)(out + (size_t)idx * 4) = o;
        }
    }
}

// ---------------- edge preprocessing (64 edges per block) -------------------
__global__ __launch_bounds__(256) void k_edge_pre(
    const float* __restrict__ pos, const float* __restrict__ edge_attr,
    const int* __restrict__ ei, const float* __restrict__ W_ee,
    const float* __restrict__ b_ee, const float* __restrict__ coors_scale,
    const u16* __restrict__ etf,
    u16* __restrict__ ea_mod, float* __restrict__ dist, float* __restrict__ cdiff)
{
    __shared__ float Ws[65][64];
    int t = threadIdx.x;
    for (int i = t; i < 65 * 64; i += 256) Ws[i >> 6][i & 63] = W_ee[i];
    __syncthreads();
    int l = t & 63;
    float bee = b_ee[l];
    float cscale = coors_scale[0];
    for (int g = 0; g < 16; g++) {
        int e = blockIdx.x * 64 + g * 4 + (t >> 6);
        int row = ei[e], col = ei[E_CNT + e];
        float d0 = pos[row * 3 + 0] - pos[col * 3 + 0];
        float d1 = pos[row * 3 + 1] - pos[col * 3 + 1];
        float d2 = pos[row * 3 + 2] - pos[col * 3 + 2];
        float ssq = d0 * d0 + d1 * d1 + d2 * d2;
        float dst = sqrtf(ssq + 1e-12f);
        float nrm = sqrtf(ssq);
        float cs = cscale / fmaxf(nrm, 1e-8f);
        if (l == 0) {
            dist[e] = dst;
            cdiff[e * 3 + 0] = d0 * cs; cdiff[e * 3 + 1] = d1 * cs; cdiff[e * 3 + 2] = d2 * cs;
        }
        float attr = edge_attr[(size_t)e * 64 + l];
        float acc = dst * Ws[0][l];
        for (int f = 0; f < 64; f++) acc += __shfl(attr, f) * Ws[1 + f][l];
        acc += bee;
        float y = wave_ln64(acc);
        const u16* ep = etf + (size_t)e * 896;
        float m = y * (1.f + b2f(ep[64 + l])) + b2f(ep[l]);
        ea_mod[(size_t)e * 64 + l] = f2b(m);
    }
}

// ---------------- node: hh = modulate(ln(h), sh_msa, sc_msa) -> bf16 --------
__global__ __launch_bounds__(256) void k_node_hh(
    const float* __restrict__ h, const float* __restrict__ nt, u16* __restrict__ hh)
{
    int n = blockIdx.x, c = threadIdx.x;
    float x = h[(size_t)n * 256 + c];
    float y = block_ln256(x);
    float m = y * (1.f + nt[(size_t)n * 1536 + 256 + c]) + nt[(size_t)n * 1536 + c];
    hh[(size_t)n * 256 + c] = f2b(m);
}

// ---------------- fused per-node: alpha + softmax + aggregation -------------
__global__ __launch_bounds__(256) void k_agg(
    const float* __restrict__ qkv, const u16* __restrict__ e01,
    float* __restrict__ hnode, u16* __restrict__ hnode_bf)
{
    int n = blockIdx.x;
    int b = n / 48, i = n % 48;
    int t = threadIdx.x;
    __shared__ float qs[8][33];
    __shared__ float att[47][8];
    __shared__ float mxs[8], dens[8];
    __shared__ int elist[47], slist[47];
    qs[t >> 5][t & 31] = qkv[(size_t)n * 768 + t];
    if (t < 47) {
        int s = t + (t >= i ? 1 : 0);
        slist[t] = s;
        elist[t] = b * EPG + s * 47 + (i < s ? i : i - 1);
    }
    __syncthreads();
    for (int idx = t; idx < 376; idx += 256) {
        int j = idx >> 3, hh = idx & 7;
        int src = b * 48 + slist[j];
        int e = elist[j];
        const float* kp = qkv + (size_t)src * 768 + 256 + hh * 32;
        const u16* ep = e01 + (size_t)e * 512 + hh * 32;
        float p = 0.f;
        #pragma unroll
        for (int d = 0; d < 32; d++) p += qs[hh][d] * kp[d] * b2f(ep[d]);
        att[j][hh] = p * 0.17677669529663687f; // 1/sqrt(32)
    }
    __syncthreads();
    if (t < 8) {
        float m = -1e30f;
        for (int j = 0; j < 47; j++) m = fmaxf(m, att[j][t]);
        float den = 0.f;
        for (int j = 0; j < 47; j++) den += expf(att[j][t] - m);
        mxs[t] = m; dens[t] = den + 1e-16f;
    }
    __syncthreads();
    for (int idx = t; idx < 376; idx += 256) {
        int j = idx >> 3, hh = idx & 7;
        att[j][hh] = expf(att[j][hh] - mxs[hh]) / dens[hh];
    }
    __syncthreads();
    int c = t, hh = t >> 5;
    float acc = 0.f;
    for (int j = 0; j < 47; j++) {
        int src = b * 48 + slist[j];
        int e = elist[j];
        acc += att[j][hh] * qkv[(size_t)src * 768 + 512 + c] * b2f(e01[(size_t)e * 512 + 256 + c]);
    }
    hnode[(size_t)n * 256 + c] = acc;
    hnode_bf[(size_t)n * 256 + c] = f2b(acc);
}

// ---------------- MERGED: node_mod (blocks 0..1535) + edge_mod (rest) -------
__global__ __launch_bounds__(256) void k_mods(
    const float* __restrict__ h, const float* __restrict__ hnode_raw,
    const float* __restrict__ nt, const float* __restrict__ mask,
    float* __restrict__ hmod, u16* __restrict__ hmod_bf,
    const float* __restrict__ Q1, const float* __restrict__ b_n2e,
    const float* __restrict__ edge_attr, const int* __restrict__ ei,
    const u16* __restrict__ etf, float* __restrict__ hemod, u16* __restrict__ hemod_bf)
{
    if ((int)blockIdx.x < BN_CNT) {
        int n = blockIdx.x, c = threadIdx.x;
        float x = h[(size_t)n * 256 + c] + nt[(size_t)n * 1536 + 512 + c] * hnode_raw[(size_t)n * 256 + c];
        float y = block_ln256(x);
        float m = (y * (1.f + nt[(size_t)n * 1536 + 1024 + c]) + nt[(size_t)n * 1536 + 768 + c]) * mask[n];
        hmod[(size_t)n * 256 + c] = m;
        hmod_bf[(size_t)n * 256 + c] = f2b(m);
    } else {
        int bb = blockIdx.x - BN_CNT;
        int l = threadIdx.x & 63;
        float bn2e = b_n2e[l];
        for (int g = 0; g < 4; g++) {
            int e = bb * 16 + g * 4 + (threadIdx.x >> 6);
            int row = ei[e], col = ei[E_CNT + e];
            float hedge = Q1[(size_t)row * 64 + l] + Q1[(size_t)col * 64 + l] + bn2e;
            const u16* ep = etf + (size_t)e * 896;
            float x = edge_attr[(size_t)e * 64 + l] + b2f(ep[128 + l]) * hedge;
            float y = wave_ln64(x);
            float m = y * (1.f + b2f(ep[256 + l])) + b2f(ep[192 + l]);
            hemod[(size_t)e * 64 + l] = m;
            hemod_bf[(size_t)e * 64 + l] = f2b(m);
        }
    }
}

// ---------------- CondEquiUpdate inv_pre: wave-per-edge, vectorized ---------
__global__ __launch_bounds__(256) void k_inv_pre4(
    const float* __restrict__ p12,
    const u16* __restrict__ P3, const float* __restrict__ dist,
    const float* __restrict__ W_ui, const float* __restrict__ b_ui,
    const int* __restrict__ ei, const u16* __restrict__ etf, u16* __restrict__ invmod)
{
    int e = blockIdx.x * 4 + (threadIdx.x >> 6);
    int l = threadIdx.x & 63;
    int c = l * 4;
    int row = ei[e], col = ei[E_CNT + e];
    f32x4 pa = *(const f32x4*)(p12 + (size_t)row * 512 + c);
    f32x4 pb = *(const f32x4*)(p12 + (size_t)col * 512 + 256 + c);
    u16x4 p3 = *(const u16x4*)(P3 + (size_t)e * 256 + c);
    f32x4 wui = *(const f32x4*)(W_ui + 576 * 256 + c);
    f32x4 bui = *(const f32x4*)(b_ui + c);
    float dd = dist[e];
    float x[4];
    float s = 0.f;
    #pragma unroll
    for (int j = 0; j < 4; j++) {
        x[j] = pa[j] + pb[j] + b2f(p3[j]) + dd * wui[j] + bui[j];
        s += x[j];
    }
    #pragma unroll
    for (int off = 1; off < 64; off <<= 1) s += __shfl_xor(s, off);
    float mean = s * (1.f / 256.f);
    float v2 = 0.f;
    #pragma unroll
    for (int j = 0; j < 4; j++) {
        float d = x[j] - mean;
        v2 += d * d;
    }
    #pragma unroll
    for (int off = 1; off < 64; off <<= 1) v2 += __shfl_xor(v2, off);
    float rs = rsqrtf(v2 * (1.f / 256.f) + 1e-6f);
    const u16* ep = etf + (size_t)e * 896;
    u16x4 sc = *(const u16x4*)(ep + 640 + c);
    u16x4 sh = *(const u16x4*)(ep + 384 + c);
    u16x4 o;
    #pragma unroll
    for (int j = 0; j < 4; j++) {
        float y = (x[j] - mean) * rs;
        o[j] = f2b(y * (1.f + b2f(sc[j])) + b2f(sh[j]));
    }
    *(u16x4*)(invmod + (size_t)e * 256 + c) = o;
}

// ---------------- final per-edge scalar: tanh( silu(y) . W_uc2 )  (x4) ------
__global__ __launch_bounds__(256) void k_inv(const u16* __restrict__ uc1,
                                             const float* __restrict__ W_uc2,
                                             float* __restrict__ inv)
{
    int l = threadIdx.x & 63;
    const float* w = W_uc2 + l * 4;
    float w0 = w[0], w1 = w[1], w2 = w[2], w3 = w[3];
    for (int g = 0; g < 4; g++) {
        int e = blockIdx.x * 16 + g * 4 + (threadIdx.x >> 6);
        u16x4 v = *(const u16x4*)(uc1 + (size_t)e * 256 + l * 4);
        float s = b2f(v[0]) * w0 + b2f(v[1]) * w1 + b2f(v[2]) * w2 + b2f(v[3]) * w3;
        #pragma unroll
        for (int off = 1; off < 64; off <<= 1) s += __shfl_xor(s, off);
        if (l == 0) inv[e] = tanhf(s);
    }
}

// ---------------- pos update: deterministic contiguous segment sum ----------
__global__ void k_pos(const float* __restrict__ pos, const float* __restrict__ cdiff,
                      const float* __restrict__ inv, float* __restrict__ out3)
{
    int n = blockIdx.x * 256 + threadIdx.x;
    if (n >= BN_CNT) return;
    int b = n / 48, s = n % 48;
    int e0 = b * EPG + s * 47;
    float a0 = 0.f, a1 = 0.f, a2 = 0.f;
    for (int j = 0; j < 47; j++) {
        float f = inv[e0 + j];
        a0 += cdiff[(size_t)(e0 + j) * 3 + 0] * f;
        a1 += cdiff[(size_t)(e0 + j) * 3 + 1] * f;
        a2 += cdiff[(size_t)(e0 + j) * 3 + 2] * f;
    }
    out3[n * 3 + 0] = pos[n * 3 + 0] + a0;
    out3[n * 3 + 1] = pos[n * 3 + 1] + a1;
    out3[n * 3 + 2] = pos[n * 3 + 2] + a2;
}

extern "C" void kernel_launch(void* const* d_in, const int* in_sizes, int n_in,
                              void* d_out, int out_size, void* d_ws, size_t ws_size,
                              hipStream_t stream)
{
    (void)in_sizes; (void)n_in; (void)out_size; (void)ws_size;
    const float* pos       = (const float*)d_in[0];
    const float* h         = (const float*)d_in[1];
    const float* edge_attr = (const float*)d_in[2];
    const float* node_mask = (const float*)d_in[3];
    const float* nte       = (const float*)d_in[4];
    const float* ete       = (const float*)d_in[5];
    const int*   ei        = (const int*)d_in[6];
    const float* W_ee = (const float*)d_in[7];  const float* b_ee = (const float*)d_in[8];
    const float* W_nt = (const float*)d_in[9];  const float* b_nt = (const float*)d_in[10];
    const float* W_et = (const float*)d_in[11]; const float* b_et = (const float*)d_in[12];
    const float* Wq  = (const float*)d_in[13];  const float* bq  = (const float*)d_in[14];
    const float* Wk  = (const float*)d_in[15];  const float* bk  = (const float*)d_in[16];
    const float* Wv  = (const float*)d_in[17];  const float* bv  = (const float*)d_in[18];
    const float* We0 = (const float*)d_in[19];  const float* We1 = (const float*)d_in[20];
    const float* W_n2e = (const float*)d_in[21]; const float* b_n2e = (const float*)d_in[22];
    const float* W_ff1 = (const float*)d_in[23]; const float* b_ff1 = (const float*)d_in[24];
    const float* W_ff2 = (const float*)d_in[25]; const float* b_ff2 = (const float*)d_in[26];
    const float* W_ff3 = (const float*)d_in[27]; const float* b_ff3 = (const float*)d_in[28];
    const float* W_ff4 = (const float*)d_in[29]; const float* b_ff4 = (const float*)d_in[30];
    const float* coors_scale = (const float*)d_in[31];
    const float* W_ut = (const float*)d_in[32]; const float* b_ut = (const float*)d_in[33];
    const float* W_ui = (const float*)d_in[34]; const float* b_ui = (const float*)d_in[35];
    const float* W_uc1 = (const float*)d_in[36]; const float* b_uc1 = (const float*)d_in[37];
    const float* W_uc2 = (const float*)d_in[38];

    const size_t E = E_CNT;
    char* ws = (char*)d_ws;
    size_t off = 0;
    auto AL = [&](size_t b) { size_t o = off; off += (b + 255) & ~(size_t)255; return o; };

    // weights (bf16, transposed [N,K])
    size_t o_wtcat  = AL(896 * 1024 * 2);
    size_t o_wtnt   = AL(1536 * 1024 * 2);
    size_t o_wtqkv  = AL(768 * 256 * 2);
    size_t o_wte01  = AL(512 * 64 * 2);
    size_t o_wtn2e  = AL(64 * 256 * 2);
    size_t o_wtff1  = AL(512 * 256 * 2), o_wtff2 = AL(256 * 512 * 2);
    size_t o_wtff3  = AL(128 * 64 * 2),  o_wtff4 = AL(64 * 128 * 2);
    size_t o_wtuiab = AL(512 * 256 * 2);
    size_t o_wtuic  = AL(256 * 64 * 2),  o_wtuc1 = AL(256 * 256 * 2);
    size_t o_bias896 = AL(896 * 4);
    size_t o_bias768 = AL(768 * 4);
    // big regions (lifetime-based aliasing)
    size_t o_reg1 = AL(E * 1024 * 2);          // ete_silu -> later P3/invmod/uc1o
    size_t o_etf  = AL(E * 896 * 2);           // persistent
    size_t o_ntes = AL(1536 * 1024 * 2);
    size_t o_ntf  = AL((size_t)1536 * 1536 * 4);
    size_t o_eamod = AL(E * 64 * 2);
    size_t o_dist = AL(E * 4), o_cdiff = AL(E * 12);
    size_t o_qkv  = AL(1536 * 768 * 4);
    size_t o_reg3 = AL(E * 512 * 2);           // e01 -> later ffem/heoutbf
    size_t o_hnode = AL(1536 * 256 * 4), o_hnodebf = AL(1536 * 256 * 2);
    size_t o_q1 = AL(1536 * 64 * 4);
    size_t o_hh = AL(1536 * 256 * 2);
    size_t o_hmod = AL(1536 * 256 * 4), o_hmodbf = AL(1536 * 256 * 2);
    size_t o_ff1 = AL(1536 * 512 * 2);
    size_t o_houtbf = AL(1536 * 256 * 2);
    size_t o_hemod = AL(E * 64 * 4), o_hemodbf = AL(E * 64 * 2);
    size_t o_p12 = AL(1536 * 512 * 4);
    size_t o_inv = AL(E * 4);
    // aliases
    size_t o_etes = o_reg1;
    size_t o_p3 = o_reg1;
    size_t o_invmod = o_reg1 + E * 256 * 2;
    size_t o_uc1o = o_reg1 + E * 256 * 4;
    size_t o_e01 = o_reg3;
    size_t o_ffem = o_reg3;
    size_t o_heoutbf = o_reg3 + E * 128 * 2 + E * 64 * 4;

    #define WSU(o) ((u16*)(ws + (o)))
    #define WSF(o) ((float*)(ws + (o)))

    // --- batched weight prep + silu streams (ONE dispatch) ---
    {
        BatchArgs a;
        int s = 0; int j = 0;
        auto add = [&](const float* W, u16* Wt, int ldw, int k0, int n0, int K, int NC) {
            a.cj[j++] = ConvJob{W, Wt, ldw, k0, n0, K, s, K / 64};
            s += (K / 64) * (NC / 64);
        };
        add(W_et, WSU(o_wtcat), 384, 0, 0, 1024, 384);
        add(W_ut, WSU(o_wtcat) + (size_t)384 * 1024, 512, 0, 0, 1024, 512);
        add(W_nt, WSU(o_wtnt), 1536, 0, 0, 1024, 1536);
        add(Wq, WSU(o_wtqkv), 256, 0, 0, 256, 256);
        add(Wk, WSU(o_wtqkv) + (size_t)256 * 256, 256, 0, 0, 256, 256);
        add(Wv, WSU(o_wtqkv) + (size_t)512 * 256, 256, 0, 0, 256, 256);
        add(We0, WSU(o_wte01), 256, 0, 0, 64, 256);
        add(We1, WSU(o_wte01) + (size_t)256 * 64, 256, 0, 0, 64, 256);
        add(W_n2e, WSU(o_wtn2e), 64, 0, 0, 256, 64);
        add(W_ff1, WSU(o_wtff1), 512, 0, 0, 256, 512);
        add(W_ff2, WSU(o_wtff2), 256, 0, 0, 512, 256);
        add(W_ff3, WSU(o_wtff3), 128, 0, 0, 64, 128);
        add(W_ff4, WSU(o_wtff4), 64, 0, 0, 128, 64);
        add(W_ui, WSU(o_wtuiab), 256, 0, 0, 256, 256);
        add(W_ui, WSU(o_wtuiab) + (size_t)256 * 256, 256, 256, 0, 256, 256);
        add(W_ui, WSU(o_wtuic), 256, 512, 0, 64, 256);
        add(W_uc1, WSU(o_wtuc1), 256, 0, 0, 256, 256);
        a.conv_blocks = s;  // 788 tiles
        a.cp[0] = CopyJob{b_et, WSF(o_bias896), 384};
        a.cp[1] = CopyJob{b_ut, WSF(o_bias896) + 384, 512};
        a.cp[2] = CopyJob{bq, WSF(o_bias768), 256};
        a.cp[3] = CopyJob{bk, WSF(o_bias768) + 256, 256};
        a.cp[4] = CopyJob{bv, WSF(o_bias768) + 512, 256};
        a.sA = ete; a.sOA = WSU(o_etes); a.n4A = (int)(E * 1024 / 4);
        a.sB = nte; a.sOB = WSU(o_ntes); a.n4B = 1536 * 1024 / 4;
        a.silu_blocks = 2048;
        k_prep<<<s + 5 + 2048, 256, 0, stream>>>(a);
    }

    // --- big time-embedding GEMMs: et || nt in ONE dispatch ---
    {
        GJob ja{WSU(o_etes), WSU(o_wtcat), WSF(o_bias896), WSU(o_etf),
                E_CNT, 896, 1024, 7, 3948, 0, 1};
        GJob jb{WSU(o_ntes), WSU(o_wtnt), b_nt, WSF(o_ntf),
                1536, 1536, 1024, 12, 144, 0, 0};
        k_gemm128_dual<<<3948 + 144, 256, 0, stream>>>(ja, jb);
    }

    // --- edge/node preprocess ---
    k_edge_pre<<<1128, 256, 0, stream>>>(pos, edge_attr, ei, W_ee, b_ee, coors_scale,
                                         WSU(o_etf), WSU(o_eamod), WSF(o_dist), WSF(o_cdiff));
    k_node_hh<<<1536, 256, 0, stream>>>(h, WSF(o_ntf), WSU(o_hh));

    // --- attention inputs: e01 || qkv in ONE dispatch ---
    {
        GJob ja{WSU(o_eamod), WSU(o_wte01), nullptr, WSU(o_e01),
                E_CNT, 512, 64, 4, 2256, 0, 1};
        GJob jb{WSU(o_hh), WSU(o_wtqkv), WSF(o_bias768), WSF(o_qkv),
                1536, 768, 256, 6, 72, 0, 0};
        k_gemm128_dual<<<2256 + 72, 256, 0, stream>>>(ja, jb);
    }
    k_agg<<<1536, 256, 0, stream>>>(WSF(o_qkv), WSU(o_e01), WSF(o_hnode), WSU(o_hnodebf));

    // --- Q1 = h_node_raw @ W_n2e ---
    k_gemm<0, 0><<<dim3(1, 24), 256, 0, stream>>>(WSU(o_hnodebf), WSU(o_wtn2e), nullptr, WSF(o_q1), 1536, 64, 256);

    // --- node_mod || edge_mod in ONE dispatch ---
    k_mods<<<BN_CNT + 4512, 256, 0, stream>>>(
        h, WSF(o_hnode), WSF(o_ntf), node_mask, WSF(o_hmod), WSU(o_hmodbf),
        WSF(o_q1), b_n2e, edge_attr, ei, WSU(o_etf), WSF(o_hemod), WSU(o_hemodbf));

    // --- FFN stage 1: ff3 || ff1 in ONE dispatch ---
    {
        GJob ja{WSU(o_hemodbf), WSU(o_wtff3), b_ff3, WSU(o_ffem),
                E_CNT, 128, 64, 1, 564, 1, 1};
        GJob jb{WSU(o_hmodbf), WSU(o_wtff1), b_ff1, WSU(o_ff1),
                1536, 512, 256, 4, 48, 1, 1};
        k_gemm128_dual<<<564 + 48, 256, 0, stream>>>(ja, jb);
    }

    // --- FFN stage 2 with fused output epilogues ---
    k_gemm_ff2ho<<<dim3(4, 24), 256, 0, stream>>>(WSU(o_ff1), WSU(o_wtff2), b_ff2,
                                                  WSF(o_hmod), WSF(o_ntf), node_mask,
                                                  (float*)d_out, WSU(o_houtbf), 1536, 256, 512);
    k_gemm_ff4eo<<<dim3(1, 1128), 256, 0, stream>>>(WSU(o_ffem), WSU(o_wtff4), b_ff4,
                                                    WSF(o_hemod), WSU(o_etf),
                                                    (float*)d_out + 393216, WSU(o_heoutbf), E_CNT, 64, 128);

    // --- CondEquiUpdate: p3 || p12 in ONE dispatch ---
    {
        GJob ja{WSU(o_heoutbf), WSU(o_wtuic), nullptr, WSU(o_p3),
                E_CNT, 256, 64, 2, 1128, 0, 1};
        GJob jb{WSU(o_houtbf), WSU(o_wtuiab), nullptr, WSF(o_p12),
                1536, 512, 256, 4, 48, 0, 0};
        k_gemm128_dual<<<1128 + 48, 256, 0, stream>>>(ja, jb);
    }
    k_inv_pre4<<<18048, 256, 0, stream>>>(WSF(o_p12), WSU(o_p3), WSF(o_dist),
                                          W_ui, b_ui, ei, WSU(o_etf), WSU(o_invmod));
    k_gemm128<1, 1><<<dim3(2, 564), 256, 0, stream>>>(WSU(o_invmod), WSU(o_wtuc1), b_uc1, WSU(o_uc1o), E_CNT, 256, 256);
    k_inv<<<4512, 256, 0, stream>>>(WSU(o_uc1o), W_uc2, WSF(o_inv));
    k_pos<<<6, 256, 0, stream>>>(pos, WSF(o_cdiff), WSF(o_inv), (float*)d_out + 393216 + E_CNT * 64);

    #undef WSU
    #undef WSF
}